// Round 3
// baseline (167.115 us; speedup 1.0000x reference)
//
#include <hip/hip_runtime.h>
#include <math.h>

#define DEV __device__ __forceinline__
typedef unsigned short ush;
typedef __attribute__((ext_vector_type(8))) short s8v;   // 8 bf16 = 4 VGPR
typedef __attribute__((ext_vector_type(4))) float f4v;
typedef __attribute__((ext_vector_type(4))) int i4v;

constexpr int NTOK = 1024;
constexpr int D    = 512;
constexpr int H    = 8;
constexpr int NB   = 16;
constexpr double EPSd = 1e-7;

DEV ush f2b(float v) {                      // fp32 -> bf16 RNE
  unsigned u = __float_as_uint(v);
  return (ush)((u + 0x7fffu + ((u >> 16) & 1u)) >> 16);
}
DEV float b2f(ush u) { return __uint_as_float(((unsigned)u) << 16); }

// ---------------- reductions ----------------
DEV double wave_sum(double v) {
#pragma unroll
  for (int m = 32; m; m >>= 1) v += __shfl_xor(v, m, 64);
  return v;
}
DEV double block_sum(double v, double* scratch) {
  v = wave_sum(v);
  __syncthreads();
  if ((threadIdx.x & 63) == 0) scratch[threadIdx.x >> 6] = v;
  __syncthreads();
  return scratch[0] + scratch[1] + scratch[2] + scratch[3];
}

// ---------------- merged weight transpose-cast (all 4 weights, 1 dispatch) ----------------
// W[K][N] f32 -> WT[N][K] bf16 (hi, and lo residual for Wqkv)
__global__ void k_prep(const float* __restrict__ Wqkv, const float* __restrict__ Wout,
                       const float* __restrict__ Wff1, const float* __restrict__ Wff2,
                       ush* __restrict__ qh, ush* __restrict__ ql, ush* __restrict__ oT,
                       ush* __restrict__ f1T, ush* __restrict__ f2T) {
  __shared__ float t[32][33];
  const int bid = blockIdx.x;
  const float* src; ush* dh; ush* dl = nullptr; int K, N, bx, by;
  if (bid < 768)       { src = Wqkv; dh = qh;  dl = ql; K = 512;  N = 1536; int l = bid;        bx = l % 48; by = l / 48; }
  else if (bid < 1024) { src = Wout; dh = oT;           K = 512;  N = 512;  int l = bid - 768;  bx = l % 16; by = l / 16; }
  else if (bid < 2048) { src = Wff1; dh = f1T;          K = 512;  N = 2048; int l = bid - 1024; bx = l % 64; by = l / 64; }
  else                 { src = Wff2; dh = f2T;          K = 2048; N = 512;  int l = bid - 2048; bx = l % 16; by = l / 16; }
  const int n0 = bx * 32, k0 = by * 32;
  const int tx = threadIdx.x & 31, ty = threadIdx.x >> 5;
  for (int i = ty; i < 32; i += 8) t[i][tx] = src[(size_t)(k0 + i) * N + n0 + tx];
  __syncthreads();
  for (int i = ty; i < 32; i += 8) {
    float v = t[tx][i];
    ush hh = f2b(v);
    dh[(size_t)(n0 + i) * K + k0 + tx] = hh;
    if (dl) dl[(size_t)(n0 + i) * K + k0 + tx] = f2b(v - b2f(hh));
  }
}

// ---------------- phase 1: logmap0 -> LN -> expmap0 -> logmap0 (fused), bf16 hi/lo out ----------
__global__ void k_pre(const float* __restrict__ x, const float* __restrict__ cg,
                      const float* __restrict__ s1, const float* __restrict__ b1,
                      ush* __restrict__ xth, ush* __restrict__ xtl) {
  __shared__ double scratch[4];
  const int tok = blockIdx.x, t = threadIdx.x;
  const float* row = x + (size_t)tok * D;
  float v0 = row[t], v1 = row[t + 256];
  double c = (double)cg[0];
  double sc = sqrt(c); if (sc < EPSd) sc = EPSd;
  double yn = sqrt(block_sum((double)v0 * v0 + (double)v1 * v1, scratch));
  double arg0 = yn; if (arg0 > 1.0 - EPSd) arg0 = 1.0 - EPSd;
  double f = (yn < EPSd) ? 0.0 : atanh(arg0) / sc / fmax(yn, EPSd);
  double u0 = f * v0, u1 = f * v1;
  double mu  = block_sum(u0 + u1, scratch) / D;
  double su2 = block_sum(u0 * u0 + u1 * u1, scratch);
  double rs = 1.0 / sqrt(su2 / D - mu * mu + 1e-6);
  double w0 = (u0 - mu) * rs * (double)s1[t]       + (double)b1[t];
  double w1 = (u1 - mu) * rs * (double)s1[t + 256] + (double)b1[t + 256];
  double vn = sqrt(block_sum(w0 * w0 + w1 * w1, scratch));
  double F = 0.0;
  if (vn >= EPSd) {
    double mag_e = tanh(sc * fmax(vn, EPSd)) / sc;
    double a2 = fmin(mag_e, 1.0 - EPSd);
    F = atanh(a2) / (sc * vn);
  }
  float o0 = (float)(F * w0), o1 = (float)(F * w1);
  ush h0 = f2b(o0), h1 = f2b(o1);
  size_t base = (size_t)tok * D + t;
  xth[base] = h0;       xth[base + 256] = h1;
  xtl[base] = f2b(o0 - b2f(h0));
  xtl[base + 256] = f2b(o1 - b2f(h1));
}

// ---------------- bf16 MFMA GEMM, 128x128 tile: C[M,N] = A[M,K] @ BT[N,K]^T + bias ------------
// SPLIT: hi/lo 3-pass (fp32-class). GELU epilogue. OBF16: bf16 output.
template <int SPLIT, int GELU, int OBF16>
__global__ __launch_bounds__(256) void k_mm(
    const ush* __restrict__ Ah, const ush* __restrict__ Al,
    const ush* __restrict__ Bh, const ush* __restrict__ Bl,
    const float* __restrict__ bias, float* __restrict__ Cf,
    ush* __restrict__ Cb, int M, int N, int K) {
  __shared__ __align__(16) ush As[SPLIT + 1][128][40];  // pad 32->40: 2-way banks (free)
  __shared__ __align__(16) ush Bs[SPLIT + 1][128][40];
  const int tid = threadIdx.x;
  const int lane = tid & 63, wid = tid >> 6;
  const int wr = (wid >> 1) * 64, wc = (wid & 1) * 64;
  const int lr = lane & 15, lg = lane >> 4;
  const size_t r0 = (size_t)blockIdx.y * 128, c0 = (size_t)blockIdx.x * 128;
  const f4v z = {0.f, 0.f, 0.f, 0.f};
  f4v acc[4][4];
#pragma unroll
  for (int m = 0; m < 4; ++m)
#pragma unroll
    for (int n = 0; n < 4; ++n) acc[m][n] = z;
  for (int k0 = 0; k0 < K; k0 += 32) {
#pragma unroll
    for (int p = 0; p < 2; ++p) {
      const int idx = p * 256 + tid;
      const int row = idx >> 2, cg = (idx & 3) * 8;
      *(i4v*)&As[0][row][cg] = *(const i4v*)(Ah + (r0 + row) * (size_t)K + k0 + cg);
      *(i4v*)&Bs[0][row][cg] = *(const i4v*)(Bh + (c0 + row) * (size_t)K + k0 + cg);
      if (SPLIT) {
        *(i4v*)&As[SPLIT][row][cg] = *(const i4v*)(Al + (r0 + row) * (size_t)K + k0 + cg);
        *(i4v*)&Bs[SPLIT][row][cg] = *(const i4v*)(Bl + (c0 + row) * (size_t)K + k0 + cg);
      }
    }
    __syncthreads();
    s8v ah[4], bh[4];
#pragma unroll
    for (int m = 0; m < 4; ++m) ah[m] = *(const s8v*)&As[0][wr + m * 16 + lr][lg * 8];
#pragma unroll
    for (int n = 0; n < 4; ++n) bh[n] = *(const s8v*)&Bs[0][wc + n * 16 + lr][lg * 8];
#pragma unroll
    for (int m = 0; m < 4; ++m)
#pragma unroll
      for (int n = 0; n < 4; ++n)
        acc[m][n] = __builtin_amdgcn_mfma_f32_16x16x32_bf16(ah[m], bh[n], acc[m][n], 0, 0, 0);
    if (SPLIT) {
      s8v al[4], bl[4];
#pragma unroll
      for (int m = 0; m < 4; ++m) al[m] = *(const s8v*)&As[SPLIT][wr + m * 16 + lr][lg * 8];
#pragma unroll
      for (int n = 0; n < 4; ++n) bl[n] = *(const s8v*)&Bs[SPLIT][wc + n * 16 + lr][lg * 8];
#pragma unroll
      for (int m = 0; m < 4; ++m)
#pragma unroll
        for (int n = 0; n < 4; ++n) {
          acc[m][n] = __builtin_amdgcn_mfma_f32_16x16x32_bf16(ah[m], bl[n], acc[m][n], 0, 0, 0);
          acc[m][n] = __builtin_amdgcn_mfma_f32_16x16x32_bf16(al[m], bh[n], acc[m][n], 0, 0, 0);
        }
    }
    __syncthreads();
  }
#pragma unroll
  for (int m = 0; m < 4; ++m)
#pragma unroll
    for (int n = 0; n < 4; ++n) {
      const size_t row = r0 + wr + m * 16 + lg * 4;
      const size_t col = c0 + wc + n * 16 + lr;
      const float bv = bias[col];
#pragma unroll
      for (int e = 0; e < 4; ++e) {
        float v = acc[m][n][e] + bv;
        if (GELU) {
          float x3 = v * v * v;
          v = 0.5f * v * (1.0f + tanhf(0.7978845608028654f * (v + 0.044715f * x3)));
        }
        if (OBF16) Cb[(row + e) * N + col] = f2b(v);
        else       Cf[(row + e) * N + col] = v;
      }
    }
}

// ---------------- attention: RoPE + per-head expmap0 + hyperbolic dist + softmax + PV (fp32) --
__global__ __launch_bounds__(256) void k_attn(
    const float* __restrict__ qkv, const float* __restrict__ chl,
    const float* __restrict__ geo, ush* __restrict__ ao) {
  __shared__ float Qs[64][65];
  __shared__ float Ks[64][65];
  __shared__ float q2s[64], k2s[64], fqv[64], fkv[64];
  const int be = blockIdx.x >> 3, h = blockIdx.x & 7;
  const int tid = threadIdx.x;
  const double chd = log1p(exp((double)chl[h]));   // softplus (cheap, once)
  const float ch = (float)chd;
  float sc = (float)sqrt(chd); if (sc < 1e-7f) sc = 1e-7f;
  // stage q,k with RoPE applied (fp32 trig; pos within block = row s)
  for (int l = tid; l < 64 * 32; l += 256) {
    int s = l >> 5, j = l & 31;
    const float* base = qkv + (size_t)(be * 64 + s) * 1536 + h * 64;
    float qa = base[j],       qb = base[j + 32];
    float ka = base[512 + j], kb = base[512 + j + 32];
    float fj = expf((float)j * -0.2878231366242557f);   // ln(10000)/32
    float th = (float)s * fj;
    float st, ct; sincosf(th, &st, &ct);
    Qs[s][j]      = qa * ct - qb * st;
    Qs[s][j + 32] = qa * st + qb * ct;
    Ks[s][j]      = ka * ct - kb * st;
    Ks[s][j + 32] = ka * st + kb * ct;
  }
  __syncthreads();
  // per-row expmap0 factors (rows kept unscaled in LDS; factors folded into Gram)
  if (tid < 128) {
    int i = tid & 63;
    const float* P = (tid < 64) ? &Qs[i][0] : &Ks[i][0];
    float a = 0.f;
    for (int d2 = 0; d2 < 64; ++d2) { float v = P[d2]; a += v * v; }
    float n = sqrtf(a);
    float m = tanhf(sc * fmaxf(n, 1e-7f)) / sc;
    float f = (n < 1e-7f) ? 0.f : m / fmaxf(n, 1e-7f);
    if (m >= 1.f) f *= (1.f - 1e-7f) / m;
    float fn = f * n;
    if (tid < 64) { fqv[i] = f; q2s[i] = fn * fn; }
    else          { fkv[i] = f; k2s[i] = fn * fn; }
  }
  __syncthreads();
  const int i = tid >> 2, g = tid & 3;
  float gacc[16];
#pragma unroll
  for (int jj = 0; jj < 16; ++jj) gacc[jj] = 0.f;
  for (int d2 = 0; d2 < 64; ++d2) {
    float qv = Qs[i][d2];
#pragma unroll
    for (int jj = 0; jj < 16; ++jj) gacc[jj] += qv * Ks[g * 16 + jj][d2];
  }
  const float gs = geo[h];
  const float q2 = q2s[i], fqi = fqv[i];
  float lg[16];
  float mx = -1e30f;
#pragma unroll
  for (int jj = 0; jj < 16; ++jj) {
    float gq = fqi * fkv[g * 16 + jj] * gacc[jj];
    float k2 = k2s[g * 16 + jj];
    float A  = 1.f - 2.f * ch * gq + ch * k2;
    float Bv = 1.f - ch * q2;
    float n2 = fmaxf(A * A * q2 - 2.f * A * Bv * gq + Bv * Bv * k2, 0.f);
    float den = fmaxf(1.f - 2.f * ch * gq + ch * ch * q2 * k2, 1e-7f);
    float r = fminf(sqrtf(n2) / den, 1.f - 1e-7f);
    float arg = fminf(sc * r, 1.f - 1e-7f);
    float l = -gs * (2.f * atanhf(arg) / sc);
    lg[jj] = l; mx = fmaxf(mx, l);
  }
  mx = fmaxf(mx, __shfl_xor(mx, 1, 64));
  mx = fmaxf(mx, __shfl_xor(mx, 2, 64));
  float pv[16]; float sum = 0.f;
#pragma unroll
  for (int jj = 0; jj < 16; ++jj) { pv[jj] = expf(lg[jj] - mx); sum += pv[jj]; }
  sum += __shfl_xor(sum, 1, 64);
  sum += __shfl_xor(sum, 2, 64);
  float inv = 1.0f / sum;
  __syncthreads();
#pragma unroll
  for (int jj = 0; jj < 16; ++jj) Qs[i][g * 16 + jj] = pv[jj] * inv;
  for (int l = tid; l < 64 * 64; l += 256) {
    int s = l >> 6, d2 = l & 63;
    Ks[s][d2] = qkv[(size_t)(be * 64 + s) * 1536 + 1024 + h * 64 + d2];
  }
  __syncthreads();
  float oacc[16];
#pragma unroll
  for (int dd = 0; dd < 16; ++dd) oacc[dd] = 0.f;
  for (int jv = 0; jv < 64; ++jv) {
    float p = Qs[i][jv];
#pragma unroll
    for (int dd = 0; dd < 16; ++dd) oacc[dd] += p * Ks[jv][g * 16 + dd];
  }
#pragma unroll
  for (int dd = 0; dd < 16; ++dd)
    ao[(size_t)(be * 64 + i) * D + h * 64 + g * 16 + dd] = f2b(oacc[dd]);
}

// ---------------- residual: expmap0(proj) -> mobius add -> LN2 chain (fp64 scalars) -----------
__global__ void k_resid(const float* __restrict__ x, const float* __restrict__ proj,
                        const float* __restrict__ cg, const float* __restrict__ s2,
                        const float* __restrict__ b2, float* __restrict__ xa,
                        ush* __restrict__ t2) {
  __shared__ double scratch[4];
  const int tok = blockIdx.x, t = threadIdx.x;
  const float* xr = x    + (size_t)tok * D;
  const float* pr = proj + (size_t)tok * D;
  float x0 = xr[t], x1 = xr[t + 256];
  float p0 = pr[t], p1 = pr[t + 256];
  double c = (double)cg[0];
  double sc = sqrt(c); if (sc < EPSd) sc = EPSd;
  double xx = block_sum((double)x0 * x0 + (double)x1 * x1, scratch);
  double pp = block_sum((double)p0 * p0 + (double)p1 * p1, scratch);
  double xp = block_sum((double)x0 * p0 + (double)x1 * p1, scratch);
  double pn = sqrt(pp);
  double me = tanh(sc * fmax(pn, EPSd)) / sc;
  double fs = (pn < EPSd) ? 0.0 : me / fmax(pn, EPSd);
  if (me >= 1.0) fs *= (1.0 - EPSd) / me;
  double y2 = fs * fs * pp, xy = fs * xp;
  double a = 1.0 + 2.0 * c * xy + c * y2;
  double b = 1.0 - c * xx;
  double den = 1.0 + 2.0 * c * xy + c * c * xx * y2;
  if (den < EPSd) den = EPSd;
  double zn = sqrt(fmax(a * a * xx + 2.0 * a * b * xy + b * b * y2, 0.0)) / den;
  double zs = 1.0 / den;
  if (zn >= 1.0) zs *= (1.0 - EPSd) / zn;
  double xan = (zn >= 1.0) ? (1.0 - EPSd) : zn;
  double A0 = zs * a, B0 = zs * b * fs;
  double xa0 = A0 * x0 + B0 * p0, xa1 = A0 * x1 + B0 * p1;
  xa[(size_t)tok * D + t]       = (float)xa0;
  xa[(size_t)tok * D + t + 256] = (float)xa1;
  double fl = 0.0;
  if (xan >= EPSd) fl = atanh(fmin(xan, 1.0 - EPSd)) / (sc * fmax(xan, EPSd));
  double u0 = fl * xa0, u1 = fl * xa1;
  double mu  = block_sum(u0 + u1, scratch) / D;
  double su2 = block_sum(u0 * u0 + u1 * u1, scratch);
  double rs = 1.0 / sqrt(su2 / D - mu * mu + 1e-6);
  double w0 = (u0 - mu) * rs * (double)s2[t]       + (double)b2[t];
  double w1 = (u1 - mu) * rs * (double)s2[t + 256] + (double)b2[t + 256];
  double vn = sqrt(block_sum(w0 * w0 + w1 * w1, scratch));
  double F = 0.0;
  if (vn >= EPSd) {
    double mag_e = tanh(sc * fmax(vn, EPSd)) / sc;
    F = atanh(fmin(mag_e, 1.0 - EPSd)) / (sc * vn);
  }
  t2[(size_t)tok * D + t]       = f2b((float)(F * w0));
  t2[(size_t)tok * D + t + 256] = f2b((float)(F * w1));
}

// ---------------- final: expmap0(ffn) -> mobius add -> out (fp64 scalars) ----------------
__global__ void k_final(const float* __restrict__ xa, const float* __restrict__ f2,
                        const float* __restrict__ cg, float* __restrict__ out) {
  __shared__ double scratch[4];
  const int tok = blockIdx.x, t = threadIdx.x;
  const float* ar = xa + (size_t)tok * D;
  const float* fr = f2 + (size_t)tok * D;
  float x0 = ar[t], x1 = ar[t + 256];
  float p0 = fr[t], p1 = fr[t + 256];
  double c = (double)cg[0];
  double sc = sqrt(c); if (sc < EPSd) sc = EPSd;
  double xx = block_sum((double)x0 * x0 + (double)x1 * x1, scratch);
  double pp = block_sum((double)p0 * p0 + (double)p1 * p1, scratch);
  double xp = block_sum((double)x0 * p0 + (double)x1 * p1, scratch);
  double pn = sqrt(pp);
  double me = tanh(sc * fmax(pn, EPSd)) / sc;
  double fs = (pn < EPSd) ? 0.0 : me / fmax(pn, EPSd);
  if (me >= 1.0) fs *= (1.0 - EPSd) / me;
  double y2 = fs * fs * pp, xy = fs * xp;
  double a = 1.0 + 2.0 * c * xy + c * y2;
  double b = 1.0 - c * xx;
  double den = 1.0 + 2.0 * c * xy + c * c * xx * y2;
  if (den < EPSd) den = EPSd;
  double zn = sqrt(fmax(a * a * xx + 2.0 * a * b * xy + b * b * y2, 0.0)) / den;
  double zs = 1.0 / den;
  if (zn >= 1.0) zs *= (1.0 - EPSd) / zn;
  double A0 = zs * a, B0 = zs * b * fs;
  out[(size_t)tok * D + t]       = (float)(A0 * x0 + B0 * p0);
  out[(size_t)tok * D + t + 256] = (float)(A0 * x1 + B0 * p1);
}

// ---------------- launch ----------------
extern "C" void kernel_launch(void* const* d_in, const int* in_sizes, int n_in,
                              void* d_out, int out_size, void* d_ws, size_t ws_size,
                              hipStream_t stream) {
  (void)in_sizes; (void)n_in; (void)out_size; (void)ws_size;
  const float* x    = (const float*)d_in[0];
  const float* cg   = (const float*)d_in[1];
  const float* Wqkv = (const float*)d_in[2];
  const float* bqkv = (const float*)d_in[3];
  const float* Wout = (const float*)d_in[4];
  const float* bout = (const float*)d_in[5];
  const float* s1   = (const float*)d_in[6];
  const float* b1   = (const float*)d_in[7];
  const float* s2   = (const float*)d_in[8];
  const float* b2   = (const float*)d_in[9];
  const float* Wff1 = (const float*)d_in[10];
  const float* bff1 = (const float*)d_in[11];
  const float* Wff2 = (const float*)d_in[12];
  const float* bff2 = (const float*)d_in[13];
  const float* chl  = (const float*)d_in[14];
  const float* geo  = (const float*)d_in[15];
  float* out = (float*)d_out;

  // ---- workspace layout (bytes), lifetime-overlaid; peak 15.5 MB ----
  char* base = (char*)d_ws;
  ush* WqkvT_h = (ush*)(base + 0);          // 1.5 MB  [dead after QKV gemm]
  ush* WqkvT_l = (ush*)(base + 1572864);    // 1.5 MB  [dead after QKV gemm]
  ush* WoutT   = (ush*)(base + 3145728);    // 0.5 MB  [dead after out-proj]
  ush* Wff1T   = (ush*)(base + 3670016);    // 2 MB
  ush* Wff2T   = (ush*)(base + 5767168);    // 2 MB
  const size_t R = 7864320;
  float* qkv  = (float*)(base + R);             // 6 MB [qkv gemm .. attn]
  ush*   xt_h = (ush*)(base + R + 6291456);     // 1 MB [pre .. qkv gemm]
  ush*   xt_l = (ush*)(base + R + 7340032);     // 1 MB
  ush*   ao   = xt_h;                           // 1 MB [attn .. out-proj]
  float* proj = (float*)(base + R);             // 2 MB [out-proj .. resid] (qkv slot)
  float* xa   = (float*)(base + 0);             // 2 MB [resid .. final]    (WqkvT slot)
  ush*   t2   = (ush*)(base + 2097152);         // 1 MB [resid .. ff1]      (WqkvT_l tail)
  ush*   h1   = (ush*)(base + R);               // 4 MB [ff1 .. ff2]        (qkv/proj slot)
  float* f2   = (float*)(base + R + 4194304);   // 2 MB [ff2 .. final]

  k_prep<<<3072, 256, 0, stream>>>(Wqkv, Wout, Wff1, Wff2,
                                   WqkvT_h, WqkvT_l, WoutT, Wff1T, Wff2T);
  k_pre<<<NTOK, 256, 0, stream>>>(x, cg, s1, b1, xt_h, xt_l);
  k_mm<1, 0, 0><<<dim3(1536 / 128, NTOK / 128), 256, 0, stream>>>(
      xt_h, xt_l, WqkvT_h, WqkvT_l, bqkv, qkv, nullptr, NTOK, 1536, 512);
  k_attn<<<NB * H, 256, 0, stream>>>(qkv, chl, geo, ao);
  k_mm<0, 0, 0><<<dim3(512 / 128, NTOK / 128), 256, 0, stream>>>(
      ao, nullptr, WoutT, nullptr, bout, proj, nullptr, NTOK, 512, 512);
  k_resid<<<NTOK, 256, 0, stream>>>(x, proj, cg, s2, b2, xa, t2);
  k_mm<0, 1, 1><<<dim3(2048 / 128, NTOK / 128), 256, 0, stream>>>(
      t2, nullptr, Wff1T, nullptr, bff1, nullptr, h1, NTOK, 2048, 512);
  k_mm<0, 0, 0><<<dim3(512 / 128, NTOK / 128), 256, 0, stream>>>(
      h1, nullptr, Wff2T, nullptr, bff2, f2, nullptr, NTOK, 512, 2048);
  k_final<<<NTOK, 256, 0, stream>>>(xa, f2, cg, out);
}

// Round 4
// 112.077 us; speedup vs baseline: 1.4911x; 1.4911x over previous
//
#include <hip/hip_runtime.h>
#include <math.h>

#define DEV __device__ __forceinline__
typedef _Float16 h16;
typedef __attribute__((ext_vector_type(8))) _Float16 h8v;  // 8 fp16 = 4 VGPR
typedef __attribute__((ext_vector_type(4))) float f4v;

constexpr int NTOK = 1024;
constexpr int D    = 512;
constexpr int H    = 8;
constexpr int NB   = 16;
constexpr double EPSd = 1e-7;

// ---------------- reductions ----------------
DEV double wave_sum(double v) {
#pragma unroll
  for (int m = 32; m; m >>= 1) v += __shfl_xor(v, m, 64);
  return v;
}
DEV double block_sum(double v, double* scratch) {
  v = wave_sum(v);
  __syncthreads();
  if ((threadIdx.x & 63) == 0) scratch[threadIdx.x >> 6] = v;
  __syncthreads();
  return scratch[0] + scratch[1] + scratch[2] + scratch[3];
}

// ---------------- merged: 4x weight transpose-cast (fp32[K][N] -> fp16[N][K]) + k_pre --------
__global__ void k_prep(const float* __restrict__ Wqkv, const float* __restrict__ Wout,
                       const float* __restrict__ Wff1, const float* __restrict__ Wff2,
                       const float* __restrict__ x, const float* __restrict__ cg,
                       const float* __restrict__ s1, const float* __restrict__ b1,
                       h16* __restrict__ qT, h16* __restrict__ oT,
                       h16* __restrict__ f1T, h16* __restrict__ f2T,
                       h16* __restrict__ xt) {
  __shared__ float t[32][33];
  __shared__ double scratch[4];
  const int bid = blockIdx.x;
  if (bid < 3072) {   // ---- transpose-cast ----
    const float* src; h16* dh; int K, N, bx, by;
    if (bid < 768)       { src = Wqkv; dh = qT;  K = 512;  N = 1536; bx = bid % 48;          by = bid / 48; }
    else if (bid < 1024) { src = Wout; dh = oT;  K = 512;  N = 512;  bx = (bid - 768) % 16;  by = (bid - 768) / 16; }
    else if (bid < 2048) { src = Wff1; dh = f1T; K = 512;  N = 2048; bx = (bid - 1024) % 64; by = (bid - 1024) / 64; }
    else                 { src = Wff2; dh = f2T; K = 2048; N = 512;  bx = (bid - 2048) % 16; by = (bid - 2048) / 16; }
    const int n0 = bx * 32, k0 = by * 32;
    const int tx = threadIdx.x & 31, ty = threadIdx.x >> 5;
    for (int i = ty; i < 32; i += 8) t[i][tx] = src[(size_t)(k0 + i) * N + n0 + tx];
    __syncthreads();
    for (int i = ty; i < 32; i += 8)
      dh[(size_t)(n0 + i) * K + k0 + tx] = (h16)t[tx][i];
    return;
  }
  // ---- k_pre: logmap0 -> LN -> expmap0 -> logmap0 (fused), fp64 scalars ----
  const int tok = bid - 3072, tt = threadIdx.x;
  const float* row = x + (size_t)tok * D;
  float v0 = row[tt], v1 = row[tt + 256];
  double c = (double)cg[0];
  double sc = sqrt(c); if (sc < EPSd) sc = EPSd;
  double yn = sqrt(block_sum((double)v0 * v0 + (double)v1 * v1, scratch));
  double arg0 = yn; if (arg0 > 1.0 - EPSd) arg0 = 1.0 - EPSd;
  double f = (yn < EPSd) ? 0.0 : atanh(arg0) / sc / fmax(yn, EPSd);
  double u0 = f * v0, u1 = f * v1;
  double mu  = block_sum(u0 + u1, scratch) / D;
  double su2 = block_sum(u0 * u0 + u1 * u1, scratch);
  double rs = 1.0 / sqrt(su2 / D - mu * mu + 1e-6);
  double w0 = (u0 - mu) * rs * (double)s1[tt]       + (double)b1[tt];
  double w1 = (u1 - mu) * rs * (double)s1[tt + 256] + (double)b1[tt + 256];
  double vn = sqrt(block_sum(w0 * w0 + w1 * w1, scratch));
  double F = 0.0;
  if (vn >= EPSd) {
    double mag_e = tanh(sc * fmax(vn, EPSd)) / sc;
    F = atanh(fmin(mag_e, 1.0 - EPSd)) / (sc * vn);
  }
  xt[(size_t)tok * D + tt]       = (h16)(float)(F * w0);
  xt[(size_t)tok * D + tt + 256] = (h16)(float)(F * w1);
}

// ---------------- fp16 MFMA GEMM, 64x64 tile, BK=64, global_load_lds + XOR swizzle ----------
// LDS linear [64][64] halves; content chunk c of row r stored at chunk position c^(r&7);
// achieved by pre-swizzling the per-lane GLOBAL source address (dest of global_load_lds is
// linear base + lane*16). Reads use the same XOR -> 2-way bank aliasing (free).
DEV void stage_tile(const h16* __restrict__ gbase, int rowstride, h16* lds,
                    int wid, int lane) {
#pragma unroll
  for (int j = 0; j < 2; ++j) {
    const int rbase = wid * 16 + j * 8;
    const int grow = rbase + (lane >> 3);
    const int gch = (lane & 7) ^ (lane >> 3);
    const h16* gp = gbase + (size_t)grow * rowstride + gch * 8;
    __builtin_amdgcn_global_load_lds(
        (const __attribute__((address_space(1))) void*)gp,
        (__attribute__((address_space(3))) void*)(lds + rbase * 64), 16, 0, 0);
  }
}
DEV h8v read_frag(const h16* lds, int row, int c) {
  const int p = c ^ (row & 7);
  return *(const h8v*)(lds + row * 64 + p * 8);
}

template <int GELU, int OHALF>
__global__ __launch_bounds__(256) void k_mm(
    const h16* __restrict__ A, const h16* __restrict__ B,
    const float* __restrict__ bias, float* __restrict__ Cf, h16* __restrict__ Ch,
    int M, int N, int K) {
  __shared__ __align__(16) h16 As[64 * 64];
  __shared__ __align__(16) h16 Bs[64 * 64];
  const int tid = threadIdx.x;
  const int lane = tid & 63, wid = tid >> 6;
  const int wr = (wid >> 1) * 32, wc = (wid & 1) * 32;
  const int lr = lane & 15, lg = lane >> 4;
  const size_t r0 = (size_t)blockIdx.y * 64, c0 = (size_t)blockIdx.x * 64;
  const f4v z = {0.f, 0.f, 0.f, 0.f};
  f4v acc[2][2]; acc[0][0] = z; acc[0][1] = z; acc[1][0] = z; acc[1][1] = z;
  const h16* Abase = A + r0 * K;
  const h16* Bbase = B + c0 * K;
  for (int k0 = 0; k0 < K; k0 += 64) {
    stage_tile(Abase + k0, K, As, wid, lane);
    stage_tile(Bbase + k0, K, Bs, wid, lane);
    __syncthreads();                     // drains vmcnt before reads
#pragma unroll
    for (int ks = 0; ks < 2; ++ks) {
      const int c = ks * 4 + lg;
      h8v a0 = read_frag(As, wr + lr, c);
      h8v a1 = read_frag(As, wr + 16 + lr, c);
      h8v b0 = read_frag(Bs, wc + lr, c);
      h8v b1 = read_frag(Bs, wc + 16 + lr, c);
      acc[0][0] = __builtin_amdgcn_mfma_f32_16x16x32_f16(a0, b0, acc[0][0], 0, 0, 0);
      acc[0][1] = __builtin_amdgcn_mfma_f32_16x16x32_f16(a0, b1, acc[0][1], 0, 0, 0);
      acc[1][0] = __builtin_amdgcn_mfma_f32_16x16x32_f16(a1, b0, acc[1][0], 0, 0, 0);
      acc[1][1] = __builtin_amdgcn_mfma_f32_16x16x32_f16(a1, b1, acc[1][1], 0, 0, 0);
    }
    __syncthreads();
  }
#pragma unroll
  for (int m = 0; m < 2; ++m)
#pragma unroll
    for (int n = 0; n < 2; ++n) {
      const size_t row = r0 + wr + m * 16 + lg * 4;
      const size_t col = c0 + wc + n * 16 + lr;
      const float bv = bias[col];
#pragma unroll
      for (int e = 0; e < 4; ++e) {
        float v = acc[m][n][e] + bv;
        if (GELU) {
          float x3 = v * v * v;
          v = 0.5f * v * (1.0f + tanhf(0.7978845608028654f * (v + 0.044715f * x3)));
        }
        if (OHALF) Ch[(row + e) * N + col] = (h16)v;
        else       Cf[(row + e) * N + col] = v;
      }
    }
}

// ---------------- attention: RoPE + per-head expmap0 + hyperbolic dist + softmax + PV (fp32) --
__global__ __launch_bounds__(256) void k_attn(
    const float* __restrict__ qkv, const float* __restrict__ chl,
    const float* __restrict__ geo, h16* __restrict__ ao) {
  __shared__ float Qs[64][65];
  __shared__ float Ks[64][65];
  __shared__ float q2s[64], k2s[64], fqv[64], fkv[64];
  const int be = blockIdx.x >> 3, h = blockIdx.x & 7;
  const int tid = threadIdx.x;
  const double chd = log1p(exp((double)chl[h]));   // softplus (once)
  const float ch = (float)chd;
  float sc = (float)sqrt(chd); if (sc < 1e-7f) sc = 1e-7f;
  for (int l = tid; l < 64 * 32; l += 256) {
    int s = l >> 5, j = l & 31;
    const float* base = qkv + (size_t)(be * 64 + s) * 1536 + h * 64;
    float qa = base[j],       qb = base[j + 32];
    float ka = base[512 + j], kb = base[512 + j + 32];
    float fj = expf((float)j * -0.2878231366242557f);   // ln(10000)/32
    float th = (float)s * fj;
    float st, ct; sincosf(th, &st, &ct);
    Qs[s][j]      = qa * ct - qb * st;
    Qs[s][j + 32] = qa * st + qb * ct;
    Ks[s][j]      = ka * ct - kb * st;
    Ks[s][j + 32] = ka * st + kb * ct;
  }
  __syncthreads();
  if (tid < 128) {
    int i = tid & 63;
    const float* P = (tid < 64) ? &Qs[i][0] : &Ks[i][0];
    float a = 0.f;
    for (int d2 = 0; d2 < 64; ++d2) { float v = P[d2]; a += v * v; }
    float n = sqrtf(a);
    float m = tanhf(sc * fmaxf(n, 1e-7f)) / sc;
    float f = (n < 1e-7f) ? 0.f : m / fmaxf(n, 1e-7f);
    if (m >= 1.f) f *= (1.f - 1e-7f) / m;
    float fn = f * n;
    if (tid < 64) { fqv[i] = f; q2s[i] = fn * fn; }
    else          { fkv[i] = f; k2s[i] = fn * fn; }
  }
  __syncthreads();
  const int i = tid >> 2, g = tid & 3;
  float gacc[16];
#pragma unroll
  for (int jj = 0; jj < 16; ++jj) gacc[jj] = 0.f;
  for (int d2 = 0; d2 < 64; ++d2) {
    float qv = Qs[i][d2];
#pragma unroll
    for (int jj = 0; jj < 16; ++jj) gacc[jj] += qv * Ks[g * 16 + jj][d2];
  }
  const float gs = geo[h];
  const float q2 = q2s[i], fqi = fqv[i];
  float lg[16];
  float mx = -1e30f;
#pragma unroll
  for (int jj = 0; jj < 16; ++jj) {
    float gq = fqi * fkv[g * 16 + jj] * gacc[jj];
    float k2 = k2s[g * 16 + jj];
    float A  = 1.f - 2.f * ch * gq + ch * k2;
    float Bv = 1.f - ch * q2;
    float n2 = fmaxf(A * A * q2 - 2.f * A * Bv * gq + Bv * Bv * k2, 0.f);
    float den = fmaxf(1.f - 2.f * ch * gq + ch * ch * q2 * k2, 1e-7f);
    float r = fminf(sqrtf(n2) / den, 1.f - 1e-7f);
    float arg = fminf(sc * r, 1.f - 1e-7f);
    float l = -gs * (2.f * atanhf(arg) / sc);
    lg[jj] = l; mx = fmaxf(mx, l);
  }
  mx = fmaxf(mx, __shfl_xor(mx, 1, 64));
  mx = fmaxf(mx, __shfl_xor(mx, 2, 64));
  float pv[16]; float sum = 0.f;
#pragma unroll
  for (int jj = 0; jj < 16; ++jj) { pv[jj] = expf(lg[jj] - mx); sum += pv[jj]; }
  sum += __shfl_xor(sum, 1, 64);
  sum += __shfl_xor(sum, 2, 64);
  float inv = 1.0f / sum;
  __syncthreads();
#pragma unroll
  for (int jj = 0; jj < 16; ++jj) Qs[i][g * 16 + jj] = pv[jj] * inv;
  for (int l = tid; l < 64 * 64; l += 256) {
    int s = l >> 6, d2 = l & 63;
    Ks[s][d2] = qkv[(size_t)(be * 64 + s) * 1536 + 1024 + h * 64 + d2];
  }
  __syncthreads();
  float oacc[16];
#pragma unroll
  for (int dd = 0; dd < 16; ++dd) oacc[dd] = 0.f;
  for (int jv = 0; jv < 64; ++jv) {
    float p = Qs[i][jv];
#pragma unroll
    for (int dd = 0; dd < 16; ++dd) oacc[dd] += p * Ks[jv][g * 16 + dd];
  }
#pragma unroll
  for (int dd = 0; dd < 16; ++dd)
    ao[(size_t)(be * 64 + i) * D + h * 64 + g * 16 + dd] = (h16)oacc[dd];
}

// ---------------- residual: expmap0(proj) -> mobius add -> LN2 chain (fp64 scalars) -----------
__global__ void k_resid(const float* __restrict__ x, const float* __restrict__ proj,
                        const float* __restrict__ cg, const float* __restrict__ s2,
                        const float* __restrict__ b2, float* __restrict__ xa,
                        h16* __restrict__ t2) {
  __shared__ double scratch[4];
  const int tok = blockIdx.x, t = threadIdx.x;
  const float* xr = x    + (size_t)tok * D;
  const float* pr = proj + (size_t)tok * D;
  float x0 = xr[t], x1 = xr[t + 256];
  float p0 = pr[t], p1 = pr[t + 256];
  double c = (double)cg[0];
  double sc = sqrt(c); if (sc < EPSd) sc = EPSd;
  double xx = block_sum((double)x0 * x0 + (double)x1 * x1, scratch);
  double pp = block_sum((double)p0 * p0 + (double)p1 * p1, scratch);
  double xp = block_sum((double)x0 * p0 + (double)x1 * p1, scratch);
  double pn = sqrt(pp);
  double me = tanh(sc * fmax(pn, EPSd)) / sc;
  double fs = (pn < EPSd) ? 0.0 : me / fmax(pn, EPSd);
  if (me >= 1.0) fs *= (1.0 - EPSd) / me;
  double y2 = fs * fs * pp, xy = fs * xp;
  double a = 1.0 + 2.0 * c * xy + c * y2;
  double b = 1.0 - c * xx;
  double den = 1.0 + 2.0 * c * xy + c * c * xx * y2;
  if (den < EPSd) den = EPSd;
  double zn = sqrt(fmax(a * a * xx + 2.0 * a * b * xy + b * b * y2, 0.0)) / den;
  double zs = 1.0 / den;
  if (zn >= 1.0) zs *= (1.0 - EPSd) / zn;
  double xan = (zn >= 1.0) ? (1.0 - EPSd) : zn;
  double A0 = zs * a, B0 = zs * b * fs;
  double xa0 = A0 * x0 + B0 * p0, xa1 = A0 * x1 + B0 * p1;
  xa[(size_t)tok * D + t]       = (float)xa0;
  xa[(size_t)tok * D + t + 256] = (float)xa1;
  double fl = 0.0;
  if (xan >= EPSd) fl = atanh(fmin(xan, 1.0 - EPSd)) / (sc * fmax(xan, EPSd));
  double u0 = fl * xa0, u1 = fl * xa1;
  double mu  = block_sum(u0 + u1, scratch) / D;
  double su2 = block_sum(u0 * u0 + u1 * u1, scratch);
  double rs = 1.0 / sqrt(su2 / D - mu * mu + 1e-6);
  double w0 = (u0 - mu) * rs * (double)s2[t]       + (double)b2[t];
  double w1 = (u1 - mu) * rs * (double)s2[t + 256] + (double)b2[t + 256];
  double vn = sqrt(block_sum(w0 * w0 + w1 * w1, scratch));
  double F = 0.0;
  if (vn >= EPSd) {
    double mag_e = tanh(sc * fmax(vn, EPSd)) / sc;
    F = atanh(fmin(mag_e, 1.0 - EPSd)) / (sc * vn);
  }
  t2[(size_t)tok * D + t]       = (h16)(float)(F * w0);
  t2[(size_t)tok * D + t + 256] = (h16)(float)(F * w1);
}

// ---------------- final: expmap0(ffn) -> mobius add -> out (fp64 scalars) ----------------
__global__ void k_final(const float* __restrict__ xa, const float* __restrict__ f2,
                        const float* __restrict__ cg, float* __restrict__ out) {
  __shared__ double scratch[4];
  const int tok = blockIdx.x, t = threadIdx.x;
  const float* ar = xa + (size_t)tok * D;
  const float* fr = f2 + (size_t)tok * D;
  float x0 = ar[t], x1 = ar[t + 256];
  float p0 = fr[t], p1 = fr[t + 256];
  double c = (double)cg[0];
  double sc = sqrt(c); if (sc < EPSd) sc = EPSd;
  double xx = block_sum((double)x0 * x0 + (double)x1 * x1, scratch);
  double pp = block_sum((double)p0 * p0 + (double)p1 * p1, scratch);
  double xp = block_sum((double)x0 * p0 + (double)x1 * p1, scratch);
  double pn = sqrt(pp);
  double me = tanh(sc * fmax(pn, EPSd)) / sc;
  double fs = (pn < EPSd) ? 0.0 : me / fmax(pn, EPSd);
  if (me >= 1.0) fs *= (1.0 - EPSd) / me;
  double y2 = fs * fs * pp, xy = fs * xp;
  double a = 1.0 + 2.0 * c * xy + c * y2;
  double b = 1.0 - c * xx;
  double den = 1.0 + 2.0 * c * xy + c * c * xx * y2;
  if (den < EPSd) den = EPSd;
  double zn = sqrt(fmax(a * a * xx + 2.0 * a * b * xy + b * b * y2, 0.0)) / den;
  double zs = 1.0 / den;
  if (zn >= 1.0) zs *= (1.0 - EPSd) / zn;
  double A0 = zs * a, B0 = zs * b * fs;
  out[(size_t)tok * D + t]       = (float)(A0 * x0 + B0 * p0);
  out[(size_t)tok * D + t + 256] = (float)(A0 * x1 + B0 * p1);
}

// ---------------- launch ----------------
extern "C" void kernel_launch(void* const* d_in, const int* in_sizes, int n_in,
                              void* d_out, int out_size, void* d_ws, size_t ws_size,
                              hipStream_t stream) {
  (void)in_sizes; (void)n_in; (void)out_size; (void)ws_size;
  const float* x    = (const float*)d_in[0];
  const float* cg   = (const float*)d_in[1];
  const float* Wqkv = (const float*)d_in[2];
  const float* bqkv = (const float*)d_in[3];
  const float* Wout = (const float*)d_in[4];
  const float* bout = (const float*)d_in[5];
  const float* s1   = (const float*)d_in[6];
  const float* b1   = (const float*)d_in[7];
  const float* s2   = (const float*)d_in[8];
  const float* b2   = (const float*)d_in[9];
  const float* Wff1 = (const float*)d_in[10];
  const float* bff1 = (const float*)d_in[11];
  const float* Wff2 = (const float*)d_in[12];
  const float* bff2 = (const float*)d_in[13];
  const float* chl  = (const float*)d_in[14];
  const float* geo  = (const float*)d_in[15];
  float* out = (float*)d_out;

  // ---- workspace layout (bytes), lifetime-overlaid; peak 13 MB ----
  char* base = (char*)d_ws;
  const size_t MB = 1024 * 1024;
  h16*   WqkvT = (h16*)(base + 0);            // 1.5 MB [prep .. qkv-mm]
  h16*   WoutT = (h16*)(base + (3*MB)/2);     // 0.5 MB [prep .. out-mm]
  h16*   Wff1T = (h16*)(base + 2*MB);         // 2 MB   [prep .. ff1-mm]
  h16*   Wff2T = (h16*)(base + 4*MB);         // 2 MB   [prep .. ff2-mm]
  h16*   xt    = (h16*)(base + 6*MB);         // 1 MB   [prep .. qkv-mm]
  float* qkv   = (float*)(base + 7*MB);       // 6 MB   [qkv-mm .. attn]
  h16*   ao    = (h16*)(base + 0);            // 1 MB   [attn .. out-mm]   (WqkvT slot)
  float* proj  = (float*)(base + 7*MB);       // 2 MB   [out-mm .. resid]  (qkv slot)
  float* xa    = (float*)(base + 0);          // 2 MB   [resid .. final]   (ao/WoutT slots)
  h16*   t2    = (h16*)(base + 6*MB);         // 1 MB   [resid .. ff1-mm]  (xt slot)
  h16*   h1    = (h16*)(base + 9*MB);         // 4 MB   [ff1-mm .. ff2-mm] (qkv tail)
  float* f2    = (float*)(base + 2*MB);       // 2 MB   [ff2-mm .. final]  (Wff1T slot)

  k_prep<<<4096, 256, 0, stream>>>(Wqkv, Wout, Wff1, Wff2, x, cg, s1, b1,
                                   WqkvT, WoutT, Wff1T, Wff2T, xt);
  k_mm<0, 0><<<dim3(1536 / 64, NTOK / 64), 256, 0, stream>>>(
      xt, WqkvT, bqkv, qkv, nullptr, NTOK, 1536, 512);
  k_attn<<<NB * H, 256, 0, stream>>>(qkv, chl, geo, ao);
  k_mm<0, 0><<<dim3(512 / 64, NTOK / 64), 256, 0, stream>>>(
      ao, WoutT, bout, proj, nullptr, NTOK, 512, 512);
  k_resid<<<NTOK, 256, 0, stream>>>(x, proj, cg, s2, b2, xa, t2);
  k_mm<1, 1><<<dim3(2048 / 64, NTOK / 64), 256, 0, stream>>>(
      t2, Wff1T, bff1, nullptr, h1, NTOK, 2048, 512);
  k_mm<0, 0><<<dim3(512 / 64, NTOK / 64), 256, 0, stream>>>(
      h1, Wff2T, bff2, f2, nullptr, NTOK, 512, 2048);
  k_final<<<NTOK, 256, 0, stream>>>(xa, f2, cg, out);
}

// Round 5
// 96.948 us; speedup vs baseline: 1.7238x; 1.1561x over previous
//
#include <hip/hip_runtime.h>
#include <math.h>

#define DEV __device__ __forceinline__
typedef _Float16 h16;
typedef __attribute__((ext_vector_type(8))) _Float16 h8v;  // 8 fp16 = 4 VGPR
typedef __attribute__((ext_vector_type(4))) float f4v;

constexpr int NTOK = 1024;
constexpr int D    = 512;
constexpr int H    = 8;
constexpr int NB   = 16;
constexpr double EPSd = 1e-7;

// ---------------- reductions ----------------
DEV double wave_sum(double v) {
#pragma unroll
  for (int m = 32; m; m >>= 1) v += __shfl_xor(v, m, 64);
  return v;
}
DEV double block_sum(double v, double* scratch) {
  v = wave_sum(v);
  __syncthreads();
  if ((threadIdx.x & 63) == 0) scratch[threadIdx.x >> 6] = v;
  __syncthreads();
  return scratch[0] + scratch[1] + scratch[2] + scratch[3];
}

// ---------------- merged: 4x weight transpose-cast (fp32[K][N] -> fp16[N][K]) + k_pre --------
__global__ void k_prep(const float* __restrict__ Wqkv, const float* __restrict__ Wout,
                       const float* __restrict__ Wff1, const float* __restrict__ Wff2,
                       const float* __restrict__ x, const float* __restrict__ cg,
                       const float* __restrict__ s1, const float* __restrict__ b1,
                       h16* __restrict__ qT, h16* __restrict__ oT,
                       h16* __restrict__ f1T, h16* __restrict__ f2T,
                       h16* __restrict__ xt) {
  __shared__ float t[32][33];
  __shared__ double scratch[4];
  const int bid = blockIdx.x;
  if (bid < 3072) {   // ---- transpose-cast ----
    const float* src; h16* dh; int K, N, bx, by;
    if (bid < 768)       { src = Wqkv; dh = qT;  K = 512;  N = 1536; bx = bid % 48;          by = bid / 48; }
    else if (bid < 1024) { src = Wout; dh = oT;  K = 512;  N = 512;  bx = (bid - 768) % 16;  by = (bid - 768) / 16; }
    else if (bid < 2048) { src = Wff1; dh = f1T; K = 512;  N = 2048; bx = (bid - 1024) % 64; by = (bid - 1024) / 64; }
    else                 { src = Wff2; dh = f2T; K = 2048; N = 512;  bx = (bid - 2048) % 16; by = (bid - 2048) / 16; }
    const int n0 = bx * 32, k0 = by * 32;
    const int tx = threadIdx.x & 31, ty = threadIdx.x >> 5;
    for (int i = ty; i < 32; i += 8) t[i][tx] = src[(size_t)(k0 + i) * N + n0 + tx];
    __syncthreads();
    for (int i = ty; i < 32; i += 8)
      dh[(size_t)(n0 + i) * K + k0 + tx] = (h16)t[tx][i];
    return;
  }
  // ---- k_pre: logmap0 -> LN -> expmap0 -> logmap0 (fused), fp64 scalars ----
  const int tok = bid - 3072, tt = threadIdx.x;
  const float* row = x + (size_t)tok * D;
  float v0 = row[tt], v1 = row[tt + 256];
  double c = (double)cg[0];
  double sc = sqrt(c); if (sc < EPSd) sc = EPSd;
  double yn = sqrt(block_sum((double)v0 * v0 + (double)v1 * v1, scratch));
  double arg0 = yn; if (arg0 > 1.0 - EPSd) arg0 = 1.0 - EPSd;
  double f = (yn < EPSd) ? 0.0 : atanh(arg0) / sc / fmax(yn, EPSd);
  double u0 = f * v0, u1 = f * v1;
  double mu  = block_sum(u0 + u1, scratch) / D;
  double su2 = block_sum(u0 * u0 + u1 * u1, scratch);
  double rs = 1.0 / sqrt(su2 / D - mu * mu + 1e-6);
  double w0 = (u0 - mu) * rs * (double)s1[tt]       + (double)b1[tt];
  double w1 = (u1 - mu) * rs * (double)s1[tt + 256] + (double)b1[tt + 256];
  double vn = sqrt(block_sum(w0 * w0 + w1 * w1, scratch));
  double F = 0.0;
  if (vn >= EPSd) {
    double mag_e = tanh(sc * fmax(vn, EPSd)) / sc;
    F = atanh(fmin(mag_e, 1.0 - EPSd)) / (sc * vn);
  }
  xt[(size_t)tok * D + tt]       = (h16)(float)(F * w0);
  xt[(size_t)tok * D + tt + 256] = (h16)(float)(F * w1);
}

// ---------------- fp16 MFMA GEMM, 64x64 tile, BK=64, 2-phase pipelined double-buffer --------
// LDS content chunk c of row r stored at chunk position c^(r&7) (pre-swizzled GLOBAL source;
// global_load_lds dest is linear base + lane*16). Reads apply the same XOR.
DEV void stage_tile(const h16* __restrict__ gbase, int rowstride, h16* lds,
                    int wid, int lane) {
#pragma unroll
  for (int j = 0; j < 2; ++j) {
    const int rbase = wid * 16 + j * 8;
    const int grow = rbase + (lane >> 3);
    const int gch = (lane & 7) ^ (lane >> 3);
    const h16* gp = gbase + (size_t)grow * rowstride + gch * 8;
    __builtin_amdgcn_global_load_lds(
        (const __attribute__((address_space(1))) void*)gp,
        (__attribute__((address_space(3))) void*)(lds + rbase * 64), 16, 0, 0);
  }
}
DEV h8v read_frag(const h16* lds, int row, int c) {
  const int p = c ^ (row & 7);
  return *(const h8v*)(lds + row * 64 + p * 8);
}

template <int GELU, int OHALF>
__global__ __launch_bounds__(256) void k_mm(
    const h16* __restrict__ A, const h16* __restrict__ B,
    const float* __restrict__ bias, float* __restrict__ Cf, h16* __restrict__ Ch,
    int M, int N, int K) {
  __shared__ __align__(16) h16 As[2][64 * 64];
  __shared__ __align__(16) h16 Bs[2][64 * 64];
  const int tid = threadIdx.x;
  const int lane = tid & 63, wid = tid >> 6;
  const int wr = (wid >> 1) * 32, wc = (wid & 1) * 32;
  const int lr = lane & 15, lg = lane >> 4;
  const size_t r0 = (size_t)blockIdx.y * 64, c0 = (size_t)blockIdx.x * 64;
  const f4v z = {0.f, 0.f, 0.f, 0.f};
  f4v acc[2][2]; acc[0][0] = z; acc[0][1] = z; acc[1][0] = z; acc[1][1] = z;
  const h16* Abase = A + r0 * K;
  const h16* Bbase = B + c0 * K;
  const int NT = K >> 6;
  stage_tile(Abase, K, As[0], wid, lane);
  stage_tile(Bbase, K, Bs[0], wid, lane);
  __syncthreads();
  int cur = 0;
  for (int t = 0; t < NT; ++t) {
    const int nxt = cur ^ 1;
    if (t + 1 < NT) {                       // issue next tile BEFORE compute
      stage_tile(Abase + (t + 1) * 64, K, As[nxt], wid, lane);
      stage_tile(Bbase + (t + 1) * 64, K, Bs[nxt], wid, lane);
    }
    const h16* Ac = As[cur];
    const h16* Bc = Bs[cur];
#pragma unroll
    for (int ks = 0; ks < 2; ++ks) {
      const int c = ks * 4 + lg;
      h8v a0 = read_frag(Ac, wr + lr, c);
      h8v a1 = read_frag(Ac, wr + 16 + lr, c);
      h8v b0 = read_frag(Bc, wc + lr, c);
      h8v b1 = read_frag(Bc, wc + 16 + lr, c);
      acc[0][0] = __builtin_amdgcn_mfma_f32_16x16x32_f16(a0, b0, acc[0][0], 0, 0, 0);
      acc[0][1] = __builtin_amdgcn_mfma_f32_16x16x32_f16(a0, b1, acc[0][1], 0, 0, 0);
      acc[1][0] = __builtin_amdgcn_mfma_f32_16x16x32_f16(a1, b0, acc[1][0], 0, 0, 0);
      acc[1][1] = __builtin_amdgcn_mfma_f32_16x16x32_f16(a1, b1, acc[1][1], 0, 0, 0);
    }
    __syncthreads();                        // drains next-tile vmcnt + LDS reads, one barrier
    cur = nxt;
  }
#pragma unroll
  for (int m = 0; m < 2; ++m)
#pragma unroll
    for (int n = 0; n < 2; ++n) {
      const size_t row = r0 + wr + m * 16 + lg * 4;
      const size_t col = c0 + wc + n * 16 + lr;
      const float bv = bias[col];
#pragma unroll
      for (int e = 0; e < 4; ++e) {
        float v = acc[m][n][e] + bv;
        if (GELU) {
          float x3 = v * v * v;
          v = 0.5f * v * (1.0f + tanhf(0.7978845608028654f * (v + 0.044715f * x3)));
        }
        if (OHALF) Ch[(row + e) * N + col] = (h16)v;
        else       Cf[(row + e) * N + col] = v;
      }
    }
}

// ---------------- attention: RoPE + per-head expmap0 + hyperbolic dist + softmax + PV (fp32) --
__global__ __launch_bounds__(256) void k_attn(
    const h16* __restrict__ qkv, const float* __restrict__ chl,
    const float* __restrict__ geo, h16* __restrict__ ao) {
  __shared__ __align__(16) float Qs[64][68];
  __shared__ __align__(16) float Kt[64][68];   // K transposed: Kt[d][s]
  __shared__ __align__(16) float Vs[64][68];
  __shared__ float q2s[64], k2s[64], fqv[64], fkv[64];
  const int be = blockIdx.x >> 3, h = blockIdx.x & 7;
  const int tid = threadIdx.x;
  const double chd = log1p(exp((double)chl[h]));   // softplus (once)
  const float ch = (float)chd;
  float sc = (float)sqrt(chd); if (sc < 1e-7f) sc = 1e-7f;
  // stage Q (RoPE), K^T (RoPE), V
  for (int l = tid; l < 64 * 32; l += 256) {
    int s = l >> 5, j = l & 31;
    const h16* base = qkv + (size_t)(be * 64 + s) * 1536 + h * 64;
    float qa = (float)base[j],       qb = (float)base[j + 32];
    float ka = (float)base[512 + j], kb = (float)base[512 + j + 32];
    float fj = expf((float)j * -0.2878231366242557f);   // ln(10000)/32
    float th = (float)s * fj;
    float st, ct; sincosf(th, &st, &ct);
    Qs[s][j]      = qa * ct - qb * st;
    Qs[s][j + 32] = qa * st + qb * ct;
    Kt[j][s]      = ka * ct - kb * st;
    Kt[j + 32][s] = ka * st + kb * ct;
    Vs[s][j]      = (float)base[1024 + j];
    Vs[s][j + 32] = (float)base[1024 + j + 32];
  }
  __syncthreads();
  // per-row expmap0 factors (rows kept unscaled; factors folded into Gram)
  if (tid < 128) {
    int i = tid & 63;
    float a = 0.f;
    if (tid < 64) { for (int d2 = 0; d2 < 64; ++d2) { float v = Qs[i][d2]; a += v * v; } }
    else          { for (int d2 = 0; d2 < 64; ++d2) { float v = Kt[d2][i]; a += v * v; } }
    float n = sqrtf(a);
    float m = tanhf(sc * fmaxf(n, 1e-7f)) / sc;
    float f = (n < 1e-7f) ? 0.f : m / fmaxf(n, 1e-7f);
    if (m >= 1.f) f *= (1.f - 1e-7f) / m;
    float fn = f * n;
    if (tid < 64) { fqv[i] = f; q2s[i] = fn * fn; }
    else          { fkv[i] = f; k2s[i] = fn * fn; }
  }
  __syncthreads();
  const int i = tid >> 2, g = tid & 3;
  float gacc[16];
#pragma unroll
  for (int jj = 0; jj < 16; ++jj) gacc[jj] = 0.f;
  for (int d2 = 0; d2 < 64; ++d2) {
    float qv = Qs[i][d2];
    const float4* kp = (const float4*)&Kt[d2][g * 16];
    float4 k0 = kp[0], k1 = kp[1], k2 = kp[2], k3 = kp[3];
    gacc[0] += qv * k0.x; gacc[1] += qv * k0.y; gacc[2] += qv * k0.z; gacc[3] += qv * k0.w;
    gacc[4] += qv * k1.x; gacc[5] += qv * k1.y; gacc[6] += qv * k1.z; gacc[7] += qv * k1.w;
    gacc[8] += qv * k2.x; gacc[9] += qv * k2.y; gacc[10] += qv * k2.z; gacc[11] += qv * k2.w;
    gacc[12] += qv * k3.x; gacc[13] += qv * k3.y; gacc[14] += qv * k3.z; gacc[15] += qv * k3.w;
  }
  const float gs = geo[h];
  const float q2 = q2s[i], fqi = fqv[i];
  float lg[16];
  float mx = -1e30f;
#pragma unroll
  for (int jj = 0; jj < 16; ++jj) {
    float gq = fqi * fkv[g * 16 + jj] * gacc[jj];
    float k2 = k2s[g * 16 + jj];
    float A  = 1.f - 2.f * ch * gq + ch * k2;
    float Bv = 1.f - ch * q2;
    float n2 = fmaxf(A * A * q2 - 2.f * A * Bv * gq + Bv * Bv * k2, 0.f);
    float den = fmaxf(1.f - 2.f * ch * gq + ch * ch * q2 * k2, 1e-7f);
    float r = fminf(sqrtf(n2) / den, 1.f - 1e-7f);
    float arg = fminf(sc * r, 1.f - 1e-7f);
    float l = -gs * (2.f * atanhf(arg) / sc);
    lg[jj] = l; mx = fmaxf(mx, l);
  }
  mx = fmaxf(mx, __shfl_xor(mx, 1, 64));
  mx = fmaxf(mx, __shfl_xor(mx, 2, 64));
  float pv[16]; float sum = 0.f;
#pragma unroll
  for (int jj = 0; jj < 16; ++jj) { pv[jj] = expf(lg[jj] - mx); sum += pv[jj]; }
  sum += __shfl_xor(sum, 1, 64);
  sum += __shfl_xor(sum, 2, 64);
  float inv = 1.0f / sum;
  __syncthreads();                         // done with Qs as scores input
#pragma unroll
  for (int jj = 0; jj < 16; ++jj) Qs[i][g * 16 + jj] = pv[jj] * inv;
  __syncthreads();
  float oacc[16];
#pragma unroll
  for (int dd = 0; dd < 16; ++dd) oacc[dd] = 0.f;
  for (int jv = 0; jv < 64; ++jv) {
    float p = Qs[i][jv];
    const float4* vp = (const float4*)&Vs[jv][g * 16];
    float4 v0 = vp[0], v1 = vp[1], v2 = vp[2], v3 = vp[3];
    oacc[0] += p * v0.x; oacc[1] += p * v0.y; oacc[2] += p * v0.z; oacc[3] += p * v0.w;
    oacc[4] += p * v1.x; oacc[5] += p * v1.y; oacc[6] += p * v1.z; oacc[7] += p * v1.w;
    oacc[8] += p * v2.x; oacc[9] += p * v2.y; oacc[10] += p * v2.z; oacc[11] += p * v2.w;
    oacc[12] += p * v3.x; oacc[13] += p * v3.y; oacc[14] += p * v3.z; oacc[15] += p * v3.w;
  }
#pragma unroll
  for (int dd = 0; dd < 16; ++dd)
    ao[(size_t)(be * 64 + i) * D + h * 64 + g * 16 + dd] = (h16)oacc[dd];
}

// ---------------- residual: expmap0(proj) -> mobius add -> LN2 chain (fp64 scalars) -----------
__global__ void k_resid(const float* __restrict__ x, const float* __restrict__ proj,
                        const float* __restrict__ cg, const float* __restrict__ s2,
                        const float* __restrict__ b2, float* __restrict__ xa,
                        h16* __restrict__ t2) {
  __shared__ double scratch[4];
  const int tok = blockIdx.x, t = threadIdx.x;
  const float* xr = x    + (size_t)tok * D;
  const float* pr = proj + (size_t)tok * D;
  float x0 = xr[t], x1 = xr[t + 256];
  float p0 = pr[t], p1 = pr[t + 256];
  double c = (double)cg[0];
  double sc = sqrt(c); if (sc < EPSd) sc = EPSd;
  double xx = block_sum((double)x0 * x0 + (double)x1 * x1, scratch);
  double pp = block_sum((double)p0 * p0 + (double)p1 * p1, scratch);
  double xp = block_sum((double)x0 * p0 + (double)x1 * p1, scratch);
  double pn = sqrt(pp);
  double me = tanh(sc * fmax(pn, EPSd)) / sc;
  double fs = (pn < EPSd) ? 0.0 : me / fmax(pn, EPSd);
  if (me >= 1.0) fs *= (1.0 - EPSd) / me;
  double y2 = fs * fs * pp, xy = fs * xp;
  double a = 1.0 + 2.0 * c * xy + c * y2;
  double b = 1.0 - c * xx;
  double den = 1.0 + 2.0 * c * xy + c * c * xx * y2;
  if (den < EPSd) den = EPSd;
  double zn = sqrt(fmax(a * a * xx + 2.0 * a * b * xy + b * b * y2, 0.0)) / den;
  double zs = 1.0 / den;
  if (zn >= 1.0) zs *= (1.0 - EPSd) / zn;
  double xan = (zn >= 1.0) ? (1.0 - EPSd) : zn;
  double A0 = zs * a, B0 = zs * b * fs;
  double xa0 = A0 * x0 + B0 * p0, xa1 = A0 * x1 + B0 * p1;
  xa[(size_t)tok * D + t]       = (float)xa0;
  xa[(size_t)tok * D + t + 256] = (float)xa1;
  double fl = 0.0;
  if (xan >= EPSd) fl = atanh(fmin(xan, 1.0 - EPSd)) / (sc * fmax(xan, EPSd));
  double u0 = fl * xa0, u1 = fl * xa1;
  double mu  = block_sum(u0 + u1, scratch) / D;
  double su2 = block_sum(u0 * u0 + u1 * u1, scratch);
  double rs = 1.0 / sqrt(su2 / D - mu * mu + 1e-6);
  double w0 = (u0 - mu) * rs * (double)s2[t]       + (double)b2[t];
  double w1 = (u1 - mu) * rs * (double)s2[t + 256] + (double)b2[t + 256];
  double vn = sqrt(block_sum(w0 * w0 + w1 * w1, scratch));
  double F = 0.0;
  if (vn >= EPSd) {
    double mag_e = tanh(sc * fmax(vn, EPSd)) / sc;
    F = atanh(fmin(mag_e, 1.0 - EPSd)) / (sc * vn);
  }
  t2[(size_t)tok * D + t]       = (h16)(float)(F * w0);
  t2[(size_t)tok * D + t + 256] = (h16)(float)(F * w1);
}

// ---------------- final: expmap0(ffn) -> mobius add -> out (fp64 scalars) ----------------
__global__ void k_final(const float* __restrict__ xa, const float* __restrict__ f2,
                        const float* __restrict__ cg, float* __restrict__ out) {
  __shared__ double scratch[4];
  const int tok = blockIdx.x, t = threadIdx.x;
  const float* ar = xa + (size_t)tok * D;
  const float* fr = f2 + (size_t)tok * D;
  float x0 = ar[t], x1 = ar[t + 256];
  float p0 = fr[t], p1 = fr[t + 256];
  double c = (double)cg[0];
  double sc = sqrt(c); if (sc < EPSd) sc = EPSd;
  double xx = block_sum((double)x0 * x0 + (double)x1 * x1, scratch);
  double pp = block_sum((double)p0 * p0 + (double)p1 * p1, scratch);
  double xp = block_sum((double)x0 * p0 + (double)x1 * p1, scratch);
  double pn = sqrt(pp);
  double me = tanh(sc * fmax(pn, EPSd)) / sc;
  double fs = (pn < EPSd) ? 0.0 : me / fmax(pn, EPSd);
  if (me >= 1.0) fs *= (1.0 - EPSd) / me;
  double y2 = fs * fs * pp, xy = fs * xp;
  double a = 1.0 + 2.0 * c * xy + c * y2;
  double b = 1.0 - c * xx;
  double den = 1.0 + 2.0 * c * xy + c * c * xx * y2;
  if (den < EPSd) den = EPSd;
  double zn = sqrt(fmax(a * a * xx + 2.0 * a * b * xy + b * b * y2, 0.0)) / den;
  double zs = 1.0 / den;
  if (zn >= 1.0) zs *= (1.0 - EPSd) / zn;
  double A0 = zs * a, B0 = zs * b * fs;
  out[(size_t)tok * D + t]       = (float)(A0 * x0 + B0 * p0);
  out[(size_t)tok * D + t + 256] = (float)(A0 * x1 + B0 * p1);
}

// ---------------- launch ----------------
extern "C" void kernel_launch(void* const* d_in, const int* in_sizes, int n_in,
                              void* d_out, int out_size, void* d_ws, size_t ws_size,
                              hipStream_t stream) {
  (void)in_sizes; (void)n_in; (void)out_size; (void)ws_size;
  const float* x    = (const float*)d_in[0];
  const float* cg   = (const float*)d_in[1];
  const float* Wqkv = (const float*)d_in[2];
  const float* bqkv = (const float*)d_in[3];
  const float* Wout = (const float*)d_in[4];
  const float* bout = (const float*)d_in[5];
  const float* s1   = (const float*)d_in[6];
  const float* b1   = (const float*)d_in[7];
  const float* s2   = (const float*)d_in[8];
  const float* b2   = (const float*)d_in[9];
  const float* Wff1 = (const float*)d_in[10];
  const float* bff1 = (const float*)d_in[11];
  const float* Wff2 = (const float*)d_in[12];
  const float* bff2 = (const float*)d_in[13];
  const float* chl  = (const float*)d_in[14];
  const float* geo  = (const float*)d_in[15];
  float* out = (float*)d_out;

  // ---- workspace layout (MB offsets), lifetime-overlaid; peak 15 MB ----
  char* base = (char*)d_ws;
  const size_t MB = 1024 * 1024;
  h16*   WqkvT = (h16*)(base + 0);            // 1.5 [prep .. qkv-mm]
  h16*   WoutT = (h16*)(base + (3*MB)/2);     // 0.5 [prep .. out-mm]
  h16*   Wff1T = (h16*)(base + 2*MB);         // 2   [prep .. ff1-mm]
  h16*   Wff2T = (h16*)(base + 4*MB);         // 2   [prep .. ff2-mm]
  h16*   xt    = (h16*)(base + 6*MB);         // 1   [prep .. qkv-mm]
  h16*   qkv   = (h16*)(base + 7*MB);         // 3   [qkv-mm .. attn]
  h16*   ao    = (h16*)(base + 10*MB);        // 1   [attn .. out-mm]
  float* proj  = (float*)(base + 11*MB);      // 2   [out-mm .. resid]
  float* xa    = (float*)(base + 13*MB);      // 2   [resid .. final]
  h16*   t2    = (h16*)(base + 6*MB);         // 1   [resid .. ff1-mm]  (xt slot)
  h16*   h1    = (h16*)(base + 7*MB);         // 4   [ff1-mm .. ff2-mm] (qkv+ao slots)
  float* f2    = (float*)(base + 0);          // 2   [ff2-mm .. final]  (WqkvT/WoutT slots)

  k_prep<<<4096, 256, 0, stream>>>(Wqkv, Wout, Wff1, Wff2, x, cg, s1, b1,
                                   WqkvT, WoutT, Wff1T, Wff2T, xt);
  k_mm<0, 1><<<dim3(1536 / 64, NTOK / 64), 256, 0, stream>>>(
      xt, WqkvT, bqkv, nullptr, qkv, NTOK, 1536, 512);
  k_attn<<<NB * H, 256, 0, stream>>>(qkv, chl, geo, ao);
  k_mm<0, 0><<<dim3(512 / 64, NTOK / 64), 256, 0, stream>>>(
      ao, WoutT, bout, proj, nullptr, NTOK, 512, 512);
  k_resid<<<NTOK, 256, 0, stream>>>(x, proj, cg, s2, b2, xa, t2);
  k_mm<1, 1><<<dim3(2048 / 64, NTOK / 64), 256, 0, stream>>>(
      t2, Wff1T, bff1, nullptr, h1, NTOK, 2048, 512);
  k_mm<0, 0><<<dim3(512 / 64, NTOK / 64), 256, 0, stream>>>(
      h1, Wff2T, bff2, f2, nullptr, NTOK, 512, 2048);
  k_final<<<NTOK, 256, 0, stream>>>(xa, f2, cg, out);
}

// Round 6
// 78.010 us; speedup vs baseline: 2.1422x; 1.2428x over previous
//
#include <hip/hip_runtime.h>
#include <math.h>

#define DEV __device__ __forceinline__
typedef _Float16 h16;
typedef __attribute__((ext_vector_type(8))) _Float16 h8v;  // 8 fp16 = 4 VGPR
typedef __attribute__((ext_vector_type(4))) _Float16 h4v;  // 8-byte fp16 store
typedef __attribute__((ext_vector_type(4))) float f4v;

constexpr int NTOK = 1024;
constexpr int D    = 512;
constexpr int H    = 8;
constexpr int NB   = 16;
constexpr double EPSd = 1e-7;

// ---------------- wave reduction (row fully owned by one wave; no barriers) ----------------
DEV double wave_sum(double v) {
#pragma unroll
  for (int m = 32; m; m >>= 1) v += __shfl_xor(v, m, 64);
  return v;
}

// ---------------- merged: 4x weight transpose-cast (fp32[K][N] -> fp16[N][K]) + pre --------
__global__ void k_prep(const float* __restrict__ Wqkv, const float* __restrict__ Wout,
                       const float* __restrict__ Wff1, const float* __restrict__ Wff2,
                       const float* __restrict__ x, const float* __restrict__ cg,
                       const float* __restrict__ s1, const float* __restrict__ b1,
                       h16* __restrict__ qT, h16* __restrict__ oT,
                       h16* __restrict__ f1T, h16* __restrict__ f2T,
                       h16* __restrict__ xt) {
  __shared__ float t[32][33];
  const int bid = blockIdx.x;
  if (bid < 3072) {   // ---- transpose-cast ----
    const float* src; h16* dh; int K, N, bx, by;
    if (bid < 768)       { src = Wqkv; dh = qT;  K = 512;  N = 1536; bx = bid % 48;          by = bid / 48; }
    else if (bid < 1024) { src = Wout; dh = oT;  K = 512;  N = 512;  bx = (bid - 768) % 16;  by = (bid - 768) / 16; }
    else if (bid < 2048) { src = Wff1; dh = f1T; K = 512;  N = 2048; bx = (bid - 1024) % 64; by = (bid - 1024) / 64; }
    else                 { src = Wff2; dh = f2T; K = 2048; N = 512;  bx = (bid - 2048) % 16; by = (bid - 2048) / 16; }
    const int n0 = bx * 32, k0 = by * 32;
    const int tx = threadIdx.x & 31, ty = threadIdx.x >> 5;
    for (int i = ty; i < 32; i += 8) t[i][tx] = src[(size_t)(k0 + i) * N + n0 + tx];
    __syncthreads();
    for (int i = ty; i < 32; i += 8)
      dh[(size_t)(n0 + i) * K + k0 + tx] = (h16)t[tx][i];
    return;
  }
  // ---- pre: logmap0 -> LN -> expmap0 -> logmap0 (fused), one WAVE per token row ----
  const int wid = threadIdx.x >> 6, lane = threadIdx.x & 63;
  const int tok = (bid - 3072) * 4 + wid;
  const float4* xr = (const float4*)(x + (size_t)tok * D);
  float4 xv0 = xr[lane], xv1 = xr[lane + 64];
  double sv = 0.0, svv = 0.0;
  {
    const float e[8] = {xv0.x, xv0.y, xv0.z, xv0.w, xv1.x, xv1.y, xv1.z, xv1.w};
#pragma unroll
    for (int j = 0; j < 8; ++j) { double d = e[j]; sv += d; svv += d * d; }
  }
  sv = wave_sum(sv); svv = wave_sum(svv);
  double c = (double)cg[0];
  double sc = sqrt(c); if (sc < EPSd) sc = EPSd;
  double yn = sqrt(svv);
  double arg0 = yn; if (arg0 > 1.0 - EPSd) arg0 = 1.0 - EPSd;
  double f = (yn < EPSd) ? 0.0 : atanh(arg0) / sc / fmax(yn, EPSd);
  double mu = f * sv / D;
  double var = f * f * svv / D - mu * mu;
  double rs = 1.0 / sqrt(var + 1e-6);
  const float4* s1r = (const float4*)s1;
  const float4* b1r = (const float4*)b1;
  float4 sA = s1r[lane], sB = s1r[lane + 64];
  float4 bA = b1r[lane], bB = b1r[lane + 64];
  double w[8]; double sww = 0.0;
  {
    const float e[8]  = {xv0.x, xv0.y, xv0.z, xv0.w, xv1.x, xv1.y, xv1.z, xv1.w};
    const float se[8] = {sA.x, sA.y, sA.z, sA.w, sB.x, sB.y, sB.z, sB.w};
    const float be[8] = {bA.x, bA.y, bA.z, bA.w, bB.x, bB.y, bB.z, bB.w};
#pragma unroll
    for (int j = 0; j < 8; ++j) {
      w[j] = (f * (double)e[j] - mu) * rs * (double)se[j] + (double)be[j];
      sww += w[j] * w[j];
    }
  }
  sww = wave_sum(sww);
  double vn = sqrt(sww);
  double F = 0.0;
  if (vn >= EPSd) {
    double mag_e = tanh(sc * fmax(vn, EPSd)) / sc;
    F = atanh(fmin(mag_e, 1.0 - EPSd)) / (sc * vn);
  }
  h16* dst = xt + (size_t)tok * D;
#pragma unroll
  for (int half = 0; half < 2; ++half) {
    h4v o;
#pragma unroll
    for (int e = 0; e < 4; ++e) o[e] = (h16)(float)(F * w[half * 4 + e]);
    *(h4v*)(dst + 4 * (lane + 64 * half)) = o;
  }
}

// ---------------- fp16 MFMA GEMM, 64x64 tile, BK=64, 2-phase pipelined double-buffer --------
// LDS content chunk c of row r stored at chunk position c^(r&7) (pre-swizzled GLOBAL source;
// global_load_lds dest is linear base + lane*16). Reads apply the same XOR.
DEV void stage_tile(const h16* __restrict__ gbase, int rowstride, h16* lds,
                    int wid, int lane) {
#pragma unroll
  for (int j = 0; j < 2; ++j) {
    const int rbase = wid * 16 + j * 8;
    const int grow = rbase + (lane >> 3);
    const int gch = (lane & 7) ^ (lane >> 3);
    const h16* gp = gbase + (size_t)grow * rowstride + gch * 8;
    __builtin_amdgcn_global_load_lds(
        (const __attribute__((address_space(1))) void*)gp,
        (__attribute__((address_space(3))) void*)(lds + rbase * 64), 16, 0, 0);
  }
}
DEV h8v read_frag(const h16* lds, int row, int c) {
  const int p = c ^ (row & 7);
  return *(const h8v*)(lds + row * 64 + p * 8);
}

// SPLITK: grid.z pieces over K; piece z writes Cf + z*M*N (fp32), bias only in piece 0.
template <int GELU, int OHALF, int SPLITK>
__global__ __launch_bounds__(256) void k_mm(
    const h16* __restrict__ A, const h16* __restrict__ B,
    const float* __restrict__ bias, float* __restrict__ Cf, h16* __restrict__ Ch,
    int M, int N, int K) {
  __shared__ __align__(16) h16 As[2][64 * 64];
  __shared__ __align__(16) h16 Bs[2][64 * 64];
  const int tid = threadIdx.x;
  const int lane = tid & 63, wid = tid >> 6;
  const int wr = (wid >> 1) * 32, wc = (wid & 1) * 32;
  const int lr = lane & 15, lg = lane >> 4;
  const size_t r0 = (size_t)blockIdx.y * 64, c0 = (size_t)blockIdx.x * 64;
  const int kz = SPLITK ? blockIdx.z : 0;
  const int Keff = SPLITK ? (K >> 1) : K;
  const f4v z = {0.f, 0.f, 0.f, 0.f};
  f4v acc[2][2]; acc[0][0] = z; acc[0][1] = z; acc[1][0] = z; acc[1][1] = z;
  const h16* Abase = A + r0 * K + (size_t)kz * Keff;
  const h16* Bbase = B + c0 * K + (size_t)kz * Keff;
  const int NT = Keff >> 6;
  stage_tile(Abase, K, As[0], wid, lane);
  stage_tile(Bbase, K, Bs[0], wid, lane);
  __syncthreads();
  int cur = 0;
  for (int t = 0; t < NT; ++t) {
    const int nxt = cur ^ 1;
    if (t + 1 < NT) {                       // issue next tile BEFORE compute
      stage_tile(Abase + (t + 1) * 64, K, As[nxt], wid, lane);
      stage_tile(Bbase + (t + 1) * 64, K, Bs[nxt], wid, lane);
    }
    const h16* Ac = As[cur];
    const h16* Bc = Bs[cur];
#pragma unroll
    for (int ks = 0; ks < 2; ++ks) {
      const int c = ks * 4 + lg;
      h8v a0 = read_frag(Ac, wr + lr, c);
      h8v a1 = read_frag(Ac, wr + 16 + lr, c);
      h8v b0 = read_frag(Bc, wc + lr, c);
      h8v b1 = read_frag(Bc, wc + 16 + lr, c);
      acc[0][0] = __builtin_amdgcn_mfma_f32_16x16x32_f16(a0, b0, acc[0][0], 0, 0, 0);
      acc[0][1] = __builtin_amdgcn_mfma_f32_16x16x32_f16(a0, b1, acc[0][1], 0, 0, 0);
      acc[1][0] = __builtin_amdgcn_mfma_f32_16x16x32_f16(a1, b0, acc[1][0], 0, 0, 0);
      acc[1][1] = __builtin_amdgcn_mfma_f32_16x16x32_f16(a1, b1, acc[1][1], 0, 0, 0);
    }
    __syncthreads();                        // drains next-tile vmcnt + LDS reads, one barrier
    cur = nxt;
  }
  float* Cfo = Cf + (size_t)kz * M * N;
#pragma unroll
  for (int m = 0; m < 2; ++m)
#pragma unroll
    for (int n = 0; n < 2; ++n) {
      const size_t row = r0 + wr + m * 16 + lg * 4;
      const size_t col = c0 + wc + n * 16 + lr;
      const float bv = (SPLITK && kz) ? 0.f : bias[col];
#pragma unroll
      for (int e = 0; e < 4; ++e) {
        float v = acc[m][n][e] + bv;
        if (GELU) {
          float x3 = v * v * v;
          v = 0.5f * v * (1.0f + tanhf(0.7978845608028654f * (v + 0.044715f * x3)));
        }
        if (OHALF) Ch[(row + e) * N + col] = (h16)v;
        else       Cfo[(row + e) * N + col] = v;
      }
    }
}

// ---------------- attention: RoPE + per-head expmap0 + hyperbolic dist + softmax + PV (fp32) --
__global__ __launch_bounds__(256) void k_attn(
    const h16* __restrict__ qkv, const float* __restrict__ chl,
    const float* __restrict__ geo, h16* __restrict__ ao) {
  __shared__ __align__(16) float Qs[64][68];
  __shared__ __align__(16) float Kt[64][68];   // K transposed: Kt[d][s]
  __shared__ __align__(16) float Vs[64][68];
  __shared__ float q2s[64], k2s[64], fqv[64], fkv[64];
  const int be = blockIdx.x >> 3, h = blockIdx.x & 7;
  const int tid = threadIdx.x;
  const double chd = log1p(exp((double)chl[h]));   // softplus (once)
  const float ch = (float)chd;
  float sc = (float)sqrt(chd); if (sc < 1e-7f) sc = 1e-7f;
  // stage Q (RoPE), K^T (RoPE), V
  for (int l = tid; l < 64 * 32; l += 256) {
    int s = l >> 5, j = l & 31;
    const h16* base = qkv + (size_t)(be * 64 + s) * 1536 + h * 64;
    float qa = (float)base[j],       qb = (float)base[j + 32];
    float ka = (float)base[512 + j], kb = (float)base[512 + j + 32];
    float fj = expf((float)j * -0.2878231366242557f);   // ln(10000)/32
    float th = (float)s * fj;
    float st, ct; sincosf(th, &st, &ct);
    Qs[s][j]      = qa * ct - qb * st;
    Qs[s][j + 32] = qa * st + qb * ct;
    Kt[j][s]      = ka * ct - kb * st;
    Kt[j + 32][s] = ka * st + kb * ct;
    Vs[s][j]      = (float)base[1024 + j];
    Vs[s][j + 32] = (float)base[1024 + j + 32];
  }
  __syncthreads();
  // per-row expmap0 factors (rows kept unscaled; factors folded into Gram)
  if (tid < 128) {
    int i = tid & 63;
    float a = 0.f;
    if (tid < 64) { for (int d2 = 0; d2 < 64; ++d2) { float v = Qs[i][d2]; a += v * v; } }
    else          { for (int d2 = 0; d2 < 64; ++d2) { float v = Kt[d2][i]; a += v * v; } }
    float n = sqrtf(a);
    float m = tanhf(sc * fmaxf(n, 1e-7f)) / sc;
    float f = (n < 1e-7f) ? 0.f : m / fmaxf(n, 1e-7f);
    if (m >= 1.f) f *= (1.f - 1e-7f) / m;
    float fn = f * n;
    if (tid < 64) { fqv[i] = f; q2s[i] = fn * fn; }
    else          { fkv[i] = f; k2s[i] = fn * fn; }
  }
  __syncthreads();
  const int i = tid >> 2, g = tid & 3;
  float gacc[16];
#pragma unroll
  for (int jj = 0; jj < 16; ++jj) gacc[jj] = 0.f;
  for (int d2 = 0; d2 < 64; ++d2) {
    float qv = Qs[i][d2];
    const float4* kp = (const float4*)&Kt[d2][g * 16];
    float4 k0 = kp[0], k1 = kp[1], k2 = kp[2], k3 = kp[3];
    gacc[0] += qv * k0.x; gacc[1] += qv * k0.y; gacc[2] += qv * k0.z; gacc[3] += qv * k0.w;
    gacc[4] += qv * k1.x; gacc[5] += qv * k1.y; gacc[6] += qv * k1.z; gacc[7] += qv * k1.w;
    gacc[8] += qv * k2.x; gacc[9] += qv * k2.y; gacc[10] += qv * k2.z; gacc[11] += qv * k2.w;
    gacc[12] += qv * k3.x; gacc[13] += qv * k3.y; gacc[14] += qv * k3.z; gacc[15] += qv * k3.w;
  }
  const float gs = geo[h];
  const float q2 = q2s[i], fqi = fqv[i];
  float lg[16];
  float mx = -1e30f;
#pragma unroll
  for (int jj = 0; jj < 16; ++jj) {
    float gq = fqi * fkv[g * 16 + jj] * gacc[jj];
    float k2 = k2s[g * 16 + jj];
    float A  = 1.f - 2.f * ch * gq + ch * k2;
    float Bv = 1.f - ch * q2;
    float n2 = fmaxf(A * A * q2 - 2.f * A * Bv * gq + Bv * Bv * k2, 0.f);
    float den = fmaxf(1.f - 2.f * ch * gq + ch * ch * q2 * k2, 1e-7f);
    float r = fminf(sqrtf(n2) / den, 1.f - 1e-7f);
    float arg = fminf(sc * r, 1.f - 1e-7f);
    float l = -gs * (2.f * atanhf(arg) / sc);
    lg[jj] = l; mx = fmaxf(mx, l);
  }
  mx = fmaxf(mx, __shfl_xor(mx, 1, 64));
  mx = fmaxf(mx, __shfl_xor(mx, 2, 64));
  float pv[16]; float sum = 0.f;
#pragma unroll
  for (int jj = 0; jj < 16; ++jj) { pv[jj] = expf(lg[jj] - mx); sum += pv[jj]; }
  sum += __shfl_xor(sum, 1, 64);
  sum += __shfl_xor(sum, 2, 64);
  float inv = 1.0f / sum;
  __syncthreads();                         // done with Qs as scores input
#pragma unroll
  for (int jj = 0; jj < 16; ++jj) Qs[i][g * 16 + jj] = pv[jj] * inv;
  __syncthreads();
  float oacc[16];
#pragma unroll
  for (int dd = 0; dd < 16; ++dd) oacc[dd] = 0.f;
  for (int jv = 0; jv < 64; ++jv) {
    float p = Qs[i][jv];
    const float4* vp = (const float4*)&Vs[jv][g * 16];
    float4 v0 = vp[0], v1 = vp[1], v2 = vp[2], v3 = vp[3];
    oacc[0] += p * v0.x; oacc[1] += p * v0.y; oacc[2] += p * v0.z; oacc[3] += p * v0.w;
    oacc[4] += p * v1.x; oacc[5] += p * v1.y; oacc[6] += p * v1.z; oacc[7] += p * v1.w;
    oacc[8] += p * v2.x; oacc[9] += p * v2.y; oacc[10] += p * v2.z; oacc[11] += p * v2.w;
    oacc[12] += p * v3.x; oacc[13] += p * v3.y; oacc[14] += p * v3.z; oacc[15] += p * v3.w;
  }
#pragma unroll
  for (int dd = 0; dd < 16; ++dd)
    ao[(size_t)(be * 64 + i) * D + h * 64 + g * 16 + dd] = (h16)oacc[dd];
}

// ---------------- residual: expmap0(proj) -> mobius add -> LN2 chain; one WAVE per row -------
// proj arrives as TWO split-K partial buffers (piece stride NTOK*D), summed here.
__global__ void k_resid(const float* __restrict__ x, const float* __restrict__ proj,
                        const float* __restrict__ cg, const float* __restrict__ s2,
                        const float* __restrict__ b2, float* __restrict__ xa,
                        h16* __restrict__ t2) {
  const int wid = threadIdx.x >> 6, lane = threadIdx.x & 63;
  const int tok = blockIdx.x * 4 + wid;
  const float4* xr  = (const float4*)(x + (size_t)tok * D);
  const float4* p0r = (const float4*)(proj + (size_t)tok * D);
  const float4* p1r = (const float4*)(proj + (size_t)NTOK * D + (size_t)tok * D);
  float4 xv0 = xr[lane], xv1 = xr[lane + 64];
  float4 pa0 = p0r[lane], pa1 = p0r[lane + 64];
  float4 pb0 = p1r[lane], pb1 = p1r[lane + 64];
  float pe[8], xe[8];
  xe[0]=xv0.x; xe[1]=xv0.y; xe[2]=xv0.z; xe[3]=xv0.w; xe[4]=xv1.x; xe[5]=xv1.y; xe[6]=xv1.z; xe[7]=xv1.w;
  pe[0]=pa0.x+pb0.x; pe[1]=pa0.y+pb0.y; pe[2]=pa0.z+pb0.z; pe[3]=pa0.w+pb0.w;
  pe[4]=pa1.x+pb1.x; pe[5]=pa1.y+pb1.y; pe[6]=pa1.z+pb1.z; pe[7]=pa1.w+pb1.w;
  double sx = 0, sp = 0, xx = 0, pp = 0, xp = 0;
#pragma unroll
  for (int j = 0; j < 8; ++j) {
    double dx = xe[j], dp = pe[j];
    sx += dx; sp += dp; xx += dx * dx; pp += dp * dp; xp += dx * dp;
  }
  sx = wave_sum(sx); sp = wave_sum(sp); xx = wave_sum(xx);
  pp = wave_sum(pp); xp = wave_sum(xp);
  double c = (double)cg[0];
  double sc = sqrt(c); if (sc < EPSd) sc = EPSd;
  double pn = sqrt(pp);
  double me = tanh(sc * fmax(pn, EPSd)) / sc;
  double fs = (pn < EPSd) ? 0.0 : me / fmax(pn, EPSd);
  if (me >= 1.0) fs *= (1.0 - EPSd) / me;
  double y2 = fs * fs * pp, xy = fs * xp;
  double a = 1.0 + 2.0 * c * xy + c * y2;
  double b = 1.0 - c * xx;
  double den = 1.0 + 2.0 * c * xy + c * c * xx * y2;
  if (den < EPSd) den = EPSd;
  double zn = sqrt(fmax(a * a * xx + 2.0 * a * b * xy + b * b * y2, 0.0)) / den;
  double zs = 1.0 / den;
  if (zn >= 1.0) zs *= (1.0 - EPSd) / zn;
  double xan = (zn >= 1.0) ? (1.0 - EPSd) : zn;
  double A0 = zs * a, B0 = zs * b * fs;
  double xav[8];
#pragma unroll
  for (int j = 0; j < 8; ++j) xav[j] = A0 * (double)xe[j] + B0 * (double)pe[j];
  {
    float4 o0 = {(float)xav[0], (float)xav[1], (float)xav[2], (float)xav[3]};
    float4 o1 = {(float)xav[4], (float)xav[5], (float)xav[6], (float)xav[7]};
    float4* xw = (float4*)(xa + (size_t)tok * D);
    xw[lane] = o0; xw[lane + 64] = o1;
  }
  double sxa  = A0 * sx + B0 * sp;
  double sxa2 = A0 * A0 * xx + 2.0 * A0 * B0 * xp + B0 * B0 * pp;
  double fl = 0.0;
  if (xan >= EPSd) fl = atanh(fmin(xan, 1.0 - EPSd)) / (sc * fmax(xan, EPSd));
  double mu = fl * sxa / D;
  double var = fl * fl * sxa2 / D - mu * mu;
  double rs = 1.0 / sqrt(var + 1e-6);
  const float4* s2r = (const float4*)s2;
  const float4* b2r = (const float4*)b2;
  float4 sA = s2r[lane], sB = s2r[lane + 64];
  float4 bA = b2r[lane], bB = b2r[lane + 64];
  const float se[8] = {sA.x, sA.y, sA.z, sA.w, sB.x, sB.y, sB.z, sB.w};
  const float be[8] = {bA.x, bA.y, bA.z, bA.w, bB.x, bB.y, bB.z, bB.w};
  double w[8]; double sww = 0.0;
#pragma unroll
  for (int j = 0; j < 8; ++j) {
    w[j] = (fl * xav[j] - mu) * rs * (double)se[j] + (double)be[j];
    sww += w[j] * w[j];
  }
  sww = wave_sum(sww);
  double vn = sqrt(sww);
  double F = 0.0;
  if (vn >= EPSd) {
    double mag_e = tanh(sc * fmax(vn, EPSd)) / sc;
    F = atanh(fmin(mag_e, 1.0 - EPSd)) / (sc * vn);
  }
  h16* dst = t2 + (size_t)tok * D;
#pragma unroll
  for (int half = 0; half < 2; ++half) {
    h4v o;
#pragma unroll
    for (int e = 0; e < 4; ++e) o[e] = (h16)(float)(F * w[half * 4 + e]);
    *(h4v*)(dst + 4 * (lane + 64 * half)) = o;
  }
}

// ---------------- final: expmap0(ffn) -> mobius add -> out; one WAVE per row -------------
// f2 arrives as TWO split-K partial buffers, summed here.
__global__ void k_final(const float* __restrict__ xa, const float* __restrict__ f2,
                        const float* __restrict__ cg, float* __restrict__ out) {
  const int wid = threadIdx.x >> 6, lane = threadIdx.x & 63;
  const int tok = blockIdx.x * 4 + wid;
  const float4* ar  = (const float4*)(xa + (size_t)tok * D);
  const float4* f0r = (const float4*)(f2 + (size_t)tok * D);
  const float4* f1r = (const float4*)(f2 + (size_t)NTOK * D + (size_t)tok * D);
  float4 xv0 = ar[lane], xv1 = ar[lane + 64];
  float4 pa0 = f0r[lane], pa1 = f0r[lane + 64];
  float4 pb0 = f1r[lane], pb1 = f1r[lane + 64];
  float pe[8], xe[8];
  xe[0]=xv0.x; xe[1]=xv0.y; xe[2]=xv0.z; xe[3]=xv0.w; xe[4]=xv1.x; xe[5]=xv1.y; xe[6]=xv1.z; xe[7]=xv1.w;
  pe[0]=pa0.x+pb0.x; pe[1]=pa0.y+pb0.y; pe[2]=pa0.z+pb0.z; pe[3]=pa0.w+pb0.w;
  pe[4]=pa1.x+pb1.x; pe[5]=pa1.y+pb1.y; pe[6]=pa1.z+pb1.z; pe[7]=pa1.w+pb1.w;
  double xx = 0, pp = 0, xp = 0;
#pragma unroll
  for (int j = 0; j < 8; ++j) {
    double dx = xe[j], dp = pe[j];
    xx += dx * dx; pp += dp * dp; xp += dx * dp;
  }
  xx = wave_sum(xx); pp = wave_sum(pp); xp = wave_sum(xp);
  double c = (double)cg[0];
  double sc = sqrt(c); if (sc < EPSd) sc = EPSd;
  double pn = sqrt(pp);
  double me = tanh(sc * fmax(pn, EPSd)) / sc;
  double fs = (pn < EPSd) ? 0.0 : me / fmax(pn, EPSd);
  if (me >= 1.0) fs *= (1.0 - EPSd) / me;
  double y2 = fs * fs * pp, xy = fs * xp;
  double a = 1.0 + 2.0 * c * xy + c * y2;
  double b = 1.0 - c * xx;
  double den = 1.0 + 2.0 * c * xy + c * c * xx * y2;
  if (den < EPSd) den = EPSd;
  double zn = sqrt(fmax(a * a * xx + 2.0 * a * b * xy + b * b * y2, 0.0)) / den;
  double zs = 1.0 / den;
  if (zn >= 1.0) zs *= (1.0 - EPSd) / zn;
  double A0 = zs * a, B0 = zs * b * fs;
  float4 o0, o1;
  o0.x = (float)(A0 * xe[0] + B0 * pe[0]); o0.y = (float)(A0 * xe[1] + B0 * pe[1]);
  o0.z = (float)(A0 * xe[2] + B0 * pe[2]); o0.w = (float)(A0 * xe[3] + B0 * pe[3]);
  o1.x = (float)(A0 * xe[4] + B0 * pe[4]); o1.y = (float)(A0 * xe[5] + B0 * pe[5]);
  o1.z = (float)(A0 * xe[6] + B0 * pe[6]); o1.w = (float)(A0 * xe[7] + B0 * pe[7]);
  float4* ow = (float4*)(out + (size_t)tok * D);
  ow[lane] = o0; ow[lane + 64] = o1;
}

// ---------------- launch ----------------
extern "C" void kernel_launch(void* const* d_in, const int* in_sizes, int n_in,
                              void* d_out, int out_size, void* d_ws, size_t ws_size,
                              hipStream_t stream) {
  (void)in_sizes; (void)n_in; (void)out_size; (void)ws_size;
  const float* x    = (const float*)d_in[0];
  const float* cg   = (const float*)d_in[1];
  const float* Wqkv = (const float*)d_in[2];
  const float* bqkv = (const float*)d_in[3];
  const float* Wout = (const float*)d_in[4];
  const float* bout = (const float*)d_in[5];
  const float* s1   = (const float*)d_in[6];
  const float* b1   = (const float*)d_in[7];
  const float* s2   = (const float*)d_in[8];
  const float* b2   = (const float*)d_in[9];
  const float* Wff1 = (const float*)d_in[10];
  const float* bff1 = (const float*)d_in[11];
  const float* Wff2 = (const float*)d_in[12];
  const float* bff2 = (const float*)d_in[13];
  const float* chl  = (const float*)d_in[14];
  const float* geo  = (const float*)d_in[15];
  float* out = (float*)d_out;

  // ---- workspace layout (MB offsets), lifetime-overlaid; peak 15 MB ----
  char* base = (char*)d_ws;
  const size_t MB = 1024 * 1024;
  h16*   WqkvT = (h16*)(base + 0);            // 1.5 [prep .. qkv-mm]
  h16*   WoutT = (h16*)(base + (3*MB)/2);     // 0.5 [prep .. out-mm]
  h16*   Wff1T = (h16*)(base + 2*MB);         // 2   [prep .. ff1-mm]
  h16*   Wff2T = (h16*)(base + 4*MB);         // 2   [prep .. ff2-mm]
  h16*   xt    = (h16*)(base + 6*MB);         // 1   [prep .. qkv-mm]
  h16*   qkv   = (h16*)(base + 7*MB);         // 3   [qkv-mm .. attn]
  h16*   ao    = (h16*)(base + 10*MB);        // 1   [attn .. out-mm]
  float* proj  = (float*)(base + 11*MB);      // 4   [out-mm .. resid]   (2 split-K pieces)
  float* xa    = (float*)(base + 7*MB);       // 2   [resid .. final]    (qkv slot, dead)
  h16*   t2    = (h16*)(base + 6*MB);         // 1   [resid .. ff1-mm]   (xt slot)
  h16*   h1    = (h16*)(base + 11*MB);        // 4   [ff1-mm .. ff2-mm]  (proj slot, dead)
  float* f2    = (float*)(base + 0);          // 4   [ff2-mm .. final]   (W*T slots, dead)

  k_prep<<<3072 + NTOK / 4, 256, 0, stream>>>(Wqkv, Wout, Wff1, Wff2, x, cg, s1, b1,
                                              WqkvT, WoutT, Wff1T, Wff2T, xt);
  k_mm<0, 1, 0><<<dim3(1536 / 64, NTOK / 64), 256, 0, stream>>>(
      xt, WqkvT, bqkv, nullptr, qkv, NTOK, 1536, 512);
  k_attn<<<NB * H, 256, 0, stream>>>(qkv, chl, geo, ao);
  k_mm<0, 0, 1><<<dim3(512 / 64, NTOK / 64, 2), 256, 0, stream>>>(
      ao, WoutT, bout, proj, nullptr, NTOK, 512, 512);
  k_resid<<<NTOK / 4, 256, 0, stream>>>(x, proj, cg, s2, b2, xa, t2);
  k_mm<1, 1, 0><<<dim3(2048 / 64, NTOK / 64), 256, 0, stream>>>(
      t2, Wff1T, bff1, nullptr, h1, NTOK, 2048, 512);
  k_mm<0, 0, 1><<<dim3(512 / 64, NTOK / 64, 2), 256, 0, stream>>>(
      h1, Wff2T, bff2, f2, nullptr, NTOK, 512, 2048);
  k_final<<<NTOK / 4, 256, 0, stream>>>(xa, f2, cg, out);
}

// Round 7
// 74.890 us; speedup vs baseline: 2.2315x; 1.0417x over previous
//
#include <hip/hip_runtime.h>
#include <math.h>

#define DEV __device__ __forceinline__
typedef _Float16 h16;
typedef __attribute__((ext_vector_type(8))) _Float16 h8v;  // 8 fp16 = 4 VGPR
typedef __attribute__((ext_vector_type(4))) _Float16 h4v;  // 8-byte fp16 store
typedef __attribute__((ext_vector_type(4))) float f4v;

constexpr int NTOK = 1024;
constexpr int D    = 512;
constexpr int H    = 8;
constexpr int NB   = 16;
constexpr double EPSd = 1e-7;

// ---------------- wave reduction (row fully owned by one wave; no barriers) ----------------
DEV double wave_sum(double v) {
#pragma unroll
  for (int m = 32; m; m >>= 1) v += __shfl_xor(v, m, 64);
  return v;
}

// ---------------- merged: 4x weight transpose-cast (fp32[K][N] -> fp16[N][K]) + pre --------
__global__ void k_prep(const float* __restrict__ Wqkv, const float* __restrict__ Wout,
                       const float* __restrict__ Wff1, const float* __restrict__ Wff2,
                       const float* __restrict__ x, const float* __restrict__ cg,
                       const float* __restrict__ s1, const float* __restrict__ b1,
                       h16* __restrict__ qT, h16* __restrict__ oT,
                       h16* __restrict__ f1T, h16* __restrict__ f2T,
                       h16* __restrict__ xt) {
  __shared__ float t[32][33];
  const int bid = blockIdx.x;
  if (bid < 3072) {   // ---- transpose-cast ----
    const float* src; h16* dh; int K, N, bx, by;
    if (bid < 768)       { src = Wqkv; dh = qT;  K = 512;  N = 1536; bx = bid % 48;          by = bid / 48; }
    else if (bid < 1024) { src = Wout; dh = oT;  K = 512;  N = 512;  bx = (bid - 768) % 16;  by = (bid - 768) / 16; }
    else if (bid < 2048) { src = Wff1; dh = f1T; K = 512;  N = 2048; bx = (bid - 1024) % 64; by = (bid - 1024) / 64; }
    else                 { src = Wff2; dh = f2T; K = 2048; N = 512;  bx = (bid - 2048) % 16; by = (bid - 2048) / 16; }
    const int n0 = bx * 32, k0 = by * 32;
    const int tx = threadIdx.x & 31, ty = threadIdx.x >> 5;
    for (int i = ty; i < 32; i += 8) t[i][tx] = src[(size_t)(k0 + i) * N + n0 + tx];
    __syncthreads();
    for (int i = ty; i < 32; i += 8)
      dh[(size_t)(n0 + i) * K + k0 + tx] = (h16)t[tx][i];
    return;
  }
  // ---- pre: logmap0 -> LN -> expmap0 -> logmap0 (fused), one WAVE per token row ----
  const int wid = threadIdx.x >> 6, lane = threadIdx.x & 63;
  const int tok = (bid - 3072) * 4 + wid;
  const float4* xr = (const float4*)(x + (size_t)tok * D);
  float4 xv0 = xr[lane], xv1 = xr[lane + 64];
  double sv = 0.0, svv = 0.0;
  {
    const float e[8] = {xv0.x, xv0.y, xv0.z, xv0.w, xv1.x, xv1.y, xv1.z, xv1.w};
#pragma unroll
    for (int j = 0; j < 8; ++j) { double d = e[j]; sv += d; svv += d * d; }
  }
  sv = wave_sum(sv); svv = wave_sum(svv);
  double c = (double)cg[0];
  double sc = sqrt(c); if (sc < EPSd) sc = EPSd;
  double yn = sqrt(svv);
  double arg0 = yn; if (arg0 > 1.0 - EPSd) arg0 = 1.0 - EPSd;
  double f = (yn < EPSd) ? 0.0 : atanh(arg0) / sc / fmax(yn, EPSd);
  double mu = f * sv / D;
  double var = f * f * svv / D - mu * mu;
  double rs = 1.0 / sqrt(var + 1e-6);
  const float4* s1r = (const float4*)s1;
  const float4* b1r = (const float4*)b1;
  float4 sA = s1r[lane], sB = s1r[lane + 64];
  float4 bA = b1r[lane], bB = b1r[lane + 64];
  double w[8]; double sww = 0.0;
  {
    const float e[8]  = {xv0.x, xv0.y, xv0.z, xv0.w, xv1.x, xv1.y, xv1.z, xv1.w};
    const float se[8] = {sA.x, sA.y, sA.z, sA.w, sB.x, sB.y, sB.z, sB.w};
    const float be[8] = {bA.x, bA.y, bA.z, bA.w, bB.x, bB.y, bB.z, bB.w};
#pragma unroll
    for (int j = 0; j < 8; ++j) {
      w[j] = (f * (double)e[j] - mu) * rs * (double)se[j] + (double)be[j];
      sww += w[j] * w[j];
    }
  }
  sww = wave_sum(sww);
  double vn = sqrt(sww);
  double F = 0.0;
  if (vn >= EPSd) {
    double mag_e = tanh(sc * fmax(vn, EPSd)) / sc;
    F = atanh(fmin(mag_e, 1.0 - EPSd)) / (sc * vn);
  }
  h16* dst = xt + (size_t)tok * D;
#pragma unroll
  for (int half = 0; half < 2; ++half) {
    h4v o;
#pragma unroll
    for (int e = 0; e < 4; ++e) o[e] = (h16)(float)(F * w[half * 4 + e]);
    *(h4v*)(dst + 4 * (lane + 64 * half)) = o;
  }
}

// ---------------- fp16 MFMA GEMM, 64x64 tile, BK=64, counted-vmcnt double-buffer ------------
// LDS content chunk c of row r stored at chunk position c^(r&7) (pre-swizzled GLOBAL source;
// global_load_lds dest is linear base + lane*16). Reads apply the same XOR.
DEV void stage_tile(const h16* __restrict__ gbase, int rowstride, h16* lds,
                    int wid, int lane) {
#pragma unroll
  for (int j = 0; j < 2; ++j) {
    const int rbase = wid * 16 + j * 8;
    const int grow = rbase + (lane >> 3);
    const int gch = (lane & 7) ^ (lane >> 3);
    const h16* gp = gbase + (size_t)grow * rowstride + gch * 8;
    __builtin_amdgcn_global_load_lds(
        (const __attribute__((address_space(1))) void*)gp,
        (__attribute__((address_space(3))) void*)(lds + rbase * 64), 16, 0, 0);
  }
}
DEV h8v read_frag(const h16* lds, int row, int c) {
  const int p = c ^ (row & 7);
  return *(const h8v*)(lds + row * 64 + p * 8);
}

// SPLITK: grid.z pieces over K; piece z writes Cf + z*M*N (fp32), bias only in piece 0.
template <int GELU, int OHALF, int SPLITK>
__global__ __launch_bounds__(256) void k_mm(
    const h16* __restrict__ A, const h16* __restrict__ B,
    const float* __restrict__ bias, float* __restrict__ Cf, h16* __restrict__ Ch,
    int M, int N, int K) {
  __shared__ __align__(16) h16 As[2][64 * 64];
  __shared__ __align__(16) h16 Bs[2][64 * 64];
  const int tid = threadIdx.x;
  const int lane = tid & 63, wid = tid >> 6;
  const int wr = (wid >> 1) * 32, wc = (wid & 1) * 32;
  const int lr = lane & 15, lg = lane >> 4;
  const size_t r0 = (size_t)blockIdx.y * 64, c0 = (size_t)blockIdx.x * 64;
  const int kz = SPLITK ? blockIdx.z : 0;
  const int Keff = SPLITK ? (K >> 1) : K;
  const f4v z = {0.f, 0.f, 0.f, 0.f};
  f4v acc[2][2]; acc[0][0] = z; acc[0][1] = z; acc[1][0] = z; acc[1][1] = z;
  const h16* Abase = A + r0 * K + (size_t)kz * Keff;
  const h16* Bbase = B + c0 * K + (size_t)kz * Keff;
  const int NT = Keff >> 6;
  // prologue: tile 0 in flight (4 loads/wave)
  stage_tile(Abase, K, As[0], wid, lane);
  stage_tile(Bbase, K, Bs[0], wid, lane);
  int cur = 0;
  for (int t = 0; t < NT; ++t) {
    const int nxt = cur ^ 1;
    if (t + 1 < NT) {                      // issue next tile, keep it in flight
      stage_tile(Abase + (t + 1) * 64, K, As[nxt], wid, lane);
      stage_tile(Bbase + (t + 1) * 64, K, Bs[nxt], wid, lane);
      asm volatile("s_waitcnt vmcnt(4)" ::: "memory");  // only cur tile's 4 loads
    } else {
      asm volatile("s_waitcnt vmcnt(0)" ::: "memory");
    }
    asm volatile("s_barrier" ::: "memory");             // all waves' cur loads landed
    const h16* Ac = As[cur];
    const h16* Bc = Bs[cur];
#pragma unroll
    for (int ks = 0; ks < 2; ++ks) {
      const int c = ks * 4 + lg;
      h8v a0 = read_frag(Ac, wr + lr, c);
      h8v a1 = read_frag(Ac, wr + 16 + lr, c);
      h8v b0 = read_frag(Bc, wc + lr, c);
      h8v b1 = read_frag(Bc, wc + 16 + lr, c);
      acc[0][0] = __builtin_amdgcn_mfma_f32_16x16x32_f16(a0, b0, acc[0][0], 0, 0, 0);
      acc[0][1] = __builtin_amdgcn_mfma_f32_16x16x32_f16(a0, b1, acc[0][1], 0, 0, 0);
      acc[1][0] = __builtin_amdgcn_mfma_f32_16x16x32_f16(a1, b0, acc[1][0], 0, 0, 0);
      acc[1][1] = __builtin_amdgcn_mfma_f32_16x16x32_f16(a1, b1, acc[1][1], 0, 0, 0);
    }
    // reads are in registers before MFMA issues (compiler lgkmcnt); safe to let
    // next iteration overwrite buf[cur] after this barrier. NO vmcnt drain here.
    asm volatile("s_barrier" ::: "memory");
    cur = nxt;
  }
  float* Cfo = Cf + (size_t)kz * M * N;
#pragma unroll
  for (int m = 0; m < 2; ++m)
#pragma unroll
    for (int n = 0; n < 2; ++n) {
      const size_t row = r0 + wr + m * 16 + lg * 4;
      const size_t col = c0 + wc + n * 16 + lr;
      const float bv = (SPLITK && kz) ? 0.f : bias[col];
#pragma unroll
      for (int e = 0; e < 4; ++e) {
        float v = acc[m][n][e] + bv;
        if (GELU) {
          float x3 = v * v * v;
          v = 0.5f * v * (1.0f + tanhf(0.7978845608028654f * (v + 0.044715f * x3)));
        }
        if (OHALF) Ch[(row + e) * N + col] = (h16)v;
        else       Cfo[(row + e) * N + col] = v;
      }
    }
}

// ---------------- attention: RoPE + per-head expmap0 + hyperbolic dist + softmax + PV -------
// 2 blocks per (be,h): each owns 32 q-rows (8 lanes/row, 8 cols each). K/V staged fully.
__global__ __launch_bounds__(256) void k_attn(
    const h16* __restrict__ qkv, const float* __restrict__ chl,
    const float* __restrict__ geo, h16* __restrict__ ao) {
  __shared__ __align__(16) float Qs[32][68];
  __shared__ __align__(16) float Kt[64][68];   // K transposed: Kt[d][s]
  __shared__ __align__(16) float Vs[64][68];
  __shared__ float q2s[32], k2s[64], fqv[32], fkv[64];
  const int bid = blockIdx.x;
  const int be = bid >> 4, h = (bid >> 1) & 7, q0 = (bid & 1) * 32;
  const int tid = threadIdx.x;
  const double chd = log1p(exp((double)chl[h]));   // softplus (once)
  const float ch = (float)chd;
  float sc = (float)sqrt(chd); if (sc < 1e-7f) sc = 1e-7f;
  // stage K^T (RoPE) + V (64 rows)
  for (int l = tid; l < 64 * 32; l += 256) {
    int s = l >> 5, j = l & 31;
    const h16* base = qkv + (size_t)(be * 64 + s) * 1536 + h * 64;
    float ka = (float)base[512 + j], kb = (float)base[512 + j + 32];
    float fj = expf((float)j * -0.2878231366242557f);   // ln(10000)/32
    float st, ct; sincosf((float)s * fj, &st, &ct);
    Kt[j][s]      = ka * ct - kb * st;
    Kt[j + 32][s] = ka * st + kb * ct;
    Vs[s][j]      = (float)base[1024 + j];
    Vs[s][j + 32] = (float)base[1024 + j + 32];
  }
  // stage Q (RoPE), 32 rows
  for (int l = tid; l < 32 * 32; l += 256) {
    int s = l >> 5, j = l & 31;
    const h16* base = qkv + (size_t)(be * 64 + q0 + s) * 1536 + h * 64;
    float qa = (float)base[j], qb = (float)base[j + 32];
    float fj = expf((float)j * -0.2878231366242557f);
    float st, ct; sincosf((float)(q0 + s) * fj, &st, &ct);
    Qs[s][j]      = qa * ct - qb * st;
    Qs[s][j + 32] = qa * st + qb * ct;
  }
  __syncthreads();
  // per-row expmap0 factors (rows kept unscaled; factors folded into Gram)
  if (tid < 64) {
    float a = 0.f;
    for (int d2 = 0; d2 < 64; ++d2) { float v = Kt[d2][tid]; a += v * v; }
    float n = sqrtf(a);
    float m = tanhf(sc * fmaxf(n, 1e-7f)) / sc;
    float f = (n < 1e-7f) ? 0.f : m / fmaxf(n, 1e-7f);
    if (m >= 1.f) f *= (1.f - 1e-7f) / m;
    float fn = f * n;
    fkv[tid] = f; k2s[tid] = fn * fn;
  } else if (tid < 96) {
    int i = tid - 64;
    float a = 0.f;
    for (int d2 = 0; d2 < 64; ++d2) { float v = Qs[i][d2]; a += v * v; }
    float n = sqrtf(a);
    float m = tanhf(sc * fmaxf(n, 1e-7f)) / sc;
    float f = (n < 1e-7f) ? 0.f : m / fmaxf(n, 1e-7f);
    if (m >= 1.f) f *= (1.f - 1e-7f) / m;
    float fn = f * n;
    fqv[i] = f; q2s[i] = fn * fn;
  }
  __syncthreads();
  const int i = tid >> 3, g = tid & 7;   // local q-row, 8-col group
  float gacc[8];
#pragma unroll
  for (int jj = 0; jj < 8; ++jj) gacc[jj] = 0.f;
  for (int d2 = 0; d2 < 64; ++d2) {
    float qv = Qs[i][d2];
    const float4* kp = (const float4*)&Kt[d2][g * 8];
    float4 k0 = kp[0], k1 = kp[1];
    gacc[0] += qv * k0.x; gacc[1] += qv * k0.y; gacc[2] += qv * k0.z; gacc[3] += qv * k0.w;
    gacc[4] += qv * k1.x; gacc[5] += qv * k1.y; gacc[6] += qv * k1.z; gacc[7] += qv * k1.w;
  }
  const float gs = geo[h];
  const float q2 = q2s[i], fqi = fqv[i];
  float lg[8];
  float mx = -1e30f;
#pragma unroll
  for (int jj = 0; jj < 8; ++jj) {
    float gq = fqi * fkv[g * 8 + jj] * gacc[jj];
    float k2 = k2s[g * 8 + jj];
    float A  = 1.f - 2.f * ch * gq + ch * k2;
    float Bv = 1.f - ch * q2;
    float n2 = fmaxf(A * A * q2 - 2.f * A * Bv * gq + Bv * Bv * k2, 0.f);
    float den = fmaxf(1.f - 2.f * ch * gq + ch * ch * q2 * k2, 1e-7f);
    float r = fminf(sqrtf(n2) / den, 1.f - 1e-7f);
    float arg = fminf(sc * r, 1.f - 1e-7f);
    float l = -gs * (2.f * atanhf(arg) / sc);
    lg[jj] = l; mx = fmaxf(mx, l);
  }
  mx = fmaxf(mx, __shfl_xor(mx, 1, 64));
  mx = fmaxf(mx, __shfl_xor(mx, 2, 64));
  mx = fmaxf(mx, __shfl_xor(mx, 4, 64));
  float pv[8]; float sum = 0.f;
#pragma unroll
  for (int jj = 0; jj < 8; ++jj) { pv[jj] = expf(lg[jj] - mx); sum += pv[jj]; }
  sum += __shfl_xor(sum, 1, 64);
  sum += __shfl_xor(sum, 2, 64);
  sum += __shfl_xor(sum, 4, 64);
  float inv = 1.0f / sum;
  // P overwrite of Qs: wave w owns rows 8w..8w+7 exclusively; in-wave lockstep
  // guarantees all lanes finished reading row i before any lane stores.
#pragma unroll
  for (int jj = 0; jj < 8; ++jj) Qs[i][g * 8 + jj] = pv[jj] * inv;
  float oacc[8];
#pragma unroll
  for (int dd = 0; dd < 8; ++dd) oacc[dd] = 0.f;
  for (int jv = 0; jv < 64; ++jv) {
    float p = Qs[i][jv];
    const float4* vp = (const float4*)&Vs[jv][g * 8];
    float4 v0 = vp[0], v1 = vp[1];
    oacc[0] += p * v0.x; oacc[1] += p * v0.y; oacc[2] += p * v0.z; oacc[3] += p * v0.w;
    oacc[4] += p * v1.x; oacc[5] += p * v1.y; oacc[6] += p * v1.z; oacc[7] += p * v1.w;
  }
#pragma unroll
  for (int dd = 0; dd < 8; ++dd)
    ao[(size_t)(be * 64 + q0 + i) * D + h * 64 + g * 8 + dd] = (h16)oacc[dd];
}

// ---------------- residual: expmap0(proj) -> mobius add -> LN2 chain; one WAVE per row -------
// proj arrives as TWO split-K partial buffers (piece stride NTOK*D), summed here.
__global__ void k_resid(const float* __restrict__ x, const float* __restrict__ proj,
                        const float* __restrict__ cg, const float* __restrict__ s2,
                        const float* __restrict__ b2, float* __restrict__ xa,
                        h16* __restrict__ t2) {
  const int wid = threadIdx.x >> 6, lane = threadIdx.x & 63;
  const int tok = blockIdx.x * 4 + wid;
  const float4* xr  = (const float4*)(x + (size_t)tok * D);
  const float4* p0r = (const float4*)(proj + (size_t)tok * D);
  const float4* p1r = (const float4*)(proj + (size_t)NTOK * D + (size_t)tok * D);
  float4 xv0 = xr[lane], xv1 = xr[lane + 64];
  float4 pa0 = p0r[lane], pa1 = p0r[lane + 64];
  float4 pb0 = p1r[lane], pb1 = p1r[lane + 64];
  float pe[8], xe[8];
  xe[0]=xv0.x; xe[1]=xv0.y; xe[2]=xv0.z; xe[3]=xv0.w; xe[4]=xv1.x; xe[5]=xv1.y; xe[6]=xv1.z; xe[7]=xv1.w;
  pe[0]=pa0.x+pb0.x; pe[1]=pa0.y+pb0.y; pe[2]=pa0.z+pb0.z; pe[3]=pa0.w+pb0.w;
  pe[4]=pa1.x+pb1.x; pe[5]=pa1.y+pb1.y; pe[6]=pa1.z+pb1.z; pe[7]=pa1.w+pb1.w;
  double sx = 0, sp = 0, xx = 0, pp = 0, xp = 0;
#pragma unroll
  for (int j = 0; j < 8; ++j) {
    double dx = xe[j], dp = pe[j];
    sx += dx; sp += dp; xx += dx * dx; pp += dp * dp; xp += dx * dp;
  }
  sx = wave_sum(sx); sp = wave_sum(sp); xx = wave_sum(xx);
  pp = wave_sum(pp); xp = wave_sum(xp);
  double c = (double)cg[0];
  double sc = sqrt(c); if (sc < EPSd) sc = EPSd;
  double pn = sqrt(pp);
  double me = tanh(sc * fmax(pn, EPSd)) / sc;
  double fs = (pn < EPSd) ? 0.0 : me / fmax(pn, EPSd);
  if (me >= 1.0) fs *= (1.0 - EPSd) / me;
  double y2 = fs * fs * pp, xy = fs * xp;
  double a = 1.0 + 2.0 * c * xy + c * y2;
  double b = 1.0 - c * xx;
  double den = 1.0 + 2.0 * c * xy + c * c * xx * y2;
  if (den < EPSd) den = EPSd;
  double zn = sqrt(fmax(a * a * xx + 2.0 * a * b * xy + b * b * y2, 0.0)) / den;
  double zs = 1.0 / den;
  if (zn >= 1.0) zs *= (1.0 - EPSd) / zn;
  double xan = (zn >= 1.0) ? (1.0 - EPSd) : zn;
  double A0 = zs * a, B0 = zs * b * fs;
  double xav[8];
#pragma unroll
  for (int j = 0; j < 8; ++j) xav[j] = A0 * (double)xe[j] + B0 * (double)pe[j];
  {
    float4 o0 = {(float)xav[0], (float)xav[1], (float)xav[2], (float)xav[3]};
    float4 o1 = {(float)xav[4], (float)xav[5], (float)xav[6], (float)xav[7]};
    float4* xw = (float4*)(xa + (size_t)tok * D);
    xw[lane] = o0; xw[lane + 64] = o1;
  }
  double sxa  = A0 * sx + B0 * sp;
  double sxa2 = A0 * A0 * xx + 2.0 * A0 * B0 * xp + B0 * B0 * pp;
  double fl = 0.0;
  if (xan >= EPSd) fl = atanh(fmin(xan, 1.0 - EPSd)) / (sc * fmax(xan, EPSd));
  double mu = fl * sxa / D;
  double var = fl * fl * sxa2 / D - mu * mu;
  double rs = 1.0 / sqrt(var + 1e-6);
  const float4* s2r = (const float4*)s2;
  const float4* b2r = (const float4*)b2;
  float4 sA = s2r[lane], sB = s2r[lane + 64];
  float4 bA = b2r[lane], bB = b2r[lane + 64];
  const float se[8] = {sA.x, sA.y, sA.z, sA.w, sB.x, sB.y, sB.z, sB.w};
  const float be[8] = {bA.x, bA.y, bA.z, bA.w, bB.x, bB.y, bB.z, bB.w};
  double w[8]; double sww = 0.0;
#pragma unroll
  for (int j = 0; j < 8; ++j) {
    w[j] = (fl * xav[j] - mu) * rs * (double)se[j] + (double)be[j];
    sww += w[j] * w[j];
  }
  sww = wave_sum(sww);
  double vn = sqrt(sww);
  double F = 0.0;
  if (vn >= EPSd) {
    double mag_e = tanh(sc * fmax(vn, EPSd)) / sc;
    F = atanh(fmin(mag_e, 1.0 - EPSd)) / (sc * vn);
  }
  h16* dst = t2 + (size_t)tok * D;
#pragma unroll
  for (int half = 0; half < 2; ++half) {
    h4v o;
#pragma unroll
    for (int e = 0; e < 4; ++e) o[e] = (h16)(float)(F * w[half * 4 + e]);
    *(h4v*)(dst + 4 * (lane + 64 * half)) = o;
  }
}

// ---------------- final: expmap0(ffn) -> mobius add -> out; one WAVE per row -------------
// f2 arrives as TWO split-K partial buffers, summed here.
__global__ void k_final(const float* __restrict__ xa, const float* __restrict__ f2,
                        const float* __restrict__ cg, float* __restrict__ out) {
  const int wid = threadIdx.x >> 6, lane = threadIdx.x & 63;
  const int tok = blockIdx.x * 4 + wid;
  const float4* ar  = (const float4*)(xa + (size_t)tok * D);
  const float4* f0r = (const float4*)(f2 + (size_t)tok * D);
  const float4* f1r = (const float4*)(f2 + (size_t)NTOK * D + (size_t)tok * D);
  float4 xv0 = ar[lane], xv1 = ar[lane + 64];
  float4 pa0 = f0r[lane], pa1 = f0r[lane + 64];
  float4 pb0 = f1r[lane], pb1 = f1r[lane + 64];
  float pe[8], xe[8];
  xe[0]=xv0.x; xe[1]=xv0.y; xe[2]=xv0.z; xe[3]=xv0.w; xe[4]=xv1.x; xe[5]=xv1.y; xe[6]=xv1.z; xe[7]=xv1.w;
  pe[0]=pa0.x+pb0.x; pe[1]=pa0.y+pb0.y; pe[2]=pa0.z+pb0.z; pe[3]=pa0.w+pb0.w;
  pe[4]=pa1.x+pb1.x; pe[5]=pa1.y+pb1.y; pe[6]=pa1.z+pb1.z; pe[7]=pa1.w+pb1.w;
  double xx = 0, pp = 0, xp = 0;
#pragma unroll
  for (int j = 0; j < 8; ++j) {
    double dx = xe[j], dp = pe[j];
    xx += dx * dx; pp += dp * dp; xp += dx * dp;
  }
  xx = wave_sum(xx); pp = wave_sum(pp); xp = wave_sum(xp);
  double c = (double)cg[0];
  double sc = sqrt(c); if (sc < EPSd) sc = EPSd;
  double pn = sqrt(pp);
  double me = tanh(sc * fmax(pn, EPSd)) / sc;
  double fs = (pn < EPSd) ? 0.0 : me / fmax(pn, EPSd);
  if (me >= 1.0) fs *= (1.0 - EPSd) / me;
  double y2 = fs * fs * pp, xy = fs * xp;
  double a = 1.0 + 2.0 * c * xy + c * y2;
  double b = 1.0 - c * xx;
  double den = 1.0 + 2.0 * c * xy + c * c * xx * y2;
  if (den < EPSd) den = EPSd;
  double zn = sqrt(fmax(a * a * xx + 2.0 * a * b * xy + b * b * y2, 0.0)) / den;
  double zs = 1.0 / den;
  if (zn >= 1.0) zs *= (1.0 - EPSd) / zn;
  double A0 = zs * a, B0 = zs * b * fs;
  float4 o0, o1;
  o0.x = (float)(A0 * xe[0] + B0 * pe[0]); o0.y = (float)(A0 * xe[1] + B0 * pe[1]);
  o0.z = (float)(A0 * xe[2] + B0 * pe[2]); o0.w = (float)(A0 * xe[3] + B0 * pe[3]);
  o1.x = (float)(A0 * xe[4] + B0 * pe[4]); o1.y = (float)(A0 * xe[5] + B0 * pe[5]);
  o1.z = (float)(A0 * xe[6] + B0 * pe[6]); o1.w = (float)(A0 * xe[7] + B0 * pe[7]);
  float4* ow = (float4*)(out + (size_t)tok * D);
  ow[lane] = o0; ow[lane + 64] = o1;
}

// ---------------- launch ----------------
extern "C" void kernel_launch(void* const* d_in, const int* in_sizes, int n_in,
                              void* d_out, int out_size, void* d_ws, size_t ws_size,
                              hipStream_t stream) {
  (void)in_sizes; (void)n_in; (void)out_size; (void)ws_size;
  const float* x    = (const float*)d_in[0];
  const float* cg   = (const float*)d_in[1];
  const float* Wqkv = (const float*)d_in[2];
  const float* bqkv = (const float*)d_in[3];
  const float* Wout = (const float*)d_in[4];
  const float* bout = (const float*)d_in[5];
  const float* s1   = (const float*)d_in[6];
  const float* b1   = (const float*)d_in[7];
  const float* s2   = (const float*)d_in[8];
  const float* b2   = (const float*)d_in[9];
  const float* Wff1 = (const float*)d_in[10];
  const float* bff1 = (const float*)d_in[11];
  const float* Wff2 = (const float*)d_in[12];
  const float* bff2 = (const float*)d_in[13];
  const float* chl  = (const float*)d_in[14];
  const float* geo  = (const float*)d_in[15];
  float* out = (float*)d_out;

  // ---- workspace layout (MB offsets), lifetime-overlaid; peak 15 MB ----
  char* base = (char*)d_ws;
  const size_t MB = 1024 * 1024;
  h16*   WqkvT = (h16*)(base + 0);            // 1.5 [prep .. qkv-mm]
  h16*   WoutT = (h16*)(base + (3*MB)/2);     // 0.5 [prep .. out-mm]
  h16*   Wff1T = (h16*)(base + 2*MB);         // 2   [prep .. ff1-mm]
  h16*   Wff2T = (h16*)(base + 4*MB);         // 2   [prep .. ff2-mm]
  h16*   xt    = (h16*)(base + 6*MB);         // 1   [prep .. qkv-mm]
  h16*   qkv   = (h16*)(base + 7*MB);         // 3   [qkv-mm .. attn]
  h16*   ao    = (h16*)(base + 10*MB);        // 1   [attn .. out-mm]
  float* proj  = (float*)(base + 11*MB);      // 4   [out-mm .. resid]   (2 split-K pieces)
  float* xa    = (float*)(base + 7*MB);       // 2   [resid .. final]    (qkv slot, dead)
  h16*   t2    = (h16*)(base + 6*MB);         // 1   [resid .. ff1-mm]   (xt slot)
  h16*   h1    = (h16*)(base + 11*MB);        // 4   [ff1-mm .. ff2-mm]  (proj slot, dead)
  float* f2    = (float*)(base + 0);          // 4   [ff2-mm .. final]   (W*T slots, dead)

  k_prep<<<3072 + NTOK / 4, 256, 0, stream>>>(Wqkv, Wout, Wff1, Wff2, x, cg, s1, b1,
                                              WqkvT, WoutT, Wff1T, Wff2T, xt);
  k_mm<0, 1, 0><<<dim3(1536 / 64, NTOK / 64), 256, 0, stream>>>(
      xt, WqkvT, bqkv, nullptr, qkv, NTOK, 1536, 512);
  k_attn<<<NB * H * 2, 256, 0, stream>>>(qkv, chl, geo, ao);
  k_mm<0, 0, 1><<<dim3(512 / 64, NTOK / 64, 2), 256, 0, stream>>>(
      ao, WoutT, bout, proj, nullptr, NTOK, 512, 512);
  k_resid<<<NTOK / 4, 256, 0, stream>>>(x, proj, cg, s2, b2, xa, t2);
  k_mm<1, 1, 0><<<dim3(2048 / 64, NTOK / 64), 256, 0, stream>>>(
      t2, Wff1T, bff1, nullptr, h1, NTOK, 2048, 512);
  k_mm<0, 0, 1><<<dim3(512 / 64, NTOK / 64, 2), 256, 0, stream>>>(
      h1, Wff2T, bff2, f2, nullptr, NTOK, 512, 2048);
  k_final<<<NTOK / 4, 256, 0, stream>>>(xa, f2, cg, out);
}

// Round 8
// 73.411 us; speedup vs baseline: 2.2764x; 1.0201x over previous
//
#include <hip/hip_runtime.h>
#include <math.h>

#define DEV __device__ __forceinline__
typedef _Float16 h16;
typedef __attribute__((ext_vector_type(8))) _Float16 h8v;  // 8 fp16 = 4 VGPR
typedef __attribute__((ext_vector_type(4))) _Float16 h4v;  // 8-byte fp16 store
typedef __attribute__((ext_vector_type(4))) float f4v;

constexpr int NTOK = 1024;
constexpr int D    = 512;
constexpr int H    = 8;
constexpr int NB   = 16;
constexpr double EPSd = 1e-7;

// ---------------- wave reduction (row fully owned by one wave; no barriers) ----------------
DEV double wave_sum(double v) {
#pragma unroll
  for (int m = 32; m; m >>= 1) v += __shfl_xor(v, m, 64);
  return v;
}

// ---------------- merged: 4x weight transpose-cast (fp32[K][N] -> fp16[N][K]) + pre --------
__global__ void k_prep(const float* __restrict__ Wqkv, const float* __restrict__ Wout,
                       const float* __restrict__ Wff1, const float* __restrict__ Wff2,
                       const float* __restrict__ x, const float* __restrict__ cg,
                       const float* __restrict__ s1, const float* __restrict__ b1,
                       h16* __restrict__ qT, h16* __restrict__ oT,
                       h16* __restrict__ f1T, h16* __restrict__ f2T,
                       h16* __restrict__ xt) {
  __shared__ float t[32][33];
  const int bid = blockIdx.x;
  if (bid < 3072) {   // ---- transpose-cast ----
    const float* src; h16* dh; int K, N, bx, by;
    if (bid < 768)       { src = Wqkv; dh = qT;  K = 512;  N = 1536; bx = bid % 48;          by = bid / 48; }
    else if (bid < 1024) { src = Wout; dh = oT;  K = 512;  N = 512;  bx = (bid - 768) % 16;  by = (bid - 768) / 16; }
    else if (bid < 2048) { src = Wff1; dh = f1T; K = 512;  N = 2048; bx = (bid - 1024) % 64; by = (bid - 1024) / 64; }
    else                 { src = Wff2; dh = f2T; K = 2048; N = 512;  bx = (bid - 2048) % 16; by = (bid - 2048) / 16; }
    const int n0 = bx * 32, k0 = by * 32;
    const int tx = threadIdx.x & 31, ty = threadIdx.x >> 5;
    for (int i = ty; i < 32; i += 8) t[i][tx] = src[(size_t)(k0 + i) * N + n0 + tx];
    __syncthreads();
    for (int i = ty; i < 32; i += 8)
      dh[(size_t)(n0 + i) * K + k0 + tx] = (h16)t[tx][i];
    return;
  }
  // ---- pre: logmap0 -> LN -> expmap0 -> logmap0 (fused), one WAVE per token row ----
  const int wid = threadIdx.x >> 6, lane = threadIdx.x & 63;
  const int tok = (bid - 3072) * 4 + wid;
  const float4* xr = (const float4*)(x + (size_t)tok * D);
  float4 xv0 = xr[lane], xv1 = xr[lane + 64];
  double sv = 0.0, svv = 0.0;
  {
    const float e[8] = {xv0.x, xv0.y, xv0.z, xv0.w, xv1.x, xv1.y, xv1.z, xv1.w};
#pragma unroll
    for (int j = 0; j < 8; ++j) { double d = e[j]; sv += d; svv += d * d; }
  }
  sv = wave_sum(sv); svv = wave_sum(svv);
  double c = (double)cg[0];
  double sc = sqrt(c); if (sc < EPSd) sc = EPSd;
  double yn = sqrt(svv);
  double arg0 = yn; if (arg0 > 1.0 - EPSd) arg0 = 1.0 - EPSd;
  double f = (yn < EPSd) ? 0.0 : atanh(arg0) / sc / fmax(yn, EPSd);
  double mu = f * sv / D;
  double var = f * f * svv / D - mu * mu;
  double rs = 1.0 / sqrt(var + 1e-6);
  const float4* s1r = (const float4*)s1;
  const float4* b1r = (const float4*)b1;
  float4 sA = s1r[lane], sB = s1r[lane + 64];
  float4 bA = b1r[lane], bB = b1r[lane + 64];
  double w[8]; double sww = 0.0;
  {
    const float e[8]  = {xv0.x, xv0.y, xv0.z, xv0.w, xv1.x, xv1.y, xv1.z, xv1.w};
    const float se[8] = {sA.x, sA.y, sA.z, sA.w, sB.x, sB.y, sB.z, sB.w};
    const float be[8] = {bA.x, bA.y, bA.z, bA.w, bB.x, bB.y, bB.z, bB.w};
#pragma unroll
    for (int j = 0; j < 8; ++j) {
      w[j] = (f * (double)e[j] - mu) * rs * (double)se[j] + (double)be[j];
      sww += w[j] * w[j];
    }
  }
  sww = wave_sum(sww);
  double vn = sqrt(sww);
  double F = 0.0;
  if (vn >= EPSd) {
    double mag_e = tanh(sc * fmax(vn, EPSd)) / sc;
    F = atanh(fmin(mag_e, 1.0 - EPSd)) / (sc * vn);
  }
  h16* dst = xt + (size_t)tok * D;
#pragma unroll
  for (int half = 0; half < 2; ++half) {
    h4v o;
#pragma unroll
    for (int e = 0; e < 4; ++e) o[e] = (h16)(float)(F * w[half * 4 + e]);
    *(h4v*)(dst + 4 * (lane + 64 * half)) = o;
  }
}

// ---------------- fp16 MFMA GEMM, 64x64 tile, BK=64, 3-deep counted-vmcnt pipeline ----------
// LDS content chunk c of row r stored at chunk position c^(r&7) (pre-swizzled GLOBAL source;
// global_load_lds dest is linear base + lane*16). Reads apply the same XOR.
DEV void stage_tile(const h16* __restrict__ gbase, int rowstride, h16* lds,
                    int wid, int lane) {
#pragma unroll
  for (int j = 0; j < 2; ++j) {
    const int rbase = wid * 16 + j * 8;
    const int grow = rbase + (lane >> 3);
    const int gch = (lane & 7) ^ (lane >> 3);
    const h16* gp = gbase + (size_t)grow * rowstride + gch * 8;
    __builtin_amdgcn_global_load_lds(
        (const __attribute__((address_space(1))) void*)gp,
        (__attribute__((address_space(3))) void*)(lds + rbase * 64), 16, 0, 0);
  }
}
DEV h8v read_frag(const h16* lds, int row, int c) {
  const int p = c ^ (row & 7);
  return *(const h8v*)(lds + row * 64 + p * 8);
}

// SPLITK: grid.z pieces over K; piece z writes Cf + z*M*N (fp32), bias only in piece 0.
template <int GELU, int OHALF, int SPLITK>
__global__ __launch_bounds__(256) void k_mm(
    const h16* __restrict__ A, const h16* __restrict__ B,
    const float* __restrict__ bias, float* __restrict__ Cf, h16* __restrict__ Ch,
    int M, int N, int K) {
  __shared__ __align__(16) h16 As[3][64 * 64];
  __shared__ __align__(16) h16 Bs[3][64 * 64];
  const int tid = threadIdx.x;
  const int lane = tid & 63, wid = tid >> 6;
  const int wr = (wid >> 1) * 32, wc = (wid & 1) * 32;
  const int lr = lane & 15, lg = lane >> 4;
  const size_t r0 = (size_t)blockIdx.y * 64, c0 = (size_t)blockIdx.x * 64;
  const int kz = SPLITK ? blockIdx.z : 0;
  const int Keff = SPLITK ? (K >> 1) : K;
  const f4v z = {0.f, 0.f, 0.f, 0.f};
  f4v acc[2][2]; acc[0][0] = z; acc[0][1] = z; acc[1][0] = z; acc[1][1] = z;
  const h16* Abase = A + r0 * K + (size_t)kz * Keff;
  const h16* Bbase = B + c0 * K + (size_t)kz * Keff;
  const int NT = Keff >> 6;
  // prologue: tiles 0,1 in flight (8 loads/wave)
  stage_tile(Abase, K, As[0], wid, lane);
  stage_tile(Bbase, K, Bs[0], wid, lane);
  stage_tile(Abase + 64, K, As[1], wid, lane);
  stage_tile(Bbase + 64, K, Bs[1], wid, lane);
  int cur = 0;
  for (int t = 0; t < NT; ++t) {
    const int pre = (cur == 2) ? 0 : cur + 1;      // buf for t+2 = (cur+2)%3
    const int pre2 = (pre == 2) ? 0 : pre + 1;
    if (t + 2 < NT) {                      // keep 2 tiles in flight
      stage_tile(Abase + (t + 2) * 64, K, As[pre2], wid, lane);
      stage_tile(Bbase + (t + 2) * 64, K, Bs[pre2], wid, lane);
    }
    const int rem = NT - 1 - t;
    if (rem >= 2)      asm volatile("s_waitcnt vmcnt(8)" ::: "memory");
    else if (rem == 1) asm volatile("s_waitcnt vmcnt(4)" ::: "memory");
    else               asm volatile("s_waitcnt vmcnt(0)" ::: "memory");
    asm volatile("s_barrier" ::: "memory");             // all waves' cur loads landed
    const h16* Ac = As[cur];
    const h16* Bc = Bs[cur];
#pragma unroll
    for (int ks = 0; ks < 2; ++ks) {
      const int c = ks * 4 + lg;
      h8v a0 = read_frag(Ac, wr + lr, c);
      h8v a1 = read_frag(Ac, wr + 16 + lr, c);
      h8v b0 = read_frag(Bc, wc + lr, c);
      h8v b1 = read_frag(Bc, wc + 16 + lr, c);
      acc[0][0] = __builtin_amdgcn_mfma_f32_16x16x32_f16(a0, b0, acc[0][0], 0, 0, 0);
      acc[0][1] = __builtin_amdgcn_mfma_f32_16x16x32_f16(a0, b1, acc[0][1], 0, 0, 0);
      acc[1][0] = __builtin_amdgcn_mfma_f32_16x16x32_f16(a1, b0, acc[1][0], 0, 0, 0);
      acc[1][1] = __builtin_amdgcn_mfma_f32_16x16x32_f16(a1, b1, acc[1][1], 0, 0, 0);
    }
    // LDS reads retire into regs before MFMA (compiler lgkmcnt); barrier ends the iter.
    asm volatile("s_barrier" ::: "memory");
    cur = pre;
  }
  float* Cfo = Cf + (size_t)kz * M * N;
#pragma unroll
  for (int m = 0; m < 2; ++m)
#pragma unroll
    for (int n = 0; n < 2; ++n) {
      const size_t row = r0 + wr + m * 16 + lg * 4;
      const size_t col = c0 + wc + n * 16 + lr;
      const float bv = (SPLITK && kz) ? 0.f : bias[col];
#pragma unroll
      for (int e = 0; e < 4; ++e) {
        float v = acc[m][n][e] + bv;
        if (GELU) {
          float x3 = v * v * v;
          v = 0.5f * v * (1.0f + tanhf(0.7978845608028654f * (v + 0.044715f * x3)));
        }
        if (OHALF) Ch[(row + e) * N + col] = (h16)v;
        else       Cfo[(row + e) * N + col] = v;
      }
    }
}

// ---------------- attention: RoPE + per-head expmap0 + hyperbolic dist + softmax + PV -------
// 2 blocks per (be,h): each owns 32 q-rows (8 lanes/row, 8 cols each). K/V staged fully.
// Vectorized h8v staging; row norms computed from RAW q/k (RoPE rotation is orthogonal).
__global__ __launch_bounds__(256) void k_attn(
    const h16* __restrict__ qkv, const float* __restrict__ chl,
    const float* __restrict__ geo, h16* __restrict__ ao) {
  __shared__ __align__(16) float Qs[32][68];
  __shared__ __align__(16) float Kt[64][68];   // K transposed: Kt[d][s]
  __shared__ __align__(16) float Vs[64][68];
  __shared__ float q2raw[32], k2raw[64];
  __shared__ float q2s[32], k2s[64], fqv[32], fkv[64];
  const int bid = blockIdx.x;
  const int be = bid >> 4, h = (bid >> 1) & 7, q0 = (bid & 1) * 32;
  const int tid = threadIdx.x;
  const double chd = log1p(exp((double)chl[h]));   // softplus (once)
  const float ch = (float)chd;
  float sc = (float)sqrt(chd); if (sc < 1e-7f) sc = 1e-7f;
  // ---- stage K^T (RoPE) + V, 64 rows; 256 tasks = (s, 8-wide j-chunk) ----
  {
    const int s = tid >> 2, jc = (tid & 3) * 8;
    const h16* base = qkv + (size_t)(be * 64 + s) * 1536 + h * 64;
    h8v klo = *(const h8v*)(base + 512 + jc);
    h8v khi = *(const h8v*)(base + 512 + jc + 32);
    h8v vlo = *(const h8v*)(base + 1024 + jc);
    h8v vhi = *(const h8v*)(base + 1024 + jc + 32);
    float racc = 0.f;
#pragma unroll
    for (int j = 0; j < 8; ++j) {
      float ka = (float)klo[j], kb = (float)khi[j];
      racc += ka * ka + kb * kb;
      float fj = expf((float)(jc + j) * -0.2878231366242557f);   // ln(10000)/32
      float st, ct; sincosf((float)s * fj, &st, &ct);
      Kt[jc + j][s]      = ka * ct - kb * st;
      Kt[jc + j + 32][s] = ka * st + kb * ct;
    }
    float4 v0, v1;
#pragma unroll
    for (int j = 0; j < 4; ++j) { v0[j] = (float)vlo[j]; v1[j] = (float)vlo[j + 4]; }
    *(float4*)&Vs[s][jc] = v0; *(float4*)&Vs[s][jc + 4] = v1;
#pragma unroll
    for (int j = 0; j < 4; ++j) { v0[j] = (float)vhi[j]; v1[j] = (float)vhi[j + 4]; }
    *(float4*)&Vs[s][jc + 32] = v0; *(float4*)&Vs[s][jc + 36] = v1;
    racc += __shfl_xor(racc, 1, 64);
    racc += __shfl_xor(racc, 2, 64);
    if ((tid & 3) == 0) k2raw[s] = racc;
  }
  // ---- stage Q (RoPE), 32 rows; 128 tasks ----
  if (tid < 128) {
    const int s = tid >> 2, jc = (tid & 3) * 8;
    const h16* base = qkv + (size_t)(be * 64 + q0 + s) * 1536 + h * 64;
    h8v qlo = *(const h8v*)(base + jc);
    h8v qhi = *(const h8v*)(base + jc + 32);
    float racc = 0.f;
    float rl[8], rh[8];
#pragma unroll
    for (int j = 0; j < 8; ++j) {
      float qa = (float)qlo[j], qb = (float)qhi[j];
      racc += qa * qa + qb * qb;
      float fj = expf((float)(jc + j) * -0.2878231366242557f);
      float st, ct; sincosf((float)(q0 + s) * fj, &st, &ct);
      rl[j] = qa * ct - qb * st;
      rh[j] = qa * st + qb * ct;
    }
    *(float4*)&Qs[s][jc]      = {rl[0], rl[1], rl[2], rl[3]};
    *(float4*)&Qs[s][jc + 4]  = {rl[4], rl[5], rl[6], rl[7]};
    *(float4*)&Qs[s][jc + 32] = {rh[0], rh[1], rh[2], rh[3]};
    *(float4*)&Qs[s][jc + 36] = {rh[4], rh[5], rh[6], rh[7]};
    racc += __shfl_xor(racc, 1, 64);
    racc += __shfl_xor(racc, 2, 64);
    if ((tid & 3) == 0) q2raw[s] = racc;
  }
  __syncthreads();
  // ---- per-row expmap0 factors from raw norms ----
  if (tid < 64) {
    float n = sqrtf(k2raw[tid]);
    float m = tanhf(sc * fmaxf(n, 1e-7f)) / sc;
    float f = (n < 1e-7f) ? 0.f : m / fmaxf(n, 1e-7f);
    if (m >= 1.f) f *= (1.f - 1e-7f) / m;
    float fn = f * n;
    fkv[tid] = f; k2s[tid] = fn * fn;
  } else if (tid < 96) {
    int i = tid - 64;
    float n = sqrtf(q2raw[i]);
    float m = tanhf(sc * fmaxf(n, 1e-7f)) / sc;
    float f = (n < 1e-7f) ? 0.f : m / fmaxf(n, 1e-7f);
    if (m >= 1.f) f *= (1.f - 1e-7f) / m;
    float fn = f * n;
    fqv[i] = f; q2s[i] = fn * fn;
  }
  __syncthreads();
  const int i = tid >> 3, g = tid & 7;   // local q-row, 8-col group
  float gacc[8];
#pragma unroll
  for (int jj = 0; jj < 8; ++jj) gacc[jj] = 0.f;
  for (int d2 = 0; d2 < 64; ++d2) {
    float qv = Qs[i][d2];
    const float4* kp = (const float4*)&Kt[d2][g * 8];
    float4 k0 = kp[0], k1 = kp[1];
    gacc[0] += qv * k0.x; gacc[1] += qv * k0.y; gacc[2] += qv * k0.z; gacc[3] += qv * k0.w;
    gacc[4] += qv * k1.x; gacc[5] += qv * k1.y; gacc[6] += qv * k1.z; gacc[7] += qv * k1.w;
  }
  const float gs = geo[h];
  const float q2 = q2s[i], fqi = fqv[i];
  float lg[8];
  float mx = -1e30f;
#pragma unroll
  for (int jj = 0; jj < 8; ++jj) {
    float gq = fqi * fkv[g * 8 + jj] * gacc[jj];
    float k2 = k2s[g * 8 + jj];
    float A  = 1.f - 2.f * ch * gq + ch * k2;
    float Bv = 1.f - ch * q2;
    float n2 = fmaxf(A * A * q2 - 2.f * A * Bv * gq + Bv * Bv * k2, 0.f);
    float den = fmaxf(1.f - 2.f * ch * gq + ch * ch * q2 * k2, 1e-7f);
    float r = fminf(sqrtf(n2) / den, 1.f - 1e-7f);
    float arg = fminf(sc * r, 1.f - 1e-7f);
    float l = -gs * (2.f * atanhf(arg) / sc);
    lg[jj] = l; mx = fmaxf(mx, l);
  }
  mx = fmaxf(mx, __shfl_xor(mx, 1, 64));
  mx = fmaxf(mx, __shfl_xor(mx, 2, 64));
  mx = fmaxf(mx, __shfl_xor(mx, 4, 64));
  float pv[8]; float sum = 0.f;
#pragma unroll
  for (int jj = 0; jj < 8; ++jj) { pv[jj] = expf(lg[jj] - mx); sum += pv[jj]; }
  sum += __shfl_xor(sum, 1, 64);
  sum += __shfl_xor(sum, 2, 64);
  sum += __shfl_xor(sum, 4, 64);
  float inv = 1.0f / sum;
  // P overwrite of Qs: wave w owns rows 8w..8w+7 exclusively; in-wave lockstep
  // guarantees all lanes finished reading row i before any lane stores.
#pragma unroll
  for (int jj = 0; jj < 8; ++jj) Qs[i][g * 8 + jj] = pv[jj] * inv;
  float oacc[8];
#pragma unroll
  for (int dd = 0; dd < 8; ++dd) oacc[dd] = 0.f;
  for (int jv = 0; jv < 64; ++jv) {
    float p = Qs[i][jv];
    const float4* vp = (const float4*)&Vs[jv][g * 8];
    float4 v0 = vp[0], v1 = vp[1];
    oacc[0] += p * v0.x; oacc[1] += p * v0.y; oacc[2] += p * v0.z; oacc[3] += p * v0.w;
    oacc[4] += p * v1.x; oacc[5] += p * v1.y; oacc[6] += p * v1.z; oacc[7] += p * v1.w;
  }
  h8v ov;
#pragma unroll
  for (int dd = 0; dd < 8; ++dd) ov[dd] = (h16)oacc[dd];
  *(h8v*)(ao + (size_t)(be * 64 + q0 + i) * D + h * 64 + g * 8) = ov;
}

// ---------------- residual: expmap0(proj) -> mobius add -> LN2 chain; one WAVE per row -------
// proj arrives as TWO split-K partial buffers (piece stride NTOK*D), summed here.
__global__ void k_resid(const float* __restrict__ x, const float* __restrict__ proj,
                        const float* __restrict__ cg, const float* __restrict__ s2,
                        const float* __restrict__ b2, float* __restrict__ xa,
                        h16* __restrict__ t2) {
  const int wid = threadIdx.x >> 6, lane = threadIdx.x & 63;
  const int tok = blockIdx.x * 4 + wid;
  const float4* xr  = (const float4*)(x + (size_t)tok * D);
  const float4* p0r = (const float4*)(proj + (size_t)tok * D);
  const float4* p1r = (const float4*)(proj + (size_t)NTOK * D + (size_t)tok * D);
  float4 xv0 = xr[lane], xv1 = xr[lane + 64];
  float4 pa0 = p0r[lane], pa1 = p0r[lane + 64];
  float4 pb0 = p1r[lane], pb1 = p1r[lane + 64];
  float pe[8], xe[8];
  xe[0]=xv0.x; xe[1]=xv0.y; xe[2]=xv0.z; xe[3]=xv0.w; xe[4]=xv1.x; xe[5]=xv1.y; xe[6]=xv1.z; xe[7]=xv1.w;
  pe[0]=pa0.x+pb0.x; pe[1]=pa0.y+pb0.y; pe[2]=pa0.z+pb0.z; pe[3]=pa0.w+pb0.w;
  pe[4]=pa1.x+pb1.x; pe[5]=pa1.y+pb1.y; pe[6]=pa1.z+pb1.z; pe[7]=pa1.w+pb1.w;
  double sx = 0, sp = 0, xx = 0, pp = 0, xp = 0;
#pragma unroll
  for (int j = 0; j < 8; ++j) {
    double dx = xe[j], dp = pe[j];
    sx += dx; sp += dp; xx += dx * dx; pp += dp * dp; xp += dx * dp;
  }
  sx = wave_sum(sx); sp = wave_sum(sp); xx = wave_sum(xx);
  pp = wave_sum(pp); xp = wave_sum(xp);
  double c = (double)cg[0];
  double sc = sqrt(c); if (sc < EPSd) sc = EPSd;
  double pn = sqrt(pp);
  double me = tanh(sc * fmax(pn, EPSd)) / sc;
  double fs = (pn < EPSd) ? 0.0 : me / fmax(pn, EPSd);
  if (me >= 1.0) fs *= (1.0 - EPSd) / me;
  double y2 = fs * fs * pp, xy = fs * xp;
  double a = 1.0 + 2.0 * c * xy + c * y2;
  double b = 1.0 - c * xx;
  double den = 1.0 + 2.0 * c * xy + c * c * xx * y2;
  if (den < EPSd) den = EPSd;
  double zn = sqrt(fmax(a * a * xx + 2.0 * a * b * xy + b * b * y2, 0.0)) / den;
  double zs = 1.0 / den;
  if (zn >= 1.0) zs *= (1.0 - EPSd) / zn;
  double xan = (zn >= 1.0) ? (1.0 - EPSd) : zn;
  double A0 = zs * a, B0 = zs * b * fs;
  double xav[8];
#pragma unroll
  for (int j = 0; j < 8; ++j) xav[j] = A0 * (double)xe[j] + B0 * (double)pe[j];
  {
    float4 o0 = {(float)xav[0], (float)xav[1], (float)xav[2], (float)xav[3]};
    float4 o1 = {(float)xav[4], (float)xav[5], (float)xav[6], (float)xav[7]};
    float4* xw = (float4*)(xa + (size_t)tok * D);
    xw[lane] = o0; xw[lane + 64] = o1;
  }
  double sxa  = A0 * sx + B0 * sp;
  double sxa2 = A0 * A0 * xx + 2.0 * A0 * B0 * xp + B0 * B0 * pp;
  double fl = 0.0;
  if (xan >= EPSd) fl = atanh(fmin(xan, 1.0 - EPSd)) / (sc * fmax(xan, EPSd));
  double mu = fl * sxa / D;
  double var = fl * fl * sxa2 / D - mu * mu;
  double rs = 1.0 / sqrt(var + 1e-6);
  const float4* s2r = (const float4*)s2;
  const float4* b2r = (const float4*)b2;
  float4 sA = s2r[lane], sB = s2r[lane + 64];
  float4 bA = b2r[lane], bB = b2r[lane + 64];
  const float se[8] = {sA.x, sA.y, sA.z, sA.w, sB.x, sB.y, sB.z, sB.w};
  const float be[8] = {bA.x, bA.y, bA.z, bA.w, bB.x, bB.y, bB.z, bB.w};
  double w[8]; double sww = 0.0;
#pragma unroll
  for (int j = 0; j < 8; ++j) {
    w[j] = (fl * xav[j] - mu) * rs * (double)se[j] + (double)be[j];
    sww += w[j] * w[j];
  }
  sww = wave_sum(sww);
  double vn = sqrt(sww);
  double F = 0.0;
  if (vn >= EPSd) {
    double mag_e = tanh(sc * fmax(vn, EPSd)) / sc;
    F = atanh(fmin(mag_e, 1.0 - EPSd)) / (sc * vn);
  }
  h16* dst = t2 + (size_t)tok * D;
#pragma unroll
  for (int half = 0; half < 2; ++half) {
    h4v o;
#pragma unroll
    for (int e = 0; e < 4; ++e) o[e] = (h16)(float)(F * w[half * 4 + e]);
    *(h4v*)(dst + 4 * (lane + 64 * half)) = o;
  }
}

// ---------------- final: expmap0(ffn) -> mobius add -> out; one WAVE per row -------------
// f2 arrives as TWO split-K partial buffers, summed here.
__global__ void k_final(const float* __restrict__ xa, const float* __restrict__ f2,
                        const float* __restrict__ cg, float* __restrict__ out) {
  const int wid = threadIdx.x >> 6, lane = threadIdx.x & 63;
  const int tok = blockIdx.x * 4 + wid;
  const float4* ar  = (const float4*)(xa + (size_t)tok * D);
  const float4* f0r = (const float4*)(f2 + (size_t)tok * D);
  const float4* f1r = (const float4*)(f2 + (size_t)NTOK * D + (size_t)tok * D);
  float4 xv0 = ar[lane], xv1 = ar[lane + 64];
  float4 pa0 = f0r[lane], pa1 = f0r[lane + 64];
  float4 pb0 = f1r[lane], pb1 = f1r[lane + 64];
  float pe[8], xe[8];
  xe[0]=xv0.x; xe[1]=xv0.y; xe[2]=xv0.z; xe[3]=xv0.w; xe[4]=xv1.x; xe[5]=xv1.y; xe[6]=xv1.z; xe[7]=xv1.w;
  pe[0]=pa0.x+pb0.x; pe[1]=pa0.y+pb0.y; pe[2]=pa0.z+pb0.z; pe[3]=pa0.w+pb0.w;
  pe[4]=pa1.x+pb1.x; pe[5]=pa1.y+pb1.y; pe[6]=pa1.z+pb1.z; pe[7]=pa1.w+pb1.w;
  double xx = 0, pp = 0, xp = 0;
#pragma unroll
  for (int j = 0; j < 8; ++j) {
    double dx = xe[j], dp = pe[j];
    xx += dx * dx; pp += dp * dp; xp += dx * dp;
  }
  xx = wave_sum(xx); pp = wave_sum(pp); xp = wave_sum(xp);
  double c = (double)cg[0];
  double sc = sqrt(c); if (sc < EPSd) sc = EPSd;
  double pn = sqrt(pp);
  double me = tanh(sc * fmax(pn, EPSd)) / sc;
  double fs = (pn < EPSd) ? 0.0 : me / fmax(pn, EPSd);
  if (me >= 1.0) fs *= (1.0 - EPSd) / me;
  double y2 = fs * fs * pp, xy = fs * xp;
  double a = 1.0 + 2.0 * c * xy + c * y2;
  double b = 1.0 - c * xx;
  double den = 1.0 + 2.0 * c * xy + c * c * xx * y2;
  if (den < EPSd) den = EPSd;
  double zn = sqrt(fmax(a * a * xx + 2.0 * a * b * xy + b * b * y2, 0.0)) / den;
  double zs = 1.0 / den;
  if (zn >= 1.0) zs *= (1.0 - EPSd) / zn;
  double A0 = zs * a, B0 = zs * b * fs;
  float4 o0, o1;
  o0.x = (float)(A0 * xe[0] + B0 * pe[0]); o0.y = (float)(A0 * xe[1] + B0 * pe[1]);
  o0.z = (float)(A0 * xe[2] + B0 * pe[2]); o0.w = (float)(A0 * xe[3] + B0 * pe[3]);
  o1.x = (float)(A0 * xe[4] + B0 * pe[4]); o1.y = (float)(A0 * xe[5] + B0 * pe[5]);
  o1.z = (float)(A0 * xe[6] + B0 * pe[6]); o1.w = (float)(A0 * xe[7] + B0 * pe[7]);
  float4* ow = (float4*)(out + (size_t)tok * D);
  ow[lane] = o0; ow[lane + 64] = o1;
}

// ---------------- launch ----------------
extern "C" void kernel_launch(void* const* d_in, const int* in_sizes, int n_in,
                              void* d_out, int out_size, void* d_ws, size_t ws_size,
                              hipStream_t stream) {
  (void)in_sizes; (void)n_in; (void)out_size; (void)ws_size;
  const float* x    = (const float*)d_in[0];
  const float* cg   = (const float*)d_in[1];
  const float* Wqkv = (const float*)d_in[2];
  const float* bqkv = (const float*)d_in[3];
  const float* Wout = (const float*)d_in[4];
  const float* bout = (const float*)d_in[5];
  const float* s1   = (const float*)d_in[6];
  const float* b1   = (const float*)d_in[7];
  const float* s2   = (const float*)d_in[8];
  const float* b2   = (const float*)d_in[9];
  const float* Wff1 = (const float*)d_in[10];
  const float* bff1 = (const float*)d_in[11];
  const float* Wff2 = (const float*)d_in[12];
  const float* bff2 = (const float*)d_in[13];
  const float* chl  = (const float*)d_in[14];
  const float* geo  = (const float*)d_in[15];
  float* out = (float*)d_out;

  // ---- workspace layout (MB offsets), lifetime-overlaid; peak 15 MB ----
  char* base = (char*)d_ws;
  const size_t MB = 1024 * 1024;
  h16*   WqkvT = (h16*)(base + 0);            // 1.5 [prep .. qkv-mm]
  h16*   WoutT = (h16*)(base + (3*MB)/2);     // 0.5 [prep .. out-mm]
  h16*   Wff1T = (h16*)(base + 2*MB);         // 2   [prep .. ff1-mm]
  h16*   Wff2T = (h16*)(base + 4*MB);         // 2   [prep .. ff2-mm]
  h16*   xt    = (h16*)(base + 6*MB);         // 1   [prep .. qkv-mm]
  h16*   qkv   = (h16*)(base + 7*MB);         // 3   [qkv-mm .. attn]
  h16*   ao    = (h16*)(base + 10*MB);        // 1   [attn .. out-mm]
  float* proj  = (float*)(base + 11*MB);      // 4   [out-mm .. resid]   (2 split-K pieces)
  float* xa    = (float*)(base + 7*MB);       // 2   [resid .. final]    (qkv slot, dead)
  h16*   t2    = (h16*)(base + 6*MB);         // 1   [resid .. ff1-mm]   (xt slot)
  h16*   h1    = (h16*)(base + 11*MB);        // 4   [ff1-mm .. ff2-mm]  (proj slot, dead)
  float* f2    = (float*)(base + 0);          // 4   [ff2-mm .. final]   (W*T slots, dead)

  k_prep<<<3072 + NTOK / 4, 256, 0, stream>>>(Wqkv, Wout, Wff1, Wff2, x, cg, s1, b1,
                                              WqkvT, WoutT, Wff1T, Wff2T, xt);
  k_mm<0, 1, 0><<<dim3(1536 / 64, NTOK / 64), 256, 0, stream>>>(
      xt, WqkvT, bqkv, nullptr, qkv, NTOK, 1536, 512);
  k_attn<<<NB * H * 2, 256, 0, stream>>>(qkv, chl, geo, ao);
  k_mm<0, 0, 1><<<dim3(512 / 64, NTOK / 64, 2), 256, 0, stream>>>(
      ao, WoutT, bout, proj, nullptr, NTOK, 512, 512);
  k_resid<<<NTOK / 4, 256, 0, stream>>>(x, proj, cg, s2, b2, xa, t2);
  k_mm<1, 1, 0><<<dim3(2048 / 64, NTOK / 64), 256, 0, stream>>>(
      t2, Wff1T, bff1, nullptr, h1, NTOK, 2048, 512);
  k_mm<0, 0, 1><<<dim3(512 / 64, NTOK / 64, 2), 256, 0, stream>>>(
      h1, Wff2T, bff2, f2, nullptr, NTOK, 512, 2048);
  k_final<<<NTOK / 4, 256, 0, stream>>>(xa, f2, cg, out);
}

// Round 10
// 71.057 us; speedup vs baseline: 2.3518x; 1.0331x over previous
//
#include <hip/hip_runtime.h>
#include <math.h>

#define DEV __device__ __forceinline__
typedef _Float16 h16;
typedef __attribute__((ext_vector_type(8))) _Float16 h8v;  // 8 fp16 = 4 VGPR
typedef __attribute__((ext_vector_type(4))) _Float16 h4v;  // 8-byte fp16 store
typedef __attribute__((ext_vector_type(4))) float f4v;

constexpr int NTOK = 1024;
constexpr int D    = 512;
constexpr int H    = 8;
constexpr int NB   = 16;
constexpr double EPSd = 1e-7;

// ---------------- wave reduction (row fully owned by one wave; no barriers) ----------------
DEV double wave_sum(double v) {
#pragma unroll
  for (int m = 32; m; m >>= 1) v += __shfl_xor(v, m, 64);
  return v;
}

// ---------------- 64x64 transpose-cast tile: fp32[K][N] -> fp16[N][K] ----------------
// float4 global loads, float4 LDS writes, h4v (8B) coalesced stores.
DEV void tcast64(const float* __restrict__ src, h16* __restrict__ dst,
                 int K, int N, int n0, int k0, float* tls /* [64*68] */) {
  const int tx = threadIdx.x & 15, ty = threadIdx.x >> 4;
#pragma unroll
  for (int it = 0; it < 4; ++it) {
    const int k = ty + it * 16;
    float4 v = *(const float4*)(src + (size_t)(k0 + k) * N + n0 + tx * 4);
    *(float4*)(tls + k * 68 + tx * 4) = v;
  }
  __syncthreads();
#pragma unroll
  for (int it = 0; it < 4; ++it) {
    const int n = ty + it * 16;
    const int kc = tx * 4;
    h4v o;
#pragma unroll
    for (int j = 0; j < 4; ++j) o[j] = (h16)tls[(kc + j) * 68 + n];
    *(h4v*)(dst + (size_t)(n0 + n) * K + k0 + kc) = o;
  }
}

// ---------------- k_prep: all 4 weight transposes (768 blocks) + pre (256 blocks) -----------
__global__ void k_prep(const float* __restrict__ Wqkv, const float* __restrict__ Wout,
                       const float* __restrict__ Wff1, const float* __restrict__ Wff2,
                       const float* __restrict__ x, const float* __restrict__ cg,
                       const float* __restrict__ s1, const float* __restrict__ b1,
                       h16* __restrict__ qT, h16* __restrict__ oT,
                       h16* __restrict__ f1T, h16* __restrict__ f2T,
                       h16* __restrict__ xt) {
  __shared__ __align__(16) float tls[64 * 68];
  const int bid = blockIdx.x;
  if (bid < 768) {    // ---- transpose-cast, 64x64 tiles ----
    const float* src; h16* dst; int K, N, bx, by, l;
    if (bid < 192)      { l = bid;       src = Wqkv; dst = qT;  K = 512;  N = 1536; bx = l % 24; by = l / 24; }
    else if (bid < 256) { l = bid - 192; src = Wout; dst = oT;  K = 512;  N = 512;  bx = l % 8;  by = l / 8;  }
    else if (bid < 512) { l = bid - 256; src = Wff1; dst = f1T; K = 512;  N = 2048; bx = l % 32; by = l / 32; }
    else                { l = bid - 512; src = Wff2; dst = f2T; K = 2048; N = 512;  bx = l % 8;  by = l / 8;  }
    tcast64(src, dst, K, N, bx * 64, by * 64, tls);
    return;
  }
  // ---- pre: logmap0 -> LN -> expmap0 -> logmap0 (fused), one WAVE per token row ----
  const int wid = threadIdx.x >> 6, lane = threadIdx.x & 63;
  const int tok = (bid - 768) * 4 + wid;
  const float4* xr = (const float4*)(x + (size_t)tok * D);
  float4 xv0 = xr[lane], xv1 = xr[lane + 64];
  double sv = 0.0, svv = 0.0;
  {
    const float e[8] = {xv0.x, xv0.y, xv0.z, xv0.w, xv1.x, xv1.y, xv1.z, xv1.w};
#pragma unroll
    for (int j = 0; j < 8; ++j) { double d = e[j]; sv += d; svv += d * d; }
  }
  sv = wave_sum(sv); svv = wave_sum(svv);
  double c = (double)cg[0];
  double sc = sqrt(c); if (sc < EPSd) sc = EPSd;
  double yn = sqrt(svv);
  double arg0 = yn; if (arg0 > 1.0 - EPSd) arg0 = 1.0 - EPSd;
  double f = (yn < EPSd) ? 0.0 : atanh(arg0) / sc / fmax(yn, EPSd);
  double mu = f * sv / D;
  double var = f * f * svv / D - mu * mu;
  double rs = 1.0 / sqrt(var + 1e-6);
  const float4* s1r = (const float4*)s1;
  const float4* b1r = (const float4*)b1;
  float4 sA = s1r[lane], sB = s1r[lane + 64];
  float4 bA = b1r[lane], bB = b1r[lane + 64];
  double w[8]; double sww = 0.0;
  {
    const float e[8]  = {xv0.x, xv0.y, xv0.z, xv0.w, xv1.x, xv1.y, xv1.z, xv1.w};
    const float se[8] = {sA.x, sA.y, sA.z, sA.w, sB.x, sB.y, sB.z, sB.w};
    const float be[8] = {bA.x, bA.y, bA.z, bA.w, bB.x, bB.y, bB.z, bB.w};
#pragma unroll
    for (int j = 0; j < 8; ++j) {
      w[j] = (f * (double)e[j] - mu) * rs * (double)se[j] + (double)be[j];
      sww += w[j] * w[j];
    }
  }
  sww = wave_sum(sww);
  double vn = sqrt(sww);
  double F = 0.0;
  if (vn >= EPSd) {
    double mag_e = tanh(sc * fmax(vn, EPSd)) / sc;
    F = atanh(fmin(mag_e, 1.0 - EPSd)) / (sc * vn);
  }
  h16* dst = xt + (size_t)tok * D;
#pragma unroll
  for (int half = 0; half < 2; ++half) {
    h4v o;
#pragma unroll
    for (int e = 0; e < 4; ++e) o[e] = (h16)(float)(F * w[half * 4 + e]);
    *(h4v*)(dst + 4 * (lane + 64 * half)) = o;
  }
}

// ---------------- fp16 MFMA GEMM, 64x64 tile, BK=64, 3-deep counted-vmcnt pipeline ----------
// LDS content chunk c of row r stored at chunk position c^(r&7) (pre-swizzled GLOBAL source;
// global_load_lds dest is linear base + lane*16). Reads apply the same XOR.
DEV void stage_tile(const h16* __restrict__ gbase, int rowstride, h16* lds,
                    int wid, int lane) {
#pragma unroll
  for (int j = 0; j < 2; ++j) {
    const int rbase = wid * 16 + j * 8;
    const int grow = rbase + (lane >> 3);
    const int gch = (lane & 7) ^ (lane >> 3);
    const h16* gp = gbase + (size_t)grow * rowstride + gch * 8;
    __builtin_amdgcn_global_load_lds(
        (const __attribute__((address_space(1))) void*)gp,
        (__attribute__((address_space(3))) void*)(lds + rbase * 64), 16, 0, 0);
  }
}
DEV h8v read_frag(const h16* lds, int row, int c) {
  const int p = c ^ (row & 7);
  return *(const h8v*)(lds + row * 64 + p * 8);
}

// SPLITK: grid.z pieces over K; piece z writes Cf + z*M*N (fp32), bias only in piece 0.
template <int GELU, int OHALF, int SPLITK>
__global__ __launch_bounds__(256) void k_mm(
    const h16* __restrict__ A, const h16* __restrict__ B,
    const float* __restrict__ bias, float* __restrict__ Cf, h16* __restrict__ Ch,
    int M, int N, int K) {
  __shared__ __align__(16) h16 As[3][64 * 64];
  __shared__ __align__(16) h16 Bs[3][64 * 64];
  const int tid = threadIdx.x;
  const int lane = tid & 63, wid = tid >> 6;
  const int wr = (wid >> 1) * 32, wc = (wid & 1) * 32;
  const int lr = lane & 15, lg = lane >> 4;
  const size_t r0 = (size_t)blockIdx.y * 64, c0 = (size_t)blockIdx.x * 64;
  const int kz = SPLITK ? blockIdx.z : 0;
  const int Keff = SPLITK ? (K >> 1) : K;
  const f4v z = {0.f, 0.f, 0.f, 0.f};
  f4v acc[2][2]; acc[0][0] = z; acc[0][1] = z; acc[1][0] = z; acc[1][1] = z;
  const h16* Abase = A + r0 * K + (size_t)kz * Keff;
  const h16* Bbase = B + c0 * K + (size_t)kz * Keff;
  const int NT = Keff >> 6;
  // prologue: tiles 0,1 in flight (8 loads/wave)
  stage_tile(Abase, K, As[0], wid, lane);
  stage_tile(Bbase, K, Bs[0], wid, lane);
  stage_tile(Abase + 64, K, As[1], wid, lane);
  stage_tile(Bbase + 64, K, Bs[1], wid, lane);
  int cur = 0;
  for (int t = 0; t < NT; ++t) {
    const int pre = (cur == 2) ? 0 : cur + 1;      // buf for t+2 = (cur+2)%3
    const int pre2 = (pre == 2) ? 0 : pre + 1;
    if (t + 2 < NT) {                      // keep 2 tiles in flight
      stage_tile(Abase + (t + 2) * 64, K, As[pre2], wid, lane);
      stage_tile(Bbase + (t + 2) * 64, K, Bs[pre2], wid, lane);
    }
    const int rem = NT - 1 - t;
    if (rem >= 2)      asm volatile("s_waitcnt vmcnt(8)" ::: "memory");
    else if (rem == 1) asm volatile("s_waitcnt vmcnt(4)" ::: "memory");
    else               asm volatile("s_waitcnt vmcnt(0)" ::: "memory");
    asm volatile("s_barrier" ::: "memory");             // all waves' cur loads landed
    const h16* Ac = As[cur];
    const h16* Bc = Bs[cur];
#pragma unroll
    for (int ks = 0; ks < 2; ++ks) {
      const int c = ks * 4 + lg;
      h8v a0 = read_frag(Ac, wr + lr, c);
      h8v a1 = read_frag(Ac, wr + 16 + lr, c);
      h8v b0 = read_frag(Bc, wc + lr, c);
      h8v b1 = read_frag(Bc, wc + 16 + lr, c);
      acc[0][0] = __builtin_amdgcn_mfma_f32_16x16x32_f16(a0, b0, acc[0][0], 0, 0, 0);
      acc[0][1] = __builtin_amdgcn_mfma_f32_16x16x32_f16(a0, b1, acc[0][1], 0, 0, 0);
      acc[1][0] = __builtin_amdgcn_mfma_f32_16x16x32_f16(a1, b0, acc[1][0], 0, 0, 0);
      acc[1][1] = __builtin_amdgcn_mfma_f32_16x16x32_f16(a1, b1, acc[1][1], 0, 0, 0);
    }
    // LDS reads retire into regs before MFMA (compiler lgkmcnt); barrier ends the iter.
    asm volatile("s_barrier" ::: "memory");
    cur = pre;
  }
  float* Cfo = Cf + (size_t)kz * M * N;
#pragma unroll
  for (int m = 0; m < 2; ++m)
#pragma unroll
    for (int n = 0; n < 2; ++n) {
      const size_t row = r0 + wr + m * 16 + lg * 4;
      const size_t col = c0 + wc + n * 16 + lr;
      const float bv = (SPLITK && kz) ? 0.f : bias[col];
#pragma unroll
      for (int e = 0; e < 4; ++e) {
        float v = acc[m][n][e] + bv;
        if (GELU) {
          float x3 = v * v * v;
          v = 0.5f * v * (1.0f + tanhf(0.7978845608028654f * (v + 0.044715f * x3)));
        }
        if (OHALF) Ch[(row + e) * N + col] = (h16)v;
        else       Cfo[(row + e) * N + col] = v;
      }
    }
}

// ---------------- attention: RoPE + per-head expmap0 + hyperbolic dist + softmax + PV -------
// 2 blocks per (be,h): each owns 32 q-rows (8 lanes/row, 8 cols each). K/V staged fully.
// Vectorized h8v staging; row norms computed from RAW q/k (RoPE rotation is orthogonal).
__global__ __launch_bounds__(256) void k_attn(
    const h16* __restrict__ qkv, const float* __restrict__ chl,
    const float* __restrict__ geo, h16* __restrict__ ao) {
  __shared__ __align__(16) float Qs[32][68];
  __shared__ __align__(16) float Kt[64][68];   // K transposed: Kt[d][s]
  __shared__ __align__(16) float Vs[64][68];
  __shared__ float q2raw[32], k2raw[64];
  __shared__ float q2s[32], k2s[64], fqv[32], fkv[64];
  const int bid = blockIdx.x;
  const int be = bid >> 4, h = (bid >> 1) & 7, q0 = (bid & 1) * 32;
  const int tid = threadIdx.x;
  const double chd = log1p(exp((double)chl[h]));   // softplus (once)
  const float ch = (float)chd;
  float sc = (float)sqrt(chd); if (sc < 1e-7f) sc = 1e-7f;
  // ---- stage K^T (RoPE) + V, 64 rows; 256 tasks = (s, 8-wide j-chunk) ----
  {
    const int s = tid >> 2, jc = (tid & 3) * 8;
    const h16* base = qkv + (size_t)(be * 64 + s) * 1536 + h * 64;
    h8v klo = *(const h8v*)(base + 512 + jc);
    h8v khi = *(const h8v*)(base + 512 + jc + 32);
    h8v vlo = *(const h8v*)(base + 1024 + jc);
    h8v vhi = *(const h8v*)(base + 1024 + jc + 32);
    float racc = 0.f;
#pragma unroll
    for (int j = 0; j < 8; ++j) {
      float ka = (float)klo[j], kb = (float)khi[j];
      racc += ka * ka + kb * kb;
      float fj = expf((float)(jc + j) * -0.2878231366242557f);   // ln(10000)/32
      float st, ct; sincosf((float)s * fj, &st, &ct);
      Kt[jc + j][s]      = ka * ct - kb * st;
      Kt[jc + j + 32][s] = ka * st + kb * ct;
    }
    float4 v0, v1;
#pragma unroll
    for (int j = 0; j < 4; ++j) { v0[j] = (float)vlo[j]; v1[j] = (float)vlo[j + 4]; }
    *(float4*)&Vs[s][jc] = v0; *(float4*)&Vs[s][jc + 4] = v1;
#pragma unroll
    for (int j = 0; j < 4; ++j) { v0[j] = (float)vhi[j]; v1[j] = (float)vhi[j + 4]; }
    *(float4*)&Vs[s][jc + 32] = v0; *(float4*)&Vs[s][jc + 36] = v1;
    racc += __shfl_xor(racc, 1, 64);
    racc += __shfl_xor(racc, 2, 64);
    if ((tid & 3) == 0) k2raw[s] = racc;
  }
  // ---- stage Q (RoPE), 32 rows; 128 tasks ----
  if (tid < 128) {
    const int s = tid >> 2, jc = (tid & 3) * 8;
    const h16* base = qkv + (size_t)(be * 64 + q0 + s) * 1536 + h * 64;
    h8v qlo = *(const h8v*)(base + jc);
    h8v qhi = *(const h8v*)(base + jc + 32);
    float racc = 0.f;
    float rl[8], rh[8];
#pragma unroll
    for (int j = 0; j < 8; ++j) {
      float qa = (float)qlo[j], qb = (float)qhi[j];
      racc += qa * qa + qb * qb;
      float fj = expf((float)(jc + j) * -0.2878231366242557f);
      float st, ct; sincosf((float)(q0 + s) * fj, &st, &ct);
      rl[j] = qa * ct - qb * st;
      rh[j] = qa * st + qb * ct;
    }
    *(float4*)&Qs[s][jc]      = {rl[0], rl[1], rl[2], rl[3]};
    *(float4*)&Qs[s][jc + 4]  = {rl[4], rl[5], rl[6], rl[7]};
    *(float4*)&Qs[s][jc + 32] = {rh[0], rh[1], rh[2], rh[3]};
    *(float4*)&Qs[s][jc + 36] = {rh[4], rh[5], rh[6], rh[7]};
    racc += __shfl_xor(racc, 1, 64);
    racc += __shfl_xor(racc, 2, 64);
    if ((tid & 3) == 0) q2raw[s] = racc;
  }
  __syncthreads();
  // ---- per-row expmap0 factors from raw norms ----
  if (tid < 64) {
    float n = sqrtf(k2raw[tid]);
    float m = tanhf(sc * fmaxf(n, 1e-7f)) / sc;
    float f = (n < 1e-7f) ? 0.f : m / fmaxf(n, 1e-7f);
    if (m >= 1.f) f *= (1.f - 1e-7f) / m;
    float fn = f * n;
    fkv[tid] = f; k2s[tid] = fn * fn;
  } else if (tid < 96) {
    int i = tid - 64;
    float n = sqrtf(q2raw[i]);
    float m = tanhf(sc * fmaxf(n, 1e-7f)) / sc;
    float f = (n < 1e-7f) ? 0.f : m / fmaxf(n, 1e-7f);
    if (m >= 1.f) f *= (1.f - 1e-7f) / m;
    float fn = f * n;
    fqv[i] = f; q2s[i] = fn * fn;
  }
  __syncthreads();
  const int i = tid >> 3, g = tid & 7;   // local q-row, 8-col group
  float gacc[8];
#pragma unroll
  for (int jj = 0; jj < 8; ++jj) gacc[jj] = 0.f;
  for (int d2 = 0; d2 < 64; ++d2) {
    float qv = Qs[i][d2];
    const float4* kp = (const float4*)&Kt[d2][g * 8];
    float4 k0 = kp[0], k1 = kp[1];
    gacc[0] += qv * k0.x; gacc[1] += qv * k0.y; gacc[2] += qv * k0.z; gacc[3] += qv * k0.w;
    gacc[4] += qv * k1.x; gacc[5] += qv * k1.y; gacc[6] += qv * k1.z; gacc[7] += qv * k1.w;
  }
  const float gs = geo[h];
  const float q2 = q2s[i], fqi = fqv[i];
  float lg[8];
  float mx = -1e30f;
#pragma unroll
  for (int jj = 0; jj < 8; ++jj) {
    float gq = fqi * fkv[g * 8 + jj] * gacc[jj];
    float k2 = k2s[g * 8 + jj];
    float A  = 1.f - 2.f * ch * gq + ch * k2;
    float Bv = 1.f - ch * q2;
    float n2 = fmaxf(A * A * q2 - 2.f * A * Bv * gq + Bv * Bv * k2, 0.f);
    float den = fmaxf(1.f - 2.f * ch * gq + ch * ch * q2 * k2, 1e-7f);
    float r = fminf(sqrtf(n2) / den, 1.f - 1e-7f);
    float arg = fminf(sc * r, 1.f - 1e-7f);
    float l = -gs * (2.f * atanhf(arg) / sc);
    lg[jj] = l; mx = fmaxf(mx, l);
  }
  mx = fmaxf(mx, __shfl_xor(mx, 1, 64));
  mx = fmaxf(mx, __shfl_xor(mx, 2, 64));
  mx = fmaxf(mx, __shfl_xor(mx, 4, 64));
  float pv[8]; float sum = 0.f;
#pragma unroll
  for (int jj = 0; jj < 8; ++jj) { pv[jj] = expf(lg[jj] - mx); sum += pv[jj]; }
  sum += __shfl_xor(sum, 1, 64);
  sum += __shfl_xor(sum, 2, 64);
  sum += __shfl_xor(sum, 4, 64);
  float inv = 1.0f / sum;
  // P overwrite of Qs: wave w owns rows 8w..8w+7 exclusively; in-wave lockstep
  // guarantees all lanes finished reading row i before any lane stores.
#pragma unroll
  for (int jj = 0; jj < 8; ++jj) Qs[i][g * 8 + jj] = pv[jj] * inv;
  float oacc[8];
#pragma unroll
  for (int dd = 0; dd < 8; ++dd) oacc[dd] = 0.f;
  for (int jv = 0; jv < 64; ++jv) {
    float p = Qs[i][jv];
    const float4* vp = (const float4*)&Vs[jv][g * 8];
    float4 v0 = vp[0], v1 = vp[1];
    oacc[0] += p * v0.x; oacc[1] += p * v0.y; oacc[2] += p * v0.z; oacc[3] += p * v0.w;
    oacc[4] += p * v1.x; oacc[5] += p * v1.y; oacc[6] += p * v1.z; oacc[7] += p * v1.w;
  }
  h8v ov;
#pragma unroll
  for (int dd = 0; dd < 8; ++dd) ov[dd] = (h16)oacc[dd];
  *(h8v*)(ao + (size_t)(be * 64 + q0 + i) * D + h * 64 + g * 8) = ov;
}

// ---------------- residual: expmap0(proj) -> mobius add -> LN2 chain; one WAVE per row -------
// proj arrives as TWO split-K partial buffers (piece stride NTOK*D), summed here.
__global__ void k_resid(const float* __restrict__ x, const float* __restrict__ proj,
                        const float* __restrict__ cg, const float* __restrict__ s2,
                        const float* __restrict__ b2, float* __restrict__ xa,
                        h16* __restrict__ t2) {
  const int wid = threadIdx.x >> 6, lane = threadIdx.x & 63;
  const int tok = blockIdx.x * 4 + wid;
  const float4* xr  = (const float4*)(x + (size_t)tok * D);
  const float4* p0r = (const float4*)(proj + (size_t)tok * D);
  const float4* p1r = (const float4*)(proj + (size_t)NTOK * D + (size_t)tok * D);
  float4 xv0 = xr[lane], xv1 = xr[lane + 64];
  float4 pa0 = p0r[lane], pa1 = p0r[lane + 64];
  float4 pb0 = p1r[lane], pb1 = p1r[lane + 64];
  float pe[8], xe[8];
  xe[0]=xv0.x; xe[1]=xv0.y; xe[2]=xv0.z; xe[3]=xv0.w; xe[4]=xv1.x; xe[5]=xv1.y; xe[6]=xv1.z; xe[7]=xv1.w;
  pe[0]=pa0.x+pb0.x; pe[1]=pa0.y+pb0.y; pe[2]=pa0.z+pb0.z; pe[3]=pa0.w+pb0.w;
  pe[4]=pa1.x+pb1.x; pe[5]=pa1.y+pb1.y; pe[6]=pa1.z+pb1.z; pe[7]=pa1.w+pb1.w;
  double sx = 0, sp = 0, xx = 0, pp = 0, xp = 0;
#pragma unroll
  for (int j = 0; j < 8; ++j) {
    double dx = xe[j], dp = pe[j];
    sx += dx; sp += dp; xx += dx * dx; pp += dp * dp; xp += dx * dp;
  }
  sx = wave_sum(sx); sp = wave_sum(sp); xx = wave_sum(xx);
  pp = wave_sum(pp); xp = wave_sum(xp);
  double c = (double)cg[0];
  double sc = sqrt(c); if (sc < EPSd) sc = EPSd;
  double pn = sqrt(pp);
  double me = tanh(sc * fmax(pn, EPSd)) / sc;
  double fs = (pn < EPSd) ? 0.0 : me / fmax(pn, EPSd);
  if (me >= 1.0) fs *= (1.0 - EPSd) / me;
  double y2 = fs * fs * pp, xy = fs * xp;
  double a = 1.0 + 2.0 * c * xy + c * y2;
  double b = 1.0 - c * xx;
  double den = 1.0 + 2.0 * c * xy + c * c * xx * y2;
  if (den < EPSd) den = EPSd;
  double zn = sqrt(fmax(a * a * xx + 2.0 * a * b * xy + b * b * y2, 0.0)) / den;
  double zs = 1.0 / den;
  if (zn >= 1.0) zs *= (1.0 - EPSd) / zn;
  double xan = (zn >= 1.0) ? (1.0 - EPSd) : zn;
  double A0 = zs * a, B0 = zs * b * fs;
  double xav[8];
#pragma unroll
  for (int j = 0; j < 8; ++j) xav[j] = A0 * (double)xe[j] + B0 * (double)pe[j];
  {
    float4 o0 = {(float)xav[0], (float)xav[1], (float)xav[2], (float)xav[3]};
    float4 o1 = {(float)xav[4], (float)xav[5], (float)xav[6], (float)xav[7]};
    float4* xw = (float4*)(xa + (size_t)tok * D);
    xw[lane] = o0; xw[lane + 64] = o1;
  }
  double sxa  = A0 * sx + B0 * sp;
  double sxa2 = A0 * A0 * xx + 2.0 * A0 * B0 * xp + B0 * B0 * pp;
  double fl = 0.0;
  if (xan >= EPSd) fl = atanh(fmin(xan, 1.0 - EPSd)) / (sc * fmax(xan, EPSd));
  double mu = fl * sxa / D;
  double var = fl * fl * sxa2 / D - mu * mu;
  double rs = 1.0 / sqrt(var + 1e-6);
  const float4* s2r = (const float4*)s2;
  const float4* b2r = (const float4*)b2;
  float4 sA = s2r[lane], sB = s2r[lane + 64];
  float4 bA = b2r[lane], bB = b2r[lane + 64];
  const float se[8] = {sA.x, sA.y, sA.z, sA.w, sB.x, sB.y, sB.z, sB.w};
  const float be[8] = {bA.x, bA.y, bA.z, bA.w, bB.x, bB.y, bB.z, bB.w};
  double w[8]; double sww = 0.0;
#pragma unroll
  for (int j = 0; j < 8; ++j) {
    w[j] = (fl * xav[j] - mu) * rs * (double)se[j] + (double)be[j];
    sww += w[j] * w[j];
  }
  sww = wave_sum(sww);
  double vn = sqrt(sww);
  double F = 0.0;
  if (vn >= EPSd) {
    double mag_e = tanh(sc * fmax(vn, EPSd)) / sc;
    F = atanh(fmin(mag_e, 1.0 - EPSd)) / (sc * vn);
  }
  h16* dst = t2 + (size_t)tok * D;
#pragma unroll
  for (int half = 0; half < 2; ++half) {
    h4v o;
#pragma unroll
    for (int e = 0; e < 4; ++e) o[e] = (h16)(float)(F * w[half * 4 + e]);
    *(h4v*)(dst + 4 * (lane + 64 * half)) = o;
  }
}

// ---------------- final: expmap0(ffn) -> mobius add -> out; one WAVE per row -------------
// f2 arrives as TWO split-K partial buffers, summed here.
__global__ void k_final(const float* __restrict__ xa, const float* __restrict__ f2,
                        const float* __restrict__ cg, float* __restrict__ out) {
  const int wid = threadIdx.x >> 6, lane = threadIdx.x & 63;
  const int tok = blockIdx.x * 4 + wid;
  const float4* ar  = (const float4*)(xa + (size_t)tok * D);
  const float4* f0r = (const float4*)(f2 + (size_t)tok * D);
  const float4* f1r = (const float4*)(f2 + (size_t)NTOK * D + (size_t)tok * D);
  float4 xv0 = ar[lane], xv1 = ar[lane + 64];
  float4 pa0 = f0r[lane], pa1 = f0r[lane + 64];
  float4 pb0 = f1r[lane], pb1 = f1r[lane + 64];
  float pe[8], xe[8];
  xe[0]=xv0.x; xe[1]=xv0.y; xe[2]=xv0.z; xe[3]=xv0.w; xe[4]=xv1.x; xe[5]=xv1.y; xe[6]=xv1.z; xe[7]=xv1.w;
  pe[0]=pa0.x+pb0.x; pe[1]=pa0.y+pb0.y; pe[2]=pa0.z+pb0.z; pe[3]=pa0.w+pb0.w;
  pe[4]=pa1.x+pb1.x; pe[5]=pa1.y+pb1.y; pe[6]=pa1.z+pb1.z; pe[7]=pa1.w+pb1.w;
  double xx = 0, pp = 0, xp = 0;
#pragma unroll
  for (int j = 0; j < 8; ++j) {
    double dx = xe[j], dp = pe[j];
    xx += dx * dx; pp += dp * dp; xp += dx * dp;
  }
  xx = wave_sum(xx); pp = wave_sum(pp); xp = wave_sum(xp);
  double c = (double)cg[0];
  double sc = sqrt(c); if (sc < EPSd) sc = EPSd;
  double pn = sqrt(pp);
  double me = tanh(sc * fmax(pn, EPSd)) / sc;
  double fs = (pn < EPSd) ? 0.0 : me / fmax(pn, EPSd);
  if (me >= 1.0) fs *= (1.0 - EPSd) / me;
  double y2 = fs * fs * pp, xy = fs * xp;
  double a = 1.0 + 2.0 * c * xy + c * y2;
  double b = 1.0 - c * xx;
  double den = 1.0 + 2.0 * c * xy + c * c * xx * y2;
  if (den < EPSd) den = EPSd;
  double zn = sqrt(fmax(a * a * xx + 2.0 * a * b * xy + b * b * y2, 0.0)) / den;
  double zs = 1.0 / den;
  if (zn >= 1.0) zs *= (1.0 - EPSd) / zn;
  double A0 = zs * a, B0 = zs * b * fs;
  float4 o0, o1;
  o0.x = (float)(A0 * xe[0] + B0 * pe[0]); o0.y = (float)(A0 * xe[1] + B0 * pe[1]);
  o0.z = (float)(A0 * xe[2] + B0 * pe[2]); o0.w = (float)(A0 * xe[3] + B0 * pe[3]);
  o1.x = (float)(A0 * xe[4] + B0 * pe[4]); o1.y = (float)(A0 * xe[5] + B0 * pe[5]);
  o1.z = (float)(A0 * xe[6] + B0 * pe[6]); o1.w = (float)(A0 * xe[7] + B0 * pe[7]);
  float4* ow = (float4*)(out + (size_t)tok * D);
  ow[lane] = o0; ow[lane + 64] = o1;
}

// ---------------- launch ----------------
extern "C" void kernel_launch(void* const* d_in, const int* in_sizes, int n_in,
                              void* d_out, int out_size, void* d_ws, size_t ws_size,
                              hipStream_t stream) {
  (void)in_sizes; (void)n_in; (void)out_size; (void)ws_size;
  const float* x    = (const float*)d_in[0];
  const float* cg   = (const float*)d_in[1];
  const float* Wqkv = (const float*)d_in[2];
  const float* bqkv = (const float*)d_in[3];
  const float* Wout = (const float*)d_in[4];
  const float* bout = (const float*)d_in[5];
  const float* s1   = (const float*)d_in[6];
  const float* b1   = (const float*)d_in[7];
  const float* s2   = (const float*)d_in[8];
  const float* b2   = (const float*)d_in[9];
  const float* Wff1 = (const float*)d_in[10];
  const float* bff1 = (const float*)d_in[11];
  const float* Wff2 = (const float*)d_in[12];
  const float* bff2 = (const float*)d_in[13];
  const float* chl  = (const float*)d_in[14];
  const float* geo  = (const float*)d_in[15];
  float* out = (float*)d_out;

  // ---- workspace layout (MB offsets), lifetime-overlaid; peak 15 MB ----
  char* base = (char*)d_ws;
  const size_t MB = 1024 * 1024;
  h16*   WqkvT = (h16*)(base + 0);            // 1.5 [prep .. qkv-mm]
  h16*   WoutT = (h16*)(base + (3*MB)/2);     // 0.5 [prep .. out-mm]
  h16*   Wff1T = (h16*)(base + 2*MB);         // 2   [prep .. ff1-mm]
  h16*   Wff2T = (h16*)(base + 4*MB);         // 2   [prep .. ff2-mm]
  h16*   xt    = (h16*)(base + 6*MB);         // 1   [prep .. qkv-mm]
  h16*   qkv   = (h16*)(base + 7*MB);         // 3   [qkv-mm .. attn]
  h16*   ao    = (h16*)(base + 10*MB);        // 1   [attn .. out-mm]
  float* proj  = (float*)(base + 11*MB);      // 4   [out-mm .. resid]   (2 split-K pieces)
  float* xa    = (float*)(base + 7*MB);       // 2   [resid .. final]    (qkv slot, dead)
  h16*   t2    = (h16*)(base + 6*MB);         // 1   [resid .. ff1-mm]   (xt slot)
  h16*   h1    = (h16*)(base + 11*MB);        // 4   [ff1-mm .. ff2-mm]  (proj slot, dead)
  float* f2    = (float*)(base + 0);          // 4   [ff2-mm .. final]   (W*T slots, dead)

  k_prep<<<768 + NTOK / 4, 256, 0, stream>>>(Wqkv, Wout, Wff1, Wff2, x, cg, s1, b1,
                                             WqkvT, WoutT, Wff1T, Wff2T, xt);
  k_mm<0, 1, 0><<<dim3(1536 / 64, NTOK / 64), 256, 0, stream>>>(
      xt, WqkvT, bqkv, nullptr, qkv, NTOK, 1536, 512);
  k_attn<<<NB * H * 2, 256, 0, stream>>>(qkv, chl, geo, ao);
  k_mm<0, 0, 1><<<dim3(512 / 64, NTOK / 64, 2), 256, 0, stream>>>(
      ao, WoutT, bout, proj, nullptr, NTOK, 512, 512);
  k_resid<<<NTOK / 4, 256, 0, stream>>>(x, proj, cg, s2, b2, xa, t2);
  k_mm<1, 1, 0><<<dim3(2048 / 64, NTOK / 64), 256, 0, stream>>>(
      t2, Wff1T, bff1, nullptr, h1, NTOK, 2048, 512);
  k_mm<0, 0, 1><<<dim3(512 / 64, NTOK / 64, 2), 256, 0, stream>>>(
      h1, Wff2T, bff2, f2, nullptr, NTOK, 512, 2048);
  k_final<<<NTOK / 4, 256, 0, stream>>>(xa, f2, cg, out);
}

// Round 11
// 68.031 us; speedup vs baseline: 2.4564x; 1.0445x over previous
//
#include <hip/hip_runtime.h>
#include <math.h>

#define DEV __device__ __forceinline__
typedef _Float16 h16;
typedef __attribute__((ext_vector_type(8))) _Float16 h8v;  // 8 fp16 = 4 VGPR
typedef __attribute__((ext_vector_type(4))) _Float16 h4v;  // 8-byte fp16 store
typedef __attribute__((ext_vector_type(4))) float f4v;

constexpr int NTOK = 1024;
constexpr int D    = 512;
constexpr int H    = 8;
constexpr int NB   = 16;
constexpr double EPSd = 1e-7;

// ---------------- wave reduction (row fully owned by one wave; no barriers) ----------------
DEV double wave_sum(double v) {
#pragma unroll
  for (int m = 32; m; m >>= 1) v += __shfl_xor(v, m, 64);
  return v;
}

// ---------------- 64x64 transpose-cast tile: fp32[K][N] -> fp16[N][K] ----------------
// float4 global loads, float4 LDS writes, h4v (8B) coalesced stores.
DEV void tcast64(const float* __restrict__ src, h16* __restrict__ dst,
                 int K, int N, int n0, int k0, float* tls /* [64*68] */) {
  const int tx = threadIdx.x & 15, ty = threadIdx.x >> 4;
#pragma unroll
  for (int it = 0; it < 4; ++it) {
    const int k = ty + it * 16;
    float4 v = *(const float4*)(src + (size_t)(k0 + k) * N + n0 + tx * 4);
    *(float4*)(tls + k * 68 + tx * 4) = v;
  }
  __syncthreads();
#pragma unroll
  for (int it = 0; it < 4; ++it) {
    const int n = ty + it * 16;
    const int kc = tx * 4;
    h4v o;
#pragma unroll
    for (int j = 0; j < 4; ++j) o[j] = (h16)tls[(kc + j) * 68 + n];
    *(h4v*)(dst + (size_t)(n0 + n) * K + k0 + kc) = o;
  }
}

// ---------------- k_prep: Wqkv transpose (192 blocks) + pre (256 blocks) ----------------
__global__ void k_prep(const float* __restrict__ Wqkv,
                       const float* __restrict__ x, const float* __restrict__ cg,
                       const float* __restrict__ s1, const float* __restrict__ b1,
                       h16* __restrict__ qT, h16* __restrict__ xt) {
  __shared__ __align__(16) float tls[64 * 68];
  const int bid = blockIdx.x;
  if (bid < 192) {    // Wqkv: K=512, N=1536 -> 24 x 8 tiles
    tcast64(Wqkv, qT, 512, 1536, (bid % 24) * 64, (bid / 24) * 64, tls);
    return;
  }
  // ---- pre: logmap0 -> LN -> expmap0 -> logmap0 (fused), one WAVE per token row ----
  const int wid = threadIdx.x >> 6, lane = threadIdx.x & 63;
  const int tok = (bid - 192) * 4 + wid;
  const float4* xr = (const float4*)(x + (size_t)tok * D);
  float4 xv0 = xr[lane], xv1 = xr[lane + 64];
  double sv = 0.0, svv = 0.0;
  {
    const float e[8] = {xv0.x, xv0.y, xv0.z, xv0.w, xv1.x, xv1.y, xv1.z, xv1.w};
#pragma unroll
    for (int j = 0; j < 8; ++j) { double d = e[j]; sv += d; svv += d * d; }
  }
  sv = wave_sum(sv); svv = wave_sum(svv);
  double c = (double)cg[0];
  double sc = sqrt(c); if (sc < EPSd) sc = EPSd;
  double yn = sqrt(svv);
  double arg0 = yn; if (arg0 > 1.0 - EPSd) arg0 = 1.0 - EPSd;
  double f = (yn < EPSd) ? 0.0 : atanh(arg0) / sc / fmax(yn, EPSd);
  double mu = f * sv / D;
  double var = f * f * svv / D - mu * mu;
  double rs = 1.0 / sqrt(var + 1e-6);
  const float4* s1r = (const float4*)s1;
  const float4* b1r = (const float4*)b1;
  float4 sA = s1r[lane], sB = s1r[lane + 64];
  float4 bA = b1r[lane], bB = b1r[lane + 64];
  double w[8]; double sww = 0.0;
  {
    const float e[8]  = {xv0.x, xv0.y, xv0.z, xv0.w, xv1.x, xv1.y, xv1.z, xv1.w};
    const float se[8] = {sA.x, sA.y, sA.z, sA.w, sB.x, sB.y, sB.z, sB.w};
    const float be[8] = {bA.x, bA.y, bA.z, bA.w, bB.x, bB.y, bB.z, bB.w};
#pragma unroll
    for (int j = 0; j < 8; ++j) {
      w[j] = (f * (double)e[j] - mu) * rs * (double)se[j] + (double)be[j];
      sww += w[j] * w[j];
    }
  }
  sww = wave_sum(sww);
  double vn = sqrt(sww);
  double F = 0.0;
  if (vn >= EPSd) {
    double mag_e = tanh(sc * fmax(vn, EPSd)) / sc;
    F = atanh(fmin(mag_e, 1.0 - EPSd)) / (sc * vn);
  }
  h16* dst = xt + (size_t)tok * D;
#pragma unroll
  for (int half = 0; half < 2; ++half) {
    h4v o;
#pragma unroll
    for (int e = 0; e < 4; ++e) o[e] = (h16)(float)(F * w[half * 4 + e]);
    *(h4v*)(dst + 4 * (lane + 64 * half)) = o;
  }
}

// ---------------- fp16 MFMA GEMM, 64x64 tile, BK=64, 3-deep counted-vmcnt pipeline ----------
// LDS content chunk c of row r stored at chunk position c^(r&7) (pre-swizzled GLOBAL source;
// global_load_lds dest is linear base + lane*16). Reads apply the same XOR.
DEV void stage_tile(const h16* __restrict__ gbase, int rowstride, h16* lds,
                    int wid, int lane) {
#pragma unroll
  for (int j = 0; j < 2; ++j) {
    const int rbase = wid * 16 + j * 8;
    const int grow = rbase + (lane >> 3);
    const int gch = (lane & 7) ^ (lane >> 3);
    const h16* gp = gbase + (size_t)grow * rowstride + gch * 8;
    __builtin_amdgcn_global_load_lds(
        (const __attribute__((address_space(1))) void*)gp,
        (__attribute__((address_space(3))) void*)(lds + rbase * 64), 16, 0, 0);
  }
}
DEV h8v read_frag(const h16* lds, int row, int c) {
  const int p = c ^ (row & 7);
  return *(const h8v*)(lds + row * 64 + p * 8);
}

// SPLITK: grid.z pieces over K; piece z writes Cf + z*M*N (fp32), bias only in piece 0.
template <int GELU, int OHALF, int SPLITK>
__global__ __launch_bounds__(256) void k_mm(
    const h16* __restrict__ A, const h16* __restrict__ B,
    const float* __restrict__ bias, float* __restrict__ Cf, h16* __restrict__ Ch,
    int M, int N, int K) {
  __shared__ __align__(16) h16 As[3][64 * 64];
  __shared__ __align__(16) h16 Bs[3][64 * 64];
  const int tid = threadIdx.x;
  const int lane = tid & 63, wid = tid >> 6;
  const int wr = (wid >> 1) * 32, wc = (wid & 1) * 32;
  const int lr = lane & 15, lg = lane >> 4;
  const size_t r0 = (size_t)blockIdx.y * 64, c0 = (size_t)blockIdx.x * 64;
  const int kz = SPLITK ? blockIdx.z : 0;
  const int Keff = SPLITK ? (K >> 1) : K;
  const f4v z = {0.f, 0.f, 0.f, 0.f};
  f4v acc[2][2]; acc[0][0] = z; acc[0][1] = z; acc[1][0] = z; acc[1][1] = z;
  const h16* Abase = A + r0 * K + (size_t)kz * Keff;
  const h16* Bbase = B + c0 * K + (size_t)kz * Keff;
  const int NT = Keff >> 6;
  // Preload bias NOW and drain vmcnt to 0 so the K-loop's counted waits are exact
  // regardless of where the compiler would otherwise place this loop-invariant load.
  const size_t col0 = c0 + wc + lr;
  float bv0 = bias[col0];
  float bv1 = bias[col0 + 16];
  asm volatile("" :: "v"(bv0), "v"(bv1));             // force loads issued here
  asm volatile("s_waitcnt vmcnt(0)" ::: "memory");    // zero outstanding VMEM
  if (SPLITK && kz) { bv0 = 0.f; bv1 = 0.f; }
  // prologue: tiles 0,1 in flight (8 loads/wave)
  stage_tile(Abase, K, As[0], wid, lane);
  stage_tile(Bbase, K, Bs[0], wid, lane);
  stage_tile(Abase + 64, K, As[1], wid, lane);
  stage_tile(Bbase + 64, K, Bs[1], wid, lane);
  int cur = 0;
  for (int t = 0; t < NT; ++t) {
    const int pre = (cur == 2) ? 0 : cur + 1;      // buf for t+2 = (cur+2)%3
    const int pre2 = (pre == 2) ? 0 : pre + 1;
    if (t + 2 < NT) {                      // keep 2 tiles in flight
      stage_tile(Abase + (t + 2) * 64, K, As[pre2], wid, lane);
      stage_tile(Bbase + (t + 2) * 64, K, Bs[pre2], wid, lane);
    }
    const int rem = NT - 1 - t;
    if (rem >= 2)      asm volatile("s_waitcnt vmcnt(8)" ::: "memory");
    else if (rem == 1) asm volatile("s_waitcnt vmcnt(4)" ::: "memory");
    else               asm volatile("s_waitcnt vmcnt(0)" ::: "memory");
    asm volatile("s_barrier" ::: "memory");             // all waves' cur loads landed
    const h16* Ac = As[cur];
    const h16* Bc = Bs[cur];
#pragma unroll
    for (int ks = 0; ks < 2; ++ks) {
      const int c = ks * 4 + lg;
      h8v a0 = read_frag(Ac, wr + lr, c);
      h8v a1 = read_frag(Ac, wr + 16 + lr, c);
      h8v b0 = read_frag(Bc, wc + lr, c);
      h8v b1 = read_frag(Bc, wc + 16 + lr, c);
      acc[0][0] = __builtin_amdgcn_mfma_f32_16x16x32_f16(a0, b0, acc[0][0], 0, 0, 0);
      acc[0][1] = __builtin_amdgcn_mfma_f32_16x16x32_f16(a0, b1, acc[0][1], 0, 0, 0);
      acc[1][0] = __builtin_amdgcn_mfma_f32_16x16x32_f16(a1, b0, acc[1][0], 0, 0, 0);
      acc[1][1] = __builtin_amdgcn_mfma_f32_16x16x32_f16(a1, b1, acc[1][1], 0, 0, 0);
    }
    // LDS reads retire into regs before MFMA (compiler lgkmcnt); barrier ends the iter.
    asm volatile("s_barrier" ::: "memory");
    cur = pre;
  }
  float* Cfo = Cf + (size_t)kz * M * N;
#pragma unroll
  for (int m = 0; m < 2; ++m)
#pragma unroll
    for (int n = 0; n < 2; ++n) {
      const size_t row = r0 + wr + m * 16 + lg * 4;
      const size_t col = col0 + n * 16;
      const float bv = n ? bv1 : bv0;
#pragma unroll
      for (int e = 0; e < 4; ++e) {
        float v = acc[m][n][e] + bv;
        if (GELU) {
          float x3 = v * v * v;
          v = 0.5f * v * (1.0f + tanhf(0.7978845608028654f * (v + 0.044715f * x3)));
        }
        if (OHALF) Ch[(row + e) * N + col] = (h16)v;
        else       Cfo[(row + e) * N + col] = v;
      }
    }
}

// ---------------- attention (256 blocks) + deferred Wout/Wff1/Wff2 transposes (576) --------
// Attn: 2 blocks per (be,h): each owns 32 q-rows (8 lanes/row, 8 cols each). K/V staged fully.
// Vectorized h8v staging; row norms computed from RAW q/k (RoPE rotation is orthogonal).
__global__ __launch_bounds__(256) void k_attn(
    const h16* __restrict__ qkv, const float* __restrict__ chl,
    const float* __restrict__ geo, h16* __restrict__ ao,
    const float* __restrict__ Wo, const float* __restrict__ Wf1,
    const float* __restrict__ Wf2,
    h16* __restrict__ oT, h16* __restrict__ f1T, h16* __restrict__ f2T) {
  __shared__ __align__(16) float Qs[32][68];
  __shared__ __align__(16) float Kt[64][68];   // K transposed: Kt[d][s]; tcast tls alias
  __shared__ __align__(16) float Vs[64][68];
  __shared__ float q2raw[32], k2raw[64];
  __shared__ float q2s[32], k2s[64], fqv[32], fkv[64];
  const int bid = blockIdx.x;
  if (bid >= 256) {   // ---- deferred transpose-casts on otherwise-idle CUs ----
    const float* src; h16* dst; int K, N, bx, by, l;
    if (bid < 320)      { l = bid - 256; src = Wo;  dst = oT;  K = 512;  N = 512;  bx = l % 8;  by = l / 8;  }
    else if (bid < 576) { l = bid - 320; src = Wf1; dst = f1T; K = 512;  N = 2048; bx = l % 32; by = l / 32; }
    else                { l = bid - 576; src = Wf2; dst = f2T; K = 2048; N = 512;  bx = l % 8;  by = l / 8;  }
    tcast64(src, dst, K, N, bx * 64, by * 64, &Kt[0][0]);
    return;
  }
  const int be = bid >> 4, h = (bid >> 1) & 7, q0 = (bid & 1) * 32;
  const int tid = threadIdx.x;
  const double chd = log1p(exp((double)chl[h]));   // softplus (once)
  const float ch = (float)chd;
  float sc = (float)sqrt(chd); if (sc < 1e-7f) sc = 1e-7f;
  // ---- stage K^T (RoPE) + V, 64 rows; 256 tasks = (s, 8-wide j-chunk) ----
  {
    const int s = tid >> 2, jc = (tid & 3) * 8;
    const h16* base = qkv + (size_t)(be * 64 + s) * 1536 + h * 64;
    h8v klo = *(const h8v*)(base + 512 + jc);
    h8v khi = *(const h8v*)(base + 512 + jc + 32);
    h8v vlo = *(const h8v*)(base + 1024 + jc);
    h8v vhi = *(const h8v*)(base + 1024 + jc + 32);
    float racc = 0.f;
#pragma unroll
    for (int j = 0; j < 8; ++j) {
      float ka = (float)klo[j], kb = (float)khi[j];
      racc += ka * ka + kb * kb;
      float fj = expf((float)(jc + j) * -0.2878231366242557f);   // ln(10000)/32
      float st, ct; sincosf((float)s * fj, &st, &ct);
      Kt[jc + j][s]      = ka * ct - kb * st;
      Kt[jc + j + 32][s] = ka * st + kb * ct;
    }
    float4 v0, v1;
#pragma unroll
    for (int j = 0; j < 4; ++j) { v0[j] = (float)vlo[j]; v1[j] = (float)vlo[j + 4]; }
    *(float4*)&Vs[s][jc] = v0; *(float4*)&Vs[s][jc + 4] = v1;
#pragma unroll
    for (int j = 0; j < 4; ++j) { v0[j] = (float)vhi[j]; v1[j] = (float)vhi[j + 4]; }
    *(float4*)&Vs[s][jc + 32] = v0; *(float4*)&Vs[s][jc + 36] = v1;
    racc += __shfl_xor(racc, 1, 64);
    racc += __shfl_xor(racc, 2, 64);
    if ((tid & 3) == 0) k2raw[s] = racc;
  }
  // ---- stage Q (RoPE), 32 rows; 128 tasks ----
  if (tid < 128) {
    const int s = tid >> 2, jc = (tid & 3) * 8;
    const h16* base = qkv + (size_t)(be * 64 + q0 + s) * 1536 + h * 64;
    h8v qlo = *(const h8v*)(base + jc);
    h8v qhi = *(const h8v*)(base + jc + 32);
    float racc = 0.f;
    float rl[8], rh[8];
#pragma unroll
    for (int j = 0; j < 8; ++j) {
      float qa = (float)qlo[j], qb = (float)qhi[j];
      racc += qa * qa + qb * qb;
      float fj = expf((float)(jc + j) * -0.2878231366242557f);
      float st, ct; sincosf((float)(q0 + s) * fj, &st, &ct);
      rl[j] = qa * ct - qb * st;
      rh[j] = qa * st + qb * ct;
    }
    *(float4*)&Qs[s][jc]      = {rl[0], rl[1], rl[2], rl[3]};
    *(float4*)&Qs[s][jc + 4]  = {rl[4], rl[5], rl[6], rl[7]};
    *(float4*)&Qs[s][jc + 32] = {rh[0], rh[1], rh[2], rh[3]};
    *(float4*)&Qs[s][jc + 36] = {rh[4], rh[5], rh[6], rh[7]};
    racc += __shfl_xor(racc, 1, 64);
    racc += __shfl_xor(racc, 2, 64);
    if ((tid & 3) == 0) q2raw[s] = racc;
  }
  __syncthreads();
  // ---- per-row expmap0 factors from raw norms ----
  if (tid < 64) {
    float n = sqrtf(k2raw[tid]);
    float m = tanhf(sc * fmaxf(n, 1e-7f)) / sc;
    float f = (n < 1e-7f) ? 0.f : m / fmaxf(n, 1e-7f);
    if (m >= 1.f) f *= (1.f - 1e-7f) / m;
    float fn = f * n;
    fkv[tid] = f; k2s[tid] = fn * fn;
  } else if (tid < 96) {
    int i = tid - 64;
    float n = sqrtf(q2raw[i]);
    float m = tanhf(sc * fmaxf(n, 1e-7f)) / sc;
    float f = (n < 1e-7f) ? 0.f : m / fmaxf(n, 1e-7f);
    if (m >= 1.f) f *= (1.f - 1e-7f) / m;
    float fn = f * n;
    fqv[i] = f; q2s[i] = fn * fn;
  }
  __syncthreads();
  const int i = tid >> 3, g = tid & 7;   // local q-row, 8-col group
  float gacc[8];
#pragma unroll
  for (int jj = 0; jj < 8; ++jj) gacc[jj] = 0.f;
  for (int d2 = 0; d2 < 64; ++d2) {
    float qv = Qs[i][d2];
    const float4* kp = (const float4*)&Kt[d2][g * 8];
    float4 k0 = kp[0], k1 = kp[1];
    gacc[0] += qv * k0.x; gacc[1] += qv * k0.y; gacc[2] += qv * k0.z; gacc[3] += qv * k0.w;
    gacc[4] += qv * k1.x; gacc[5] += qv * k1.y; gacc[6] += qv * k1.z; gacc[7] += qv * k1.w;
  }
  const float gs = geo[h];
  const float q2 = q2s[i], fqi = fqv[i];
  float lg[8];
  float mx = -1e30f;
#pragma unroll
  for (int jj = 0; jj < 8; ++jj) {
    float gq = fqi * fkv[g * 8 + jj] * gacc[jj];
    float k2 = k2s[g * 8 + jj];
    float A  = 1.f - 2.f * ch * gq + ch * k2;
    float Bv = 1.f - ch * q2;
    float n2 = fmaxf(A * A * q2 - 2.f * A * Bv * gq + Bv * Bv * k2, 0.f);
    float den = fmaxf(1.f - 2.f * ch * gq + ch * ch * q2 * k2, 1e-7f);
    float r = fminf(sqrtf(n2) / den, 1.f - 1e-7f);
    float arg = fminf(sc * r, 1.f - 1e-7f);
    float l = -gs * (2.f * atanhf(arg) / sc);
    lg[jj] = l; mx = fmaxf(mx, l);
  }
  mx = fmaxf(mx, __shfl_xor(mx, 1, 64));
  mx = fmaxf(mx, __shfl_xor(mx, 2, 64));
  mx = fmaxf(mx, __shfl_xor(mx, 4, 64));
  float pv[8]; float sum = 0.f;
#pragma unroll
  for (int jj = 0; jj < 8; ++jj) { pv[jj] = expf(lg[jj] - mx); sum += pv[jj]; }
  sum += __shfl_xor(sum, 1, 64);
  sum += __shfl_xor(sum, 2, 64);
  sum += __shfl_xor(sum, 4, 64);
  float inv = 1.0f / sum;
  // P overwrite of Qs: wave w owns rows 8w..8w+7 exclusively; in-wave lockstep
  // guarantees all lanes finished reading row i before any lane stores.
#pragma unroll
  for (int jj = 0; jj < 8; ++jj) Qs[i][g * 8 + jj] = pv[jj] * inv;
  float oacc[8];
#pragma unroll
  for (int dd = 0; dd < 8; ++dd) oacc[dd] = 0.f;
  for (int jv = 0; jv < 64; ++jv) {
    float p = Qs[i][jv];
    const float4* vp = (const float4*)&Vs[jv][g * 8];
    float4 v0 = vp[0], v1 = vp[1];
    oacc[0] += p * v0.x; oacc[1] += p * v0.y; oacc[2] += p * v0.z; oacc[3] += p * v0.w;
    oacc[4] += p * v1.x; oacc[5] += p * v1.y; oacc[6] += p * v1.z; oacc[7] += p * v1.w;
  }
  h8v ov;
#pragma unroll
  for (int dd = 0; dd < 8; ++dd) ov[dd] = (h16)oacc[dd];
  *(h8v*)(ao + (size_t)(be * 64 + q0 + i) * D + h * 64 + g * 8) = ov;
}

// ---------------- residual: expmap0(proj) -> mobius add -> LN2 chain; one WAVE per row -------
// proj arrives as TWO split-K partial buffers (piece stride NTOK*D), summed here.
__global__ void k_resid(const float* __restrict__ x, const float* __restrict__ proj,
                        const float* __restrict__ cg, const float* __restrict__ s2,
                        const float* __restrict__ b2, float* __restrict__ xa,
                        h16* __restrict__ t2) {
  const int wid = threadIdx.x >> 6, lane = threadIdx.x & 63;
  const int tok = blockIdx.x * 4 + wid;
  const float4* xr  = (const float4*)(x + (size_t)tok * D);
  const float4* p0r = (const float4*)(proj + (size_t)tok * D);
  const float4* p1r = (const float4*)(proj + (size_t)NTOK * D + (size_t)tok * D);
  float4 xv0 = xr[lane], xv1 = xr[lane + 64];
  float4 pa0 = p0r[lane], pa1 = p0r[lane + 64];
  float4 pb0 = p1r[lane], pb1 = p1r[lane + 64];
  float pe[8], xe[8];
  xe[0]=xv0.x; xe[1]=xv0.y; xe[2]=xv0.z; xe[3]=xv0.w; xe[4]=xv1.x; xe[5]=xv1.y; xe[6]=xv1.z; xe[7]=xv1.w;
  pe[0]=pa0.x+pb0.x; pe[1]=pa0.y+pb0.y; pe[2]=pa0.z+pb0.z; pe[3]=pa0.w+pb0.w;
  pe[4]=pa1.x+pb1.x; pe[5]=pa1.y+pb1.y; pe[6]=pa1.z+pb1.z; pe[7]=pa1.w+pb1.w;
  double sx = 0, sp = 0, xx = 0, pp = 0, xp = 0;
#pragma unroll
  for (int j = 0; j < 8; ++j) {
    double dx = xe[j], dp = pe[j];
    sx += dx; sp += dp; xx += dx * dx; pp += dp * dp; xp += dx * dp;
  }
  sx = wave_sum(sx); sp = wave_sum(sp); xx = wave_sum(xx);
  pp = wave_sum(pp); xp = wave_sum(xp);
  double c = (double)cg[0];
  double sc = sqrt(c); if (sc < EPSd) sc = EPSd;
  double pn = sqrt(pp);
  double me = tanh(sc * fmax(pn, EPSd)) / sc;
  double fs = (pn < EPSd) ? 0.0 : me / fmax(pn, EPSd);
  if (me >= 1.0) fs *= (1.0 - EPSd) / me;
  double y2 = fs * fs * pp, xy = fs * xp;
  double a = 1.0 + 2.0 * c * xy + c * y2;
  double b = 1.0 - c * xx;
  double den = 1.0 + 2.0 * c * xy + c * c * xx * y2;
  if (den < EPSd) den = EPSd;
  double zn = sqrt(fmax(a * a * xx + 2.0 * a * b * xy + b * b * y2, 0.0)) / den;
  double zs = 1.0 / den;
  if (zn >= 1.0) zs *= (1.0 - EPSd) / zn;
  double xan = (zn >= 1.0) ? (1.0 - EPSd) : zn;
  double A0 = zs * a, B0 = zs * b * fs;
  double xav[8];
#pragma unroll
  for (int j = 0; j < 8; ++j) xav[j] = A0 * (double)xe[j] + B0 * (double)pe[j];
  {
    float4 o0 = {(float)xav[0], (float)xav[1], (float)xav[2], (float)xav[3]};
    float4 o1 = {(float)xav[4], (float)xav[5], (float)xav[6], (float)xav[7]};
    float4* xw = (float4*)(xa + (size_t)tok * D);
    xw[lane] = o0; xw[lane + 64] = o1;
  }
  double sxa  = A0 * sx + B0 * sp;
  double sxa2 = A0 * A0 * xx + 2.0 * A0 * B0 * xp + B0 * B0 * pp;
  double fl = 0.0;
  if (xan >= EPSd) fl = atanh(fmin(xan, 1.0 - EPSd)) / (sc * fmax(xan, EPSd));
  double mu = fl * sxa / D;
  double var = fl * fl * sxa2 / D - mu * mu;
  double rs = 1.0 / sqrt(var + 1e-6);
  const float4* s2r = (const float4*)s2;
  const float4* b2r = (const float4*)b2;
  float4 sA = s2r[lane], sB = s2r[lane + 64];
  float4 bA = b2r[lane], bB = b2r[lane + 64];
  const float se[8] = {sA.x, sA.y, sA.z, sA.w, sB.x, sB.y, sB.z, sB.w};
  const float be[8] = {bA.x, bA.y, bA.z, bA.w, bB.x, bB.y, bB.z, bB.w};
  double w[8]; double sww = 0.0;
#pragma unroll
  for (int j = 0; j < 8; ++j) {
    w[j] = (fl * xav[j] - mu) * rs * (double)se[j] + (double)be[j];
    sww += w[j] * w[j];
  }
  sww = wave_sum(sww);
  double vn = sqrt(sww);
  double F = 0.0;
  if (vn >= EPSd) {
    double mag_e = tanh(sc * fmax(vn, EPSd)) / sc;
    F = atanh(fmin(mag_e, 1.0 - EPSd)) / (sc * vn);
  }
  h16* dst = t2 + (size_t)tok * D;
#pragma unroll
  for (int half = 0; half < 2; ++half) {
    h4v o;
#pragma unroll
    for (int e = 0; e < 4; ++e) o[e] = (h16)(float)(F * w[half * 4 + e]);
    *(h4v*)(dst + 4 * (lane + 64 * half)) = o;
  }
}

// ---------------- final: expmap0(ffn) -> mobius add -> out; one WAVE per row -------------
// f2 arrives as TWO split-K partial buffers, summed here.
__global__ void k_final(const float* __restrict__ xa, const float* __restrict__ f2,
                        const float* __restrict__ cg, float* __restrict__ out) {
  const int wid = threadIdx.x >> 6, lane = threadIdx.x & 63;
  const int tok = blockIdx.x * 4 + wid;
  const float4* ar  = (const float4*)(xa + (size_t)tok * D);
  const float4* f0r = (const float4*)(f2 + (size_t)tok * D);
  const float4* f1r = (const float4*)(f2 + (size_t)NTOK * D + (size_t)tok * D);
  float4 xv0 = ar[lane], xv1 = ar[lane + 64];
  float4 pa0 = f0r[lane], pa1 = f0r[lane + 64];
  float4 pb0 = f1r[lane], pb1 = f1r[lane + 64];
  float pe[8], xe[8];
  xe[0]=xv0.x; xe[1]=xv0.y; xe[2]=xv0.z; xe[3]=xv0.w; xe[4]=xv1.x; xe[5]=xv1.y; xe[6]=xv1.z; xe[7]=xv1.w;
  pe[0]=pa0.x+pb0.x; pe[1]=pa0.y+pb0.y; pe[2]=pa0.z+pb0.z; pe[3]=pa0.w+pb0.w;
  pe[4]=pa1.x+pb1.x; pe[5]=pa1.y+pb1.y; pe[6]=pa1.z+pb1.z; pe[7]=pa1.w+pb1.w;
  double xx = 0, pp = 0, xp = 0;
#pragma unroll
  for (int j = 0; j < 8; ++j) {
    double dx = xe[j], dp = pe[j];
    xx += dx * dx; pp += dp * dp; xp += dx * dp;
  }
  xx = wave_sum(xx); pp = wave_sum(pp); xp = wave_sum(xp);
  double c = (double)cg[0];
  double sc = sqrt(c); if (sc < EPSd) sc = EPSd;
  double pn = sqrt(pp);
  double me = tanh(sc * fmax(pn, EPSd)) / sc;
  double fs = (pn < EPSd) ? 0.0 : me / fmax(pn, EPSd);
  if (me >= 1.0) fs *= (1.0 - EPSd) / me;
  double y2 = fs * fs * pp, xy = fs * xp;
  double a = 1.0 + 2.0 * c * xy + c * y2;
  double b = 1.0 - c * xx;
  double den = 1.0 + 2.0 * c * xy + c * c * xx * y2;
  if (den < EPSd) den = EPSd;
  double zn = sqrt(fmax(a * a * xx + 2.0 * a * b * xy + b * b * y2, 0.0)) / den;
  double zs = 1.0 / den;
  if (zn >= 1.0) zs *= (1.0 - EPSd) / zn;
  double A0 = zs * a, B0 = zs * b * fs;
  float4 o0, o1;
  o0.x = (float)(A0 * xe[0] + B0 * pe[0]); o0.y = (float)(A0 * xe[1] + B0 * pe[1]);
  o0.z = (float)(A0 * xe[2] + B0 * pe[2]); o0.w = (float)(A0 * xe[3] + B0 * pe[3]);
  o1.x = (float)(A0 * xe[4] + B0 * pe[4]); o1.y = (float)(A0 * xe[5] + B0 * pe[5]);
  o1.z = (float)(A0 * xe[6] + B0 * pe[6]); o1.w = (float)(A0 * xe[7] + B0 * pe[7]);
  float4* ow = (float4*)(out + (size_t)tok * D);
  ow[lane] = o0; ow[lane + 64] = o1;
}

// ---------------- launch ----------------
extern "C" void kernel_launch(void* const* d_in, const int* in_sizes, int n_in,
                              void* d_out, int out_size, void* d_ws, size_t ws_size,
                              hipStream_t stream) {
  (void)in_sizes; (void)n_in; (void)out_size; (void)ws_size;
  const float* x    = (const float*)d_in[0];
  const float* cg   = (const float*)d_in[1];
  const float* Wqkv = (const float*)d_in[2];
  const float* bqkv = (const float*)d_in[3];
  const float* Wout = (const float*)d_in[4];
  const float* bout = (const float*)d_in[5];
  const float* s1   = (const float*)d_in[6];
  const float* b1   = (const float*)d_in[7];
  const float* s2   = (const float*)d_in[8];
  const float* b2   = (const float*)d_in[9];
  const float* Wff1 = (const float*)d_in[10];
  const float* bff1 = (const float*)d_in[11];
  const float* Wff2 = (const float*)d_in[12];
  const float* bff2 = (const float*)d_in[13];
  const float* chl  = (const float*)d_in[14];
  const float* geo  = (const float*)d_in[15];
  float* out = (float*)d_out;

  // ---- workspace layout (MB offsets), lifetime-overlaid; peak 15 MB ----
  char* base = (char*)d_ws;
  const size_t MB = 1024 * 1024;
  h16*   WqkvT = (h16*)(base + 0);            // 1.5 [prep .. qkv-mm]
  h16*   WoutT = (h16*)(base + (3*MB)/2);     // 0.5 [attn .. out-mm]
  h16*   Wff1T = (h16*)(base + 2*MB);         // 2   [attn .. ff1-mm]
  h16*   Wff2T = (h16*)(base + 4*MB);         // 2   [attn .. ff2-mm]
  h16*   xt    = (h16*)(base + 6*MB);         // 1   [prep .. qkv-mm]
  h16*   qkv   = (h16*)(base + 7*MB);         // 3   [qkv-mm .. attn]
  h16*   ao    = (h16*)(base + 10*MB);        // 1   [attn .. out-mm]
  float* proj  = (float*)(base + 11*MB);      // 4   [out-mm .. resid]   (2 split-K pieces)
  float* xa    = (float*)(base + 7*MB);       // 2   [resid .. final]    (qkv slot, dead)
  h16*   t2    = (h16*)(base + 6*MB);         // 1   [resid .. ff1-mm]   (xt slot)
  h16*   h1    = (h16*)(base + 11*MB);        // 4   [ff1-mm .. ff2-mm]  (proj slot, dead)
  float* f2    = (float*)(base + 0);          // 4   [ff2-mm .. final]   (W*T slots, dead)

  k_prep<<<192 + NTOK / 4, 256, 0, stream>>>(Wqkv, x, cg, s1, b1, WqkvT, xt);
  k_mm<0, 1, 0><<<dim3(1536 / 64, NTOK / 64), 256, 0, stream>>>(
      xt, WqkvT, bqkv, nullptr, qkv, NTOK, 1536, 512);
  k_attn<<<NB * H * 2 + 576, 256, 0, stream>>>(qkv, chl, geo, ao,
                                               Wout, Wff1, Wff2, WoutT, Wff1T, Wff2T);
  k_mm<0, 0, 1><<<dim3(512 / 64, NTOK / 64, 2), 256, 0, stream>>>(
      ao, WoutT, bout, proj, nullptr, NTOK, 512, 512);
  k_resid<<<NTOK / 4, 256, 0, stream>>>(x, proj, cg, s2, b2, xa, t2);
  k_mm<1, 1, 0><<<dim3(2048 / 64, NTOK / 64), 256, 0, stream>>>(
      t2, Wff1T, bff1, nullptr, h1, NTOK, 2048, 512);
  k_mm<0, 0, 1><<<dim3(512 / 64, NTOK / 64, 2), 256, 0, stream>>>(
      h1, Wff2T, bff2, f2, nullptr, NTOK, 512, 2048);
  k_final<<<NTOK / 4, 256, 0, stream>>>(xa, f2, cg, out);
}